// Round 16
// baseline (745.081 us; speedup 1.0000x reference)
//
#include <hip/hip_runtime.h>
#include <hip/hip_bf16.h>

// MultiViewFusion — two-kernel split, round 16.
// Evidence ledger:
//   R5  PASS 0.0156 (1338us): scalar-f32 fused (folding algebra correct).
//   R6-R9 FAIL: within-kernel MFMA acc->LDS->read corrupts. QUARANTINE:
//        MFMA results exit ONLY via acc->VALU->global store.
//   R10 PASS + zero poisons: MFMA stages 1/2 coordinate-exact.
//   R13 PASS 646us: k_s12 (MFMA->global S) + k_gfl (scalar).
//   R14 PASS 547us: k_gfl2 2-col (285us); k_s12 ~230us (L2-bound).
//   R15 FAIL 4.44: staging stride bug — float4 converts to ushort4 (8 B),
//        but staging wrote rem*16 -> row overrun, S garbage.
// R16: R15 with the two-token fix (rem*16 -> rem*8 in both k_s12 staging
//      loops). (a) k_s12 M=32, K-halved staging (xt[32][384]+xu[32][128]
//      hi/lo = 64KB, 2 passes) -> weight L2 traffic halved; K order ascending
//      -> S bit-identical. (b) k_gfl3 4x4 thread tile -> FMA-bound.

namespace {

typedef __attribute__((ext_vector_type(8))) short short8v;   // 8 bf16 = 4 VGPR
typedef __attribute__((ext_vector_type(4))) float floatx4;   // MFMA C/D

// workspace byte offsets (unchanged from R13/R14)
constexpr int OFF_CW  = 0;        // f32 CWt[4][128][128]
constexpr int OFF_CB  = 262144;   // f32 cv[4][128]
constexpr int OFF_BT  = 264192;   // f32 bT[256]  [ts|uc]
constexpr int OFF_BU  = 265216;   // f32 bU[256]  [tc|us]
constexpr int OFF_MTH = 266240;   // bf16 M_text hi packed [96][256][8]
constexpr int OFF_MTL = 659456;   // bf16 M_text lo
constexpr int OFF_MUH = 1052672;  // bf16 M_user hi packed [32][256][8]
constexpr int OFF_MUL = 1183744;  // bf16 M_user lo
constexpr int OFF_GW4 = 1314816;  // f32 gate W [64][256][4] (cols tg|ug)
constexpr int OFF_FW4 = 1576960;  // f32 ff  W  [64][256][4]
constexpr int OFF_MT4 = 1839104;  // f32 M_text pack [192][256][4]  (fallback)
constexpr int OFF_MU4 = 2625536;  // f32 M_user pack [64][256][4]   (fallback)
constexpr long OFF_S  = 2887680;  // f32 S [65536][512] = 134217728 B
constexpr long WS_NEED = OFF_S + 134217728L;

__device__ inline unsigned short f2b(float f) {
  __hip_bfloat16 h = __float2bfloat16(f);
  return __builtin_bit_cast(unsigned short, h);
}
__device__ inline float b2f(unsigned short u) {
  unsigned int v = ((unsigned int)u) << 16;
  return __builtin_bit_cast(float, v);
}
__device__ inline void split2(float v, unsigned short& h, unsigned short& l) {
  h = f2b(v);
  l = f2b(v - b2f(h));
}

// ---------------- precompute (tiny, L2-resident; validated) ----------------

__global__ void k_combine(const float* __restrict__ ipw, const float* __restrict__ opw,
                          char* __restrict__ wsb) {
  float* cw = (float*)(wsb + OFF_CW);
  int n = blockIdx.x * 256 + threadIdx.x;
  int i = n >> 14, o = (n >> 7) & 127, d = n & 127;
  const float* op = opw + i * 16384 + o * 128;
  const float* iv = ipw + i * 49152 + 256 * 128 + d;
  float s = 0.f;
#pragma unroll 4
  for (int m = 0; m < 128; ++m) s = fmaf(op[m], iv[m * 128], s);
  cw[i * 16384 + d * 128 + o] = s;
}

__global__ void k_combine_bias(const float* __restrict__ ipb, const float* __restrict__ opb,
                               const float* __restrict__ opw, char* __restrict__ wsb) {
  float* cb = (float*)(wsb + OFF_CB);
  int t = blockIdx.x * 256 + threadIdx.x;
  int i = t >> 7, o = t & 127;
  const float* op = opw + i * 16384 + o * 128;
  const float* ib = ipb + i * 384 + 256;
  float s = opb[i * 128 + o];
#pragma unroll 4
  for (int m = 0; m < 128; ++m) s = fmaf(op[m], ib[m], s);
  cb[t] = s;
}

// hi/lo bf16 pack for MFMA (fast path)
__global__ void k_mt_hl(const float* __restrict__ tm_w, char* __restrict__ wsb) {
  const float* cw = (const float*)(wsb + OFF_CW);
  unsigned short* dh = (unsigned short*)(wsb + OFF_MTH);
  unsigned short* dl = (unsigned short*)(wsb + OFF_MTL);
  int n = blockIdx.x * 256 + threadIdx.x;  // 768*256
  int k = n >> 8, c = n & 255;
  const float* p = cw + ((c >> 7) ? 3 : 0) * 16384 + (c & 127);
  float s = 0.f;
#pragma unroll 4
  for (int d = 0; d < 128; ++d) s = fmaf(p[d * 128], tm_w[d * 768 + k], s);
  unsigned short h, l;
  split2(s, h, l);
  int ofs = (((k >> 3) * 256 + c) << 3) + (k & 7);
  dh[ofs] = h;
  dl[ofs] = l;
}

__global__ void k_mu_hl(const float* __restrict__ um_w, char* __restrict__ wsb) {
  const float* cw = (const float*)(wsb + OFF_CW);
  unsigned short* dh = (unsigned short*)(wsb + OFF_MUH);
  unsigned short* dl = (unsigned short*)(wsb + OFF_MUL);
  int n = blockIdx.x * 256 + threadIdx.x;  // 256*256
  int k = n >> 8, c = n & 255;
  const float* p = cw + ((c >> 7) ? 1 : 2) * 16384 + (c & 127);
  float s = 0.f;
#pragma unroll 4
  for (int d = 0; d < 128; ++d) s = fmaf(p[d * 128], um_w[d * 256 + k], s);
  unsigned short h, l;
  split2(s, h, l);
  int ofs = (((k >> 3) * 256 + c) << 3) + (k & 7);
  dh[ofs] = h;
  dl[ofs] = l;
}

// f32 [K/4][256][4] packs (fallback scalar path)
__global__ void k_mt4(const float* __restrict__ tm_w, char* __restrict__ wsb) {
  const float* cw = (const float*)(wsb + OFF_CW);
  float* dst = (float*)(wsb + OFF_MT4);
  int n = blockIdx.x * 256 + threadIdx.x;  // 768*256
  int k = n >> 8, c = n & 255;
  const float* p = cw + ((c >> 7) ? 3 : 0) * 16384 + (c & 127);
  float s = 0.f;
#pragma unroll 4
  for (int d = 0; d < 128; ++d) s = fmaf(p[d * 128], tm_w[d * 768 + k], s);
  dst[(((k >> 2) * 256 + c) << 2) + (k & 3)] = s;
}

__global__ void k_mu4(const float* __restrict__ um_w, char* __restrict__ wsb) {
  const float* cw = (const float*)(wsb + OFF_CW);
  float* dst = (float*)(wsb + OFF_MU4);
  int n = blockIdx.x * 256 + threadIdx.x;  // 256*256
  int k = n >> 8, c = n & 255;
  const float* p = cw + ((c >> 7) ? 1 : 2) * 16384 + (c & 127);
  float s = 0.f;
#pragma unroll 4
  for (int d = 0; d < 128; ++d) s = fmaf(p[d * 128], um_w[d * 256 + k], s);
  dst[(((k >> 2) * 256 + c) << 2) + (k & 3)] = s;
}

__global__ void k_bias_tu(const float* __restrict__ tm_b, const float* __restrict__ um_b,
                          char* __restrict__ wsb) {
  const float* cw = (const float*)(wsb + OFF_CW);
  const float* cb = (const float*)(wsb + OFF_CB);
  float* bT = (float*)(wsb + OFF_BT);
  float* bU = (float*)(wsb + OFF_BU);
  int t = blockIdx.x * 256 + threadIdx.x;
  if (t < 256) {
    int sel = (t >> 7) ? 3 : 0;
    const float* p = cw + sel * 16384 + (t & 127);
    float s = cb[sel * 128 + (t & 127)];
#pragma unroll 4
    for (int d = 0; d < 128; ++d) s = fmaf(p[d * 128], tm_b[d], s);
    bT[t] = s;
  } else {
    int c = t - 256;
    int sel = (c >> 7) ? 1 : 2;
    const float* p = cw + sel * 16384 + (c & 127);
    float s = cb[sel * 128 + (c & 127)];
#pragma unroll 4
    for (int d = 0; d < 128; ++d) s = fmaf(p[d * 128], um_b[d], s);
    bU[c] = s;
  }
}

// combined gate pack: cols 0..127 = tg_w, 128..255 = ug_w
__global__ void k_pack_gw4(const float* __restrict__ tg_w, const float* __restrict__ ug_w,
                           char* __restrict__ wsb) {
  float* dst = (float*)(wsb + OFF_GW4);
  int idx = blockIdx.x * 256 + threadIdx.x;  // 65536
  int j = idx >> 8, n = idx & 255;
  float v = (n < 128) ? tg_w[n * 256 + j] : ug_w[(n - 128) * 256 + j];
  dst[(((j >> 2) * 256 + n) << 2) + (j & 3)] = v;
}

// dst[((k>>2)*R + o)*4 + (k&3)] = src[o*C + k]
__global__ void k_transpose4(const float* __restrict__ src, float* __restrict__ dst,
                             int R, int C) {
  int n = blockIdx.x * 256 + threadIdx.x;
  if (n >= R * C) return;
  int o = n / C, k = n % C;
  dst[(((k >> 2) * R + o) << 2) + (k & 3)] = src[n];
}

// ---------------- kA: MFMA stages 1/2 -> global S, M=32, K-halved staging ----------------
// 512 threads = 8 waves, 32 rows/block (2048 blocks), 64 KB LDS.
// Per pass p: stage xt[32][p*384..+384) hi/lo (48KB: [32][768 B] each) +
// xu[32][p*128..+128) hi/lo (16KB: [32][256 B] each); MFMA accumulates over
// that K-window. K ascending -> S bit-identical to R13/R14.
// STAGING STRIDE: each float4 -> ushort4 (8 bytes) -> b0 uses rem*8 (R15 bug
// was rem*16: row overrun -> garbage S).

#define SWZ(byte, row) ((byte) ^ (((row) & 7) << 4))

__launch_bounds__(512)
__global__ void k_s12(const float* __restrict__ xt_g, const float* __restrict__ xu_g,
                      const char* __restrict__ wsb, float* __restrict__ Sg) {
  __shared__ __align__(16) char sm[65536];
  constexpr int XTL = 24576;   // xt lo   (xt hi at 0; [32][384] bf16 = 24576 B each)
  constexpr int XUH = 49152;   // xu hi   ([32][128] bf16 = 8192 B each)
  constexpr int XUL = 57344;   // xu lo

  const int t = threadIdx.x;
  const int wave = t >> 6, lane = t & 63;
  const int lrow = lane & 15;
  const int lk8 = lane >> 4;
  const int n0w = wave * 32;
  const long row0 = (long)blockIdx.x * 32;

  const float* bT = (const float*)(wsb + OFF_BT);
  const float* bU = (const float*)(wsb + OFF_BU);

  floatx4 zero = {0.f, 0.f, 0.f, 0.f};
  floatx4 acc1[2][2] = {{zero, zero}, {zero, zero}};  // [rowgrp][nt]
  floatx4 acc2[2][2] = {{zero, zero}, {zero, zero}};

  for (int p = 0; p < 2; ++p) {
    if (p) __syncthreads();  // pass-0 LDS reads complete before overwrite

    // ---- stage xt K-window: 32 rows x 96 float4/row; ushort4 out -> rem*8 ----
#pragma unroll
    for (int it = 0; it < 6; ++it) {
      int idx = it * 512 + t;
      int row = idx / 96, rem = idx - row * 96;
      float4 v = *(const float4*)(xt_g + (row0 + row) * 768 + p * 384 + rem * 4);
      int b0 = row * 768 + rem * 8;
      ushort4 hh, ll;
      split2(v.x, hh.x, ll.x); split2(v.y, hh.y, ll.y);
      split2(v.z, hh.z, ll.z); split2(v.w, hh.w, ll.w);
      *(ushort4*)(sm + SWZ(b0, row)) = hh;
      *(ushort4*)(sm + XTL + SWZ(b0, row)) = ll;
    }
    // ---- stage xu K-window: 32 rows x 32 float4/row; ushort4 out -> rem*8 ----
#pragma unroll
    for (int it = 0; it < 2; ++it) {
      int idx = it * 512 + t;
      int row = idx >> 5, rem = idx & 31;
      float4 v = *(const float4*)(xu_g + (row0 + row) * 256 + p * 128 + rem * 4);
      int b0 = row * 256 + rem * 8;
      ushort4 hh, ll;
      split2(v.x, hh.x, ll.x); split2(v.y, hh.y, ll.y);
      split2(v.z, hh.z, ll.z); split2(v.w, hh.w, ll.w);
      *(ushort4*)(sm + XUH + SWZ(b0, row)) = hh;
      *(ushort4*)(sm + XUL + SWZ(b0, row)) = ll;
    }
    __syncthreads();

    // ---- stage 1 MFMA over this K-window (12 chunks of 32) ----
    {
      const char* wh = wsb + OFF_MTH;
      const char* wl = wsb + OFF_MTL;
#pragma unroll 4
      for (int kk = 0; kk < 384; kk += 32) {
        int kb = (kk + lk8 * 8) * 2;
        int k8 = ((p * 384 + kk) >> 3) + lk8;
        int o0 = (k8 * 256 + n0w + lrow) << 4;
        int o1 = (k8 * 256 + n0w + 16 + lrow) << 4;
        short8v bh0 = *(const short8v*)(wh + o0);
        short8v bh1 = *(const short8v*)(wh + o1);
        short8v bl0 = *(const short8v*)(wl + o0);
        short8v bl1 = *(const short8v*)(wl + o1);
#pragma unroll
        for (int rg = 0; rg < 2; ++rg) {
          int ar = rg * 16 + lrow;
          short8v ah = *(const short8v*)(sm + SWZ(ar * 768 + kb, ar));
          short8v al = *(const short8v*)(sm + XTL + SWZ(ar * 768 + kb, ar));
          acc1[rg][0] = __builtin_amdgcn_mfma_f32_16x16x32_bf16(ah, bh0, acc1[rg][0], 0, 0, 0);
          acc1[rg][0] = __builtin_amdgcn_mfma_f32_16x16x32_bf16(ah, bl0, acc1[rg][0], 0, 0, 0);
          acc1[rg][0] = __builtin_amdgcn_mfma_f32_16x16x32_bf16(al, bh0, acc1[rg][0], 0, 0, 0);
          acc1[rg][1] = __builtin_amdgcn_mfma_f32_16x16x32_bf16(ah, bh1, acc1[rg][1], 0, 0, 0);
          acc1[rg][1] = __builtin_amdgcn_mfma_f32_16x16x32_bf16(ah, bl1, acc1[rg][1], 0, 0, 0);
          acc1[rg][1] = __builtin_amdgcn_mfma_f32_16x16x32_bf16(al, bh1, acc1[rg][1], 0, 0, 0);
        }
      }
    }
    // ---- stage 2 MFMA over this K-window (4 chunks of 32) ----
    {
      const char* wh = wsb + OFF_MUH;
      const char* wl = wsb + OFF_MUL;
#pragma unroll
      for (int kk = 0; kk < 128; kk += 32) {
        int kb = (kk + lk8 * 8) * 2;
        int k8 = ((p * 128 + kk) >> 3) + lk8;
        int o0 = (k8 * 256 + n0w + lrow) << 4;
        int o1 = (k8 * 256 + n0w + 16 + lrow) << 4;
        short8v bh0 = *(const short8v*)(wh + o0);
        short8v bh1 = *(const short8v*)(wh + o1);
        short8v bl0 = *(const short8v*)(wl + o0);
        short8v bl1 = *(const short8v*)(wl + o1);
#pragma unroll
        for (int rg = 0; rg < 2; ++rg) {
          int ar = rg * 16 + lrow;
          short8v ah = *(const short8v*)(sm + XUH + SWZ(ar * 256 + kb, ar));
          short8v al = *(const short8v*)(sm + XUL + SWZ(ar * 256 + kb, ar));
          acc2[rg][0] = __builtin_amdgcn_mfma_f32_16x16x32_bf16(ah, bh0, acc2[rg][0], 0, 0, 0);
          acc2[rg][0] = __builtin_amdgcn_mfma_f32_16x16x32_bf16(ah, bl0, acc2[rg][0], 0, 0, 0);
          acc2[rg][0] = __builtin_amdgcn_mfma_f32_16x16x32_bf16(al, bh0, acc2[rg][0], 0, 0, 0);
          acc2[rg][1] = __builtin_amdgcn_mfma_f32_16x16x32_bf16(ah, bh1, acc2[rg][1], 0, 0, 0);
          acc2[rg][1] = __builtin_amdgcn_mfma_f32_16x16x32_bf16(ah, bl1, acc2[rg][1], 0, 0, 0);
          acc2[rg][1] = __builtin_amdgcn_mfma_f32_16x16x32_bf16(al, bh1, acc2[rg][1], 0, 0, 0);
        }
      }
    }
  }

  // ---- epilogue: acc+bias -> GLOBAL S (quarantine-compliant) ----
  // C/D map: row = rg*16 + lk8*4 + reg, col = n0w + nt*16 + lrow.
#pragma unroll
  for (int rg = 0; rg < 2; ++rg)
#pragma unroll
    for (int nt = 0; nt < 2; ++nt) {
      int n = n0w + nt * 16 + lrow;
      float bvT = bT[n], bvU = bU[n];
      int scolT = (n < 128) ? n : 256 + n;  // ts | uc
      int scolU = 128 + n;                  // tc | us
#pragma unroll
      for (int reg = 0; reg < 4; ++reg) {
        long grow = row0 + rg * 16 + lk8 * 4 + reg;
        Sg[grow * 512 + scolT] = acc1[rg][nt][reg] + bvT;
        Sg[grow * 512 + scolU] = acc2[rg][nt][reg] + bvU;
      }
    }
}

// ---------------- kB: gates/mix/ff/LN from global S — 4 rows x 4 cols per thread ----------------
// 256 threads, 16 rows/block (4096 blocks), 48 KB LDS.
// thread: rg = t>>6 (4-row group), c0 = (t&63)*4 (4 adjacent cols).
// Per j-step: 4 ds_read + 4 wloads per 64 FMA.

__launch_bounds__(256)
__global__ void k_gfl3(const float* __restrict__ Sg, const char* __restrict__ wsb,
                       const float* __restrict__ tg_b, const float* __restrict__ ug_b,
                       const float* __restrict__ ff_b, const float* __restrict__ ln_g,
                       const float* __restrict__ ln_b, float* __restrict__ out) {
  __shared__ float lds[16 * 512 + 16 * 256];  // S 32KB + F 16KB = 48KB
  float* S = lds;             // [16][512]
  float* F = lds + 8192;      // [16][256]
  float* H = lds;             // [16][256] overlays S (dead after phase 3)

  const int t = threadIdx.x;
  const long row0 = (long)blockIdx.x * 16;

  // ---- stage S from global (coalesced): 2048 float4 ----
  {
    const float4* g = (const float4*)(Sg + row0 * 512);
    float4* l = (float4*)S;
#pragma unroll
    for (int it = 0; it < 8; ++it) l[it * 256 + t] = g[it * 256 + t];
  }
  __syncthreads();

  const int rg = t >> 6, r0 = rg * 4;
  const int c0 = (t & 63) * 4;

  // ---- phase 3: gates + mix -> F ----
  {
    const int so3 = (c0 < 128) ? 0 : 256;  // tg: [ts|tc]; ug: [us|uc]
    const float4* GW = (const float4*)(wsb + OFF_GW4);
    float acc[4][4] = {};
    for (int j = 0; j < 256; j += 4) {
      float4 w0 = GW[(j >> 2) * 256 + c0];
      float4 w1 = GW[(j >> 2) * 256 + c0 + 1];
      float4 w2 = GW[(j >> 2) * 256 + c0 + 2];
      float4 w3 = GW[(j >> 2) * 256 + c0 + 3];
#pragma unroll
      for (int r = 0; r < 4; ++r) {
        float4 sv = *(const float4*)&S[(r0 + r) * 512 + so3 + j];  // broadcast
        acc[r][0] = fmaf(sv.x, w0.x, fmaf(sv.y, w0.y, fmaf(sv.z, w0.z, fmaf(sv.w, w0.w, acc[r][0]))));
        acc[r][1] = fmaf(sv.x, w1.x, fmaf(sv.y, w1.y, fmaf(sv.z, w1.z, fmaf(sv.w, w1.w, acc[r][1]))));
        acc[r][2] = fmaf(sv.x, w2.x, fmaf(sv.y, w2.y, fmaf(sv.z, w2.z, fmaf(sv.w, w2.w, acc[r][2]))));
        acc[r][3] = fmaf(sv.x, w3.x, fmaf(sv.y, w3.y, fmaf(sv.z, w3.z, fmaf(sv.w, w3.w, acc[r][3]))));
      }
    }
    float gb[4];
#pragma unroll
    for (int c = 0; c < 4; ++c)
      gb[c] = (c0 < 128) ? tg_b[c0 + c] : ug_b[c0 + c - 128];
    int am = (c0 < 128) ? c0 : 128 + c0;  // self col in S
#pragma unroll
    for (int r = 0; r < 4; ++r) {
      int row = r0 + r;
#pragma unroll
      for (int c = 0; c < 4; ++c) {
        float g = 1.f / (1.f + __expf(-(acc[r][c] + gb[c])));
        float a = S[row * 512 + am + c];
        float b = S[row * 512 + am + 128 + c];
        F[row * 256 + c0 + c] = fmaf(g, b - a, a);
      }
    }
  }
  __syncthreads();

  // ---- phase 4: ff GEMM -> H (overlays dead S) ----
  {
    const float4* FW = (const float4*)(wsb + OFF_FW4);
    float acc[4][4] = {};
    for (int j = 0; j < 256; j += 4) {
      float4 w0 = FW[(j >> 2) * 256 + c0];
      float4 w1 = FW[(j >> 2) * 256 + c0 + 1];
      float4 w2 = FW[(j >> 2) * 256 + c0 + 2];
      float4 w3 = FW[(j >> 2) * 256 + c0 + 3];
#pragma unroll
      for (int r = 0; r < 4; ++r) {
        float4 fv = *(const float4*)&F[(r0 + r) * 256 + j];  // broadcast
        acc[r][0] = fmaf(fv.x, w0.x, fmaf(fv.y, w0.y, fmaf(fv.z, w0.z, fmaf(fv.w, w0.w, acc[r][0]))));
        acc[r][1] = fmaf(fv.x, w1.x, fmaf(fv.y, w1.y, fmaf(fv.z, w1.z, fmaf(fv.w, w1.w, acc[r][1]))));
        acc[r][2] = fmaf(fv.x, w2.x, fmaf(fv.y, w2.y, fmaf(fv.z, w2.z, fmaf(fv.w, w2.w, acc[r][2]))));
        acc[r][3] = fmaf(fv.x, w3.x, fmaf(fv.y, w3.y, fmaf(fv.z, w3.z, fmaf(fv.w, w3.w, acc[r][3]))));
      }
    }
#pragma unroll
    for (int r = 0; r < 4; ++r) {
      int row = r0 + r;
#pragma unroll
      for (int c = 0; c < 4; ++c)
        H[row * 256 + c0 + c] = acc[r][c] + ff_b[c0 + c];
    }
  }
  __syncthreads();

  // ---- phase 5: LayerNorm + ReLU + store. 16 threads/row, 16 elems each ----
  {
    int r = t >> 4, q = t & 15;
    const float* Hr = H + r * 256 + q * 16;
    float4 hv[4];
    float s1 = 0.f, s2 = 0.f;
#pragma unroll
    for (int j = 0; j < 4; ++j) {
      hv[j] = *(const float4*)(Hr + j * 4);
      s1 += hv[j].x + hv[j].y + hv[j].z + hv[j].w;
      s2 += hv[j].x * hv[j].x + hv[j].y * hv[j].y + hv[j].z * hv[j].z + hv[j].w * hv[j].w;
    }
#pragma unroll
    for (int off = 1; off < 16; off <<= 1) {
      s1 += __shfl_xor(s1, off);
      s2 += __shfl_xor(s2, off);
    }
    float mu = s1 * (1.f / 256.f);
    float var = s2 * (1.f / 256.f) - mu * mu;
    float rstd = rsqrtf(var + 1e-5f);
    float* op = out + (row0 + r) * 256 + q * 16;
#pragma unroll
    for (int j = 0; j < 4; ++j) {
      const float* gp = ln_g + q * 16 + j * 4;
      const float* bp = ln_b + q * 16 + j * 4;
      float4 o;
      o.x = fmaf((hv[j].x - mu) * rstd, gp[0], bp[0]);
      o.y = fmaf((hv[j].y - mu) * rstd, gp[1], bp[1]);
      o.z = fmaf((hv[j].z - mu) * rstd, gp[2], bp[2]);
      o.w = fmaf((hv[j].w - mu) * rstd, gp[3], bp[3]);
      o.x = o.x > 0.f ? o.x : 0.f;
      o.y = o.y > 0.f ? o.y : 0.f;
      o.z = o.z > 0.f ? o.z : 0.f;
      o.w = o.w > 0.f ? o.w : 0.f;
      *(float4*)(op + j * 4) = o;
    }
  }
}

// ---------------- fallback: R5 fused scalar kernel (GW4-adapted; known-pass) ----------------

__launch_bounds__(256)
__global__ void k_main5(const float* __restrict__ xt_g, const float* __restrict__ xu_g,
                        const char* __restrict__ wsb,
                        const float* __restrict__ tg_b, const float* __restrict__ ug_b,
                        const float* __restrict__ ff_b, const float* __restrict__ ln_g,
                        const float* __restrict__ ln_b, float* __restrict__ out) {
  __shared__ float lds[8 * 768 + 8 * 512 + 8 * 256];  // 48 KB
  float* xt = lds;
  float* S = lds + 8 * 768;
  float* xu = lds + 8 * 768 + 8 * 512;

  const int t = threadIdx.x;
  const long row0 = (long)blockIdx.x * 8;

  {
    const float4* g = (const float4*)(xt_g + row0 * 768);
    float4* l = (float4*)xt;
#pragma unroll
    for (int it = 0; it < 6; ++it) l[it * 256 + t] = g[it * 256 + t];
    const float4* gu = (const float4*)(xu_g + row0 * 256);
    float4* lu = (float4*)xu;
#pragma unroll
    for (int it = 0; it < 2; ++it) lu[it * 256 + t] = gu[it * 256 + t];
  }
  __syncthreads();

  {
    const float4* W4 = (const float4*)(wsb + OFF_MT4);
    float acc[8];
#pragma unroll
    for (int r = 0; r < 8; ++r) acc[r] = 0.f;
    for (int k = 0; k < 768; k += 4) {
      float4 w = W4[(k >> 2) * 256 + t];
#pragma unroll
      for (int r = 0; r < 8; ++r) {
        float4 xv = *(const float4*)&xt[r * 768 + k];
        acc[r] = fmaf(w.x, xv.x, acc[r]);
        acc[r] = fmaf(w.y, xv.y, acc[r]);
        acc[r] = fmaf(w.z, xv.z, acc[r]);
        acc[r] = fmaf(w.w, xv.w, acc[r]);
      }
    }
    float bias = ((const float*)(wsb + OFF_BT))[t];
    int d = (t < 128) ? t : (256 + t);
#pragma unroll
    for (int r = 0; r < 8; ++r) S[r * 512 + d] = acc[r] + bias;
  }

  {
    const float4* W4 = (const float4*)(wsb + OFF_MU4);
    float acc[8];
#pragma unroll
    for (int r = 0; r < 8; ++r) acc[r] = 0.f;
    for (int k = 0; k < 256; k += 4) {
      float4 w = W4[(k >> 2) * 256 + t];
#pragma unroll
      for (int r = 0; r < 8; ++r) {
        float4 xv = *(const float4*)&xu[r * 256 + k];
        acc[r] = fmaf(w.x, xv.x, acc[r]);
        acc[r] = fmaf(w.y, xv.y, acc[r]);
        acc[r] = fmaf(w.z, xv.z, acc[r]);
        acc[r] = fmaf(w.w, xv.w, acc[r]);
      }
    }
    float bias = ((const float*)(wsb + OFF_BU))[t];
#pragma unroll
    for (int r = 0; r < 8; ++r) S[r * 512 + 128 + t] = acc[r] + bias;
  }
  __syncthreads();

  {
    int c = t & 127, half = t >> 7;
    const float4* W4 = (const float4*)(wsb + OFF_GW4);
    const int wcol = half * 128 + c;
    const int so = half * 256;
    float acc[8];
#pragma unroll
    for (int r = 0; r < 8; ++r) acc[r] = 0.f;
    for (int j = 0; j < 256; j += 4) {
      float4 w = W4[(j >> 2) * 256 + wcol];
#pragma unroll
      for (int r = 0; r < 8; ++r) {
        float4 sv = *(const float4*)&S[r * 512 + so + j];
        acc[r] = fmaf(w.x, sv.x, acc[r]);
        acc[r] = fmaf(w.y, sv.y, acc[r]);
        acc[r] = fmaf(w.z, sv.z, acc[r]);
        acc[r] = fmaf(w.w, sv.w, acc[r]);
      }
    }
    float gb = half ? ug_b[c] : tg_b[c];
    float* F = xu;
#pragma unroll
    for (int r = 0; r < 8; ++r) {
      float g = 1.f / (1.f + __expf(-(acc[r] + gb)));
      float a = S[r * 512 + so + c];
      float b = S[r * 512 + so + 128 + c];
      F[r * 256 + half * 128 + c] = fmaf(g, b - a, a);
    }
  }
  __syncthreads();

  {
    const float4* W4 = (const float4*)(wsb + OFF_FW4);
    const float* F = xu;
    float acc[8];
#pragma unroll
    for (int r = 0; r < 8; ++r) acc[r] = 0.f;
    for (int j = 0; j < 256; j += 4) {
      float4 w = W4[(j >> 2) * 256 + t];
#pragma unroll
      for (int r = 0; r < 8; ++r) {
        float4 fv = *(const float4*)&F[r * 256 + j];
        acc[r] = fmaf(w.x, fv.x, acc[r]);
        acc[r] = fmaf(w.y, fv.y, acc[r]);
        acc[r] = fmaf(w.z, fv.z, acc[r]);
        acc[r] = fmaf(w.w, fv.w, acc[r]);
      }
    }
    float* H = xt;
    float bias = ff_b[t];
#pragma unroll
    for (int r = 0; r < 8; ++r) H[r * 256 + t] = acc[r] + bias;
  }
  __syncthreads();

  {
    const float* H = xt;
    int r = t >> 5, q = t & 31;
    const float* Hr = H + r * 256 + q * 8;
    float s1 = 0.f, s2 = 0.f;
#pragma unroll
    for (int i = 0; i < 8; ++i) {
      float v = Hr[i];
      s1 += v;
      s2 += v * v;
    }
#pragma unroll
    for (int off = 1; off < 32; off <<= 1) {
      s1 += __shfl_xor(s1, off);
      s2 += __shfl_xor(s2, off);
    }
    float mu = s1 * (1.f / 256.f);
    float var = s2 * (1.f / 256.f) - mu * mu;
    float rstd = rsqrtf(var + 1e-5f);
    float* op = out + (row0 + r) * 256 + q * 8;
#pragma unroll
    for (int i = 0; i < 8; ++i) {
      float v = (Hr[i] - mu) * rstd * ln_g[q * 8 + i] + ln_b[q * 8 + i];
      op[i] = v > 0.f ? v : 0.f;
    }
  }
}

}  // namespace

extern "C" void kernel_launch(void* const* d_in, const int* in_sizes, int n_in,
                              void* d_out, int out_size, void* d_ws, size_t ws_size,
                              hipStream_t stream) {
  const float* text = (const float*)d_in[0];
  const float* user = (const float*)d_in[1];
  const float* tm_w = (const float*)d_in[2];
  const float* tm_b = (const float*)d_in[3];
  const float* um_w = (const float*)d_in[4];
  const float* um_b = (const float*)d_in[5];
  const float* ipw = (const float*)d_in[6];
  const float* ipb = (const float*)d_in[7];
  const float* opw = (const float*)d_in[8];
  const float* opb = (const float*)d_in[9];
  const float* tg_w = (const float*)d_in[10];
  const float* tg_b = (const float*)d_in[11];
  const float* ug_w = (const float*)d_in[12];
  const float* ug_b = (const float*)d_in[13];
  const float* ff_w = (const float*)d_in[14];
  const float* ff_b = (const float*)d_in[15];
  const float* ln_g = (const float*)d_in[16];
  const float* ln_b = (const float*)d_in[17];
  char* wsb = (char*)d_ws;
  float* out = (float*)d_out;

  // common precompute
  k_combine<<<256, 256, 0, stream>>>(ipw, opw, wsb);
  k_combine_bias<<<2, 256, 0, stream>>>(ipb, opb, opw, wsb);
  k_bias_tu<<<2, 256, 0, stream>>>(tm_b, um_b, wsb);
  k_pack_gw4<<<256, 256, 0, stream>>>(tg_w, ug_w, wsb);
  k_transpose4<<<256, 256, 0, stream>>>(ff_w, (float*)(wsb + OFF_FW4), 256, 256);

  if ((long)ws_size >= WS_NEED) {
    // fast path: MFMA front (M=32, K-halved staging) -> global S -> 4x4 scalar back
    float* Sg = (float*)(wsb + OFF_S);
    k_mt_hl<<<768, 256, 0, stream>>>(tm_w, wsb);
    k_mu_hl<<<256, 256, 0, stream>>>(um_w, wsb);
    k_s12<<<2048, 512, 0, stream>>>(text, user, wsb, Sg);
    k_gfl3<<<4096, 256, 0, stream>>>(Sg, wsb, tg_b, ug_b, ff_b, ln_g, ln_b, out);
  } else {
    // fallback: R5 fused scalar (known-pass)
    k_mt4<<<768, 256, 0, stream>>>(tm_w, wsb);
    k_mu4<<<256, 256, 0, stream>>>(um_w, wsb);
    k_main5<<<8192, 256, 0, stream>>>(text, user, wsb, tg_b, ug_b, ff_b, ln_g, ln_b, out);
  }
}

// Round 17
// 660.221 us; speedup vs baseline: 1.1285x; 1.1285x over previous
//
#include <hip/hip_runtime.h>
#include <hip/hip_bf16.h>

// MultiViewFusion — two-kernel split, round 17.
// Evidence ledger:
//   R5  PASS 0.0156 (1338us): scalar-f32 fused (folding algebra correct).
//   R6-R9 FAIL: MFMA acc->LDS->read corrupts. QUARANTINE: acc exits only via
//        VALU->global store. (Scalar-computed values in LDS are fine.)
//   R10 PASS + zero poisons: MFMA stages 1/2 coordinate-exact.
//   R13 PASS 646us. R14 PASS 547us: k_gfl2 2-col = 285us (VALU 73%).
//   R15 FAIL (staging stride bug). R16 PASS 745us: k_s12 M=32 = ~150us
//        (validated; L2-amortization works) but k_gfl3 4x4 = 565us REGRESSION
//        (strided weight loads + 8-way bank conflicts; VALU 35%).
// R17: k_s12 R16-verbatim + kB = R14's 2-col structure WITHOUT S LDS staging:
//      GEMM K-loop reads S wave-uniform direct from global (L1 broadcast),
//      mix reads coalesced direct from global. LDS = F+H only (32KB) ->
//      occupancy ~2x. FMA order identical to R14 -> bit-identical output.

namespace {

typedef __attribute__((ext_vector_type(8))) short short8v;   // 8 bf16 = 4 VGPR
typedef __attribute__((ext_vector_type(4))) float floatx4;   // MFMA C/D

// workspace byte offsets (unchanged from R13..R16)
constexpr int OFF_CW  = 0;        // f32 CWt[4][128][128]
constexpr int OFF_CB  = 262144;   // f32 cv[4][128]
constexpr int OFF_BT  = 264192;   // f32 bT[256]  [ts|uc]
constexpr int OFF_BU  = 265216;   // f32 bU[256]  [tc|us]
constexpr int OFF_MTH = 266240;   // bf16 M_text hi packed [96][256][8]
constexpr int OFF_MTL = 659456;   // bf16 M_text lo
constexpr int OFF_MUH = 1052672;  // bf16 M_user hi packed [32][256][8]
constexpr int OFF_MUL = 1183744;  // bf16 M_user lo
constexpr int OFF_GW4 = 1314816;  // f32 gate W [64][256][4] (cols tg|ug)
constexpr int OFF_FW4 = 1576960;  // f32 ff  W  [64][256][4]
constexpr int OFF_MT4 = 1839104;  // f32 M_text pack [192][256][4]  (fallback)
constexpr int OFF_MU4 = 2625536;  // f32 M_user pack [64][256][4]   (fallback)
constexpr long OFF_S  = 2887680;  // f32 S [65536][512] = 134217728 B
constexpr long WS_NEED = OFF_S + 134217728L;

__device__ inline unsigned short f2b(float f) {
  __hip_bfloat16 h = __float2bfloat16(f);
  return __builtin_bit_cast(unsigned short, h);
}
__device__ inline float b2f(unsigned short u) {
  unsigned int v = ((unsigned int)u) << 16;
  return __builtin_bit_cast(float, v);
}
__device__ inline void split2(float v, unsigned short& h, unsigned short& l) {
  h = f2b(v);
  l = f2b(v - b2f(h));
}

// ---------------- precompute (tiny, L2-resident; validated) ----------------

__global__ void k_combine(const float* __restrict__ ipw, const float* __restrict__ opw,
                          char* __restrict__ wsb) {
  float* cw = (float*)(wsb + OFF_CW);
  int n = blockIdx.x * 256 + threadIdx.x;
  int i = n >> 14, o = (n >> 7) & 127, d = n & 127;
  const float* op = opw + i * 16384 + o * 128;
  const float* iv = ipw + i * 49152 + 256 * 128 + d;
  float s = 0.f;
#pragma unroll 4
  for (int m = 0; m < 128; ++m) s = fmaf(op[m], iv[m * 128], s);
  cw[i * 16384 + d * 128 + o] = s;
}

__global__ void k_combine_bias(const float* __restrict__ ipb, const float* __restrict__ opb,
                               const float* __restrict__ opw, char* __restrict__ wsb) {
  float* cb = (float*)(wsb + OFF_CB);
  int t = blockIdx.x * 256 + threadIdx.x;
  int i = t >> 7, o = t & 127;
  const float* op = opw + i * 16384 + o * 128;
  const float* ib = ipb + i * 384 + 256;
  float s = opb[i * 128 + o];
#pragma unroll 4
  for (int m = 0; m < 128; ++m) s = fmaf(op[m], ib[m], s);
  cb[t] = s;
}

// hi/lo bf16 pack for MFMA (fast path)
__global__ void k_mt_hl(const float* __restrict__ tm_w, char* __restrict__ wsb) {
  const float* cw = (const float*)(wsb + OFF_CW);
  unsigned short* dh = (unsigned short*)(wsb + OFF_MTH);
  unsigned short* dl = (unsigned short*)(wsb + OFF_MTL);
  int n = blockIdx.x * 256 + threadIdx.x;  // 768*256
  int k = n >> 8, c = n & 255;
  const float* p = cw + ((c >> 7) ? 3 : 0) * 16384 + (c & 127);
  float s = 0.f;
#pragma unroll 4
  for (int d = 0; d < 128; ++d) s = fmaf(p[d * 128], tm_w[d * 768 + k], s);
  unsigned short h, l;
  split2(s, h, l);
  int ofs = (((k >> 3) * 256 + c) << 3) + (k & 7);
  dh[ofs] = h;
  dl[ofs] = l;
}

__global__ void k_mu_hl(const float* __restrict__ um_w, char* __restrict__ wsb) {
  const float* cw = (const float*)(wsb + OFF_CW);
  unsigned short* dh = (unsigned short*)(wsb + OFF_MUH);
  unsigned short* dl = (unsigned short*)(wsb + OFF_MUL);
  int n = blockIdx.x * 256 + threadIdx.x;  // 256*256
  int k = n >> 8, c = n & 255;
  const float* p = cw + ((c >> 7) ? 1 : 2) * 16384 + (c & 127);
  float s = 0.f;
#pragma unroll 4
  for (int d = 0; d < 128; ++d) s = fmaf(p[d * 128], um_w[d * 256 + k], s);
  unsigned short h, l;
  split2(s, h, l);
  int ofs = (((k >> 3) * 256 + c) << 3) + (k & 7);
  dh[ofs] = h;
  dl[ofs] = l;
}

// f32 [K/4][256][4] packs (fallback scalar path)
__global__ void k_mt4(const float* __restrict__ tm_w, char* __restrict__ wsb) {
  const float* cw = (const float*)(wsb + OFF_CW);
  float* dst = (float*)(wsb + OFF_MT4);
  int n = blockIdx.x * 256 + threadIdx.x;  // 768*256
  int k = n >> 8, c = n & 255;
  const float* p = cw + ((c >> 7) ? 3 : 0) * 16384 + (c & 127);
  float s = 0.f;
#pragma unroll 4
  for (int d = 0; d < 128; ++d) s = fmaf(p[d * 128], tm_w[d * 768 + k], s);
  dst[(((k >> 2) * 256 + c) << 2) + (k & 3)] = s;
}

__global__ void k_mu4(const float* __restrict__ um_w, char* __restrict__ wsb) {
  const float* cw = (const float*)(wsb + OFF_CW);
  float* dst = (float*)(wsb + OFF_MU4);
  int n = blockIdx.x * 256 + threadIdx.x;  // 256*256
  int k = n >> 8, c = n & 255;
  const float* p = cw + ((c >> 7) ? 1 : 2) * 16384 + (c & 127);
  float s = 0.f;
#pragma unroll 4
  for (int d = 0; d < 128; ++d) s = fmaf(p[d * 128], um_w[d * 256 + k], s);
  dst[(((k >> 2) * 256 + c) << 2) + (k & 3)] = s;
}

__global__ void k_bias_tu(const float* __restrict__ tm_b, const float* __restrict__ um_b,
                          char* __restrict__ wsb) {
  const float* cw = (const float*)(wsb + OFF_CW);
  const float* cb = (const float*)(wsb + OFF_CB);
  float* bT = (float*)(wsb + OFF_BT);
  float* bU = (float*)(wsb + OFF_BU);
  int t = blockIdx.x * 256 + threadIdx.x;
  if (t < 256) {
    int sel = (t >> 7) ? 3 : 0;
    const float* p = cw + sel * 16384 + (t & 127);
    float s = cb[sel * 128 + (t & 127)];
#pragma unroll 4
    for (int d = 0; d < 128; ++d) s = fmaf(p[d * 128], tm_b[d], s);
    bT[t] = s;
  } else {
    int c = t - 256;
    int sel = (c >> 7) ? 1 : 2;
    const float* p = cw + sel * 16384 + (c & 127);
    float s = cb[sel * 128 + (c & 127)];
#pragma unroll 4
    for (int d = 0; d < 128; ++d) s = fmaf(p[d * 128], um_b[d], s);
    bU[c] = s;
  }
}

// combined gate pack: cols 0..127 = tg_w, 128..255 = ug_w
__global__ void k_pack_gw4(const float* __restrict__ tg_w, const float* __restrict__ ug_w,
                           char* __restrict__ wsb) {
  float* dst = (float*)(wsb + OFF_GW4);
  int idx = blockIdx.x * 256 + threadIdx.x;  // 65536
  int j = idx >> 8, n = idx & 255;
  float v = (n < 128) ? tg_w[n * 256 + j] : ug_w[(n - 128) * 256 + j];
  dst[(((j >> 2) * 256 + n) << 2) + (j & 3)] = v;
}

// dst[((k>>2)*R + o)*4 + (k&3)] = src[o*C + k]
__global__ void k_transpose4(const float* __restrict__ src, float* __restrict__ dst,
                             int R, int C) {
  int n = blockIdx.x * 256 + threadIdx.x;
  if (n >= R * C) return;
  int o = n / C, k = n % C;
  dst[(((k >> 2) * R + o) << 2) + (k & 3)] = src[n];
}

// ---------------- kA: MFMA stages 1/2 -> global S, M=32, K-halved staging ----------------
// (R16-verbatim; validated PASS, ~150us.)

#define SWZ(byte, row) ((byte) ^ (((row) & 7) << 4))

__launch_bounds__(512)
__global__ void k_s12(const float* __restrict__ xt_g, const float* __restrict__ xu_g,
                      const char* __restrict__ wsb, float* __restrict__ Sg) {
  __shared__ __align__(16) char sm[65536];
  constexpr int XTL = 24576;   // xt lo   (xt hi at 0; [32][384] bf16 = 24576 B each)
  constexpr int XUH = 49152;   // xu hi   ([32][128] bf16 = 8192 B each)
  constexpr int XUL = 57344;   // xu lo

  const int t = threadIdx.x;
  const int wave = t >> 6, lane = t & 63;
  const int lrow = lane & 15;
  const int lk8 = lane >> 4;
  const int n0w = wave * 32;
  const long row0 = (long)blockIdx.x * 32;

  const float* bT = (const float*)(wsb + OFF_BT);
  const float* bU = (const float*)(wsb + OFF_BU);

  floatx4 zero = {0.f, 0.f, 0.f, 0.f};
  floatx4 acc1[2][2] = {{zero, zero}, {zero, zero}};  // [rowgrp][nt]
  floatx4 acc2[2][2] = {{zero, zero}, {zero, zero}};

  for (int p = 0; p < 2; ++p) {
    if (p) __syncthreads();  // pass-0 LDS reads complete before overwrite

    // ---- stage xt K-window: 32 rows x 96 float4/row; ushort4 out -> rem*8 ----
#pragma unroll
    for (int it = 0; it < 6; ++it) {
      int idx = it * 512 + t;
      int row = idx / 96, rem = idx - row * 96;
      float4 v = *(const float4*)(xt_g + (row0 + row) * 768 + p * 384 + rem * 4);
      int b0 = row * 768 + rem * 8;
      ushort4 hh, ll;
      split2(v.x, hh.x, ll.x); split2(v.y, hh.y, ll.y);
      split2(v.z, hh.z, ll.z); split2(v.w, hh.w, ll.w);
      *(ushort4*)(sm + SWZ(b0, row)) = hh;
      *(ushort4*)(sm + XTL + SWZ(b0, row)) = ll;
    }
    // ---- stage xu K-window: 32 rows x 32 float4/row; ushort4 out -> rem*8 ----
#pragma unroll
    for (int it = 0; it < 2; ++it) {
      int idx = it * 512 + t;
      int row = idx >> 5, rem = idx & 31;
      float4 v = *(const float4*)(xu_g + (row0 + row) * 256 + p * 128 + rem * 4);
      int b0 = row * 256 + rem * 8;
      ushort4 hh, ll;
      split2(v.x, hh.x, ll.x); split2(v.y, hh.y, ll.y);
      split2(v.z, hh.z, ll.z); split2(v.w, hh.w, ll.w);
      *(ushort4*)(sm + XUH + SWZ(b0, row)) = hh;
      *(ushort4*)(sm + XUL + SWZ(b0, row)) = ll;
    }
    __syncthreads();

    // ---- stage 1 MFMA over this K-window (12 chunks of 32) ----
    {
      const char* wh = wsb + OFF_MTH;
      const char* wl = wsb + OFF_MTL;
#pragma unroll 4
      for (int kk = 0; kk < 384; kk += 32) {
        int kb = (kk + lk8 * 8) * 2;
        int k8 = ((p * 384 + kk) >> 3) + lk8;
        int o0 = (k8 * 256 + n0w + lrow) << 4;
        int o1 = (k8 * 256 + n0w + 16 + lrow) << 4;
        short8v bh0 = *(const short8v*)(wh + o0);
        short8v bh1 = *(const short8v*)(wh + o1);
        short8v bl0 = *(const short8v*)(wl + o0);
        short8v bl1 = *(const short8v*)(wl + o1);
#pragma unroll
        for (int rg = 0; rg < 2; ++rg) {
          int ar = rg * 16 + lrow;
          short8v ah = *(const short8v*)(sm + SWZ(ar * 768 + kb, ar));
          short8v al = *(const short8v*)(sm + XTL + SWZ(ar * 768 + kb, ar));
          acc1[rg][0] = __builtin_amdgcn_mfma_f32_16x16x32_bf16(ah, bh0, acc1[rg][0], 0, 0, 0);
          acc1[rg][0] = __builtin_amdgcn_mfma_f32_16x16x32_bf16(ah, bl0, acc1[rg][0], 0, 0, 0);
          acc1[rg][0] = __builtin_amdgcn_mfma_f32_16x16x32_bf16(al, bh0, acc1[rg][0], 0, 0, 0);
          acc1[rg][1] = __builtin_amdgcn_mfma_f32_16x16x32_bf16(ah, bh1, acc1[rg][1], 0, 0, 0);
          acc1[rg][1] = __builtin_amdgcn_mfma_f32_16x16x32_bf16(ah, bl1, acc1[rg][1], 0, 0, 0);
          acc1[rg][1] = __builtin_amdgcn_mfma_f32_16x16x32_bf16(al, bh1, acc1[rg][1], 0, 0, 0);
        }
      }
    }
    // ---- stage 2 MFMA over this K-window (4 chunks of 32) ----
    {
      const char* wh = wsb + OFF_MUH;
      const char* wl = wsb + OFF_MUL;
#pragma unroll
      for (int kk = 0; kk < 128; kk += 32) {
        int kb = (kk + lk8 * 8) * 2;
        int k8 = ((p * 128 + kk) >> 3) + lk8;
        int o0 = (k8 * 256 + n0w + lrow) << 4;
        int o1 = (k8 * 256 + n0w + 16 + lrow) << 4;
        short8v bh0 = *(const short8v*)(wh + o0);
        short8v bh1 = *(const short8v*)(wh + o1);
        short8v bl0 = *(const short8v*)(wl + o0);
        short8v bl1 = *(const short8v*)(wl + o1);
#pragma unroll
        for (int rg = 0; rg < 2; ++rg) {
          int ar = rg * 16 + lrow;
          short8v ah = *(const short8v*)(sm + XUH + SWZ(ar * 256 + kb, ar));
          short8v al = *(const short8v*)(sm + XUL + SWZ(ar * 256 + kb, ar));
          acc2[rg][0] = __builtin_amdgcn_mfma_f32_16x16x32_bf16(ah, bh0, acc2[rg][0], 0, 0, 0);
          acc2[rg][0] = __builtin_amdgcn_mfma_f32_16x16x32_bf16(ah, bl0, acc2[rg][0], 0, 0, 0);
          acc2[rg][0] = __builtin_amdgcn_mfma_f32_16x16x32_bf16(al, bh0, acc2[rg][0], 0, 0, 0);
          acc2[rg][1] = __builtin_amdgcn_mfma_f32_16x16x32_bf16(ah, bh1, acc2[rg][1], 0, 0, 0);
          acc2[rg][1] = __builtin_amdgcn_mfma_f32_16x16x32_bf16(ah, bl1, acc2[rg][1], 0, 0, 0);
          acc2[rg][1] = __builtin_amdgcn_mfma_f32_16x16x32_bf16(al, bh1, acc2[rg][1], 0, 0, 0);
        }
      }
    }
  }

  // ---- epilogue: acc+bias -> GLOBAL S (quarantine-compliant) ----
  // C/D map: row = rg*16 + lk8*4 + reg, col = n0w + nt*16 + lrow.
#pragma unroll
  for (int rg = 0; rg < 2; ++rg)
#pragma unroll
    for (int nt = 0; nt < 2; ++nt) {
      int n = n0w + nt * 16 + lrow;
      float bvT = bT[n], bvU = bU[n];
      int scolT = (n < 128) ? n : 256 + n;  // ts | uc
      int scolU = 128 + n;                  // tc | us
#pragma unroll
      for (int reg = 0; reg < 4; ++reg) {
        long grow = row0 + rg * 16 + lk8 * 4 + reg;
        Sg[grow * 512 + scolT] = acc1[rg][nt][reg] + bvT;
        Sg[grow * 512 + scolU] = acc2[rg][nt][reg] + bvU;
      }
    }
}

// ---------------- kB: gates/mix/ff/LN — R14 2-col structure, NO S staging ----------------
// 256 threads, 16 rows/block (4096 blocks), 32 KB LDS (F + H only).
// thread: rh = t>>7 (8-row half), c0 = (t&127)*2.
// GEMM K-loop reads S wave-uniform from GLOBAL (L1 broadcast); mix reads
// coalesced from GLOBAL. F/H (scalar-computed) live in LDS.

__launch_bounds__(256)
__global__ void k_gfl2b(const float* __restrict__ Sg, const char* __restrict__ wsb,
                        const float* __restrict__ tg_b, const float* __restrict__ ug_b,
                        const float* __restrict__ ff_b, const float* __restrict__ ln_g,
                        const float* __restrict__ ln_b, float* __restrict__ out) {
  __shared__ float lds[16 * 256 + 16 * 256];  // F 16KB + H 16KB = 32KB
  float* F = lds;             // [16][256]
  float* H = lds + 4096;      // [16][256]

  const int t = threadIdx.x;
  const long row0 = (long)blockIdx.x * 16;
  const float* Sb = Sg + row0 * 512;  // this block's 16 S rows

  const int rh = t >> 7, c0 = (t & 127) * 2;
  const int r0 = rh * 8;

  // ---- phase 3: gates + mix -> F (S read direct from global) ----
  {
    const int so3 = (c0 < 128) ? 0 : 256;  // tg: S[0:256]=[ts|tc]; ug: S[256:512]=[us|uc]
    const float4* GW = (const float4*)(wsb + OFF_GW4);
    float acc[8][2] = {};
    for (int j = 0; j < 256; j += 4) {
      float4 w0 = GW[(j >> 2) * 256 + c0];
      float4 w1 = GW[(j >> 2) * 256 + c0 + 1];
#pragma unroll
      for (int r = 0; r < 8; ++r) {
        float4 sv = *(const float4*)&Sb[(r0 + r) * 512 + so3 + j];  // wave-uniform
        acc[r][0] = fmaf(sv.x, w0.x, fmaf(sv.y, w0.y, fmaf(sv.z, w0.z, fmaf(sv.w, w0.w, acc[r][0]))));
        acc[r][1] = fmaf(sv.x, w1.x, fmaf(sv.y, w1.y, fmaf(sv.z, w1.z, fmaf(sv.w, w1.w, acc[r][1]))));
      }
    }
    float gb0 = (c0 < 128) ? tg_b[c0] : ug_b[c0 - 128];
    float gb1 = (c0 < 128) ? tg_b[c0 + 1] : ug_b[c0 - 127];
    int am = (c0 < 128) ? c0 : 128 + c0;  // self col in S
#pragma unroll
    for (int r = 0; r < 8; ++r) {
      int row = r0 + r;
      float g0 = 1.f / (1.f + __expf(-(acc[r][0] + gb0)));
      float g1 = 1.f / (1.f + __expf(-(acc[r][1] + gb1)));
      float a0 = Sb[row * 512 + am],     b0v = Sb[row * 512 + am + 128];
      float a1 = Sb[row * 512 + am + 1], b1v = Sb[row * 512 + am + 129];
      F[row * 256 + c0]     = fmaf(g0, b0v - a0, a0);
      F[row * 256 + c0 + 1] = fmaf(g1, b1v - a1, a1);
    }
  }
  __syncthreads();

  // ---- phase 4: ff GEMM -> H (F broadcast from LDS) ----
  {
    const float4* FW = (const float4*)(wsb + OFF_FW4);
    float acc[8][2] = {};
    for (int j = 0; j < 256; j += 4) {
      float4 w0 = FW[(j >> 2) * 256 + c0];
      float4 w1 = FW[(j >> 2) * 256 + c0 + 1];
#pragma unroll
      for (int r = 0; r < 8; ++r) {
        float4 fv = *(const float4*)&F[(r0 + r) * 256 + j];  // broadcast
        acc[r][0] = fmaf(fv.x, w0.x, fmaf(fv.y, w0.y, fmaf(fv.z, w0.z, fmaf(fv.w, w0.w, acc[r][0]))));
        acc[r][1] = fmaf(fv.x, w1.x, fmaf(fv.y, w1.y, fmaf(fv.z, w1.z, fmaf(fv.w, w1.w, acc[r][1]))));
      }
    }
    float fb0 = ff_b[c0], fb1 = ff_b[c0 + 1];
#pragma unroll
    for (int r = 0; r < 8; ++r) {
      int row = r0 + r;
      H[row * 256 + c0]     = acc[r][0] + fb0;
      H[row * 256 + c0 + 1] = acc[r][1] + fb1;
    }
  }
  __syncthreads();

  // ---- phase 5: LayerNorm + ReLU + store. 16 threads/row, 16 elems each ----
  {
    int r = t >> 4, q = t & 15;
    const float* Hr = H + r * 256 + q * 16;
    float4 hv[4];
    float s1 = 0.f, s2 = 0.f;
#pragma unroll
    for (int j = 0; j < 4; ++j) {
      hv[j] = *(const float4*)(Hr + j * 4);
      s1 += hv[j].x + hv[j].y + hv[j].z + hv[j].w;
      s2 += hv[j].x * hv[j].x + hv[j].y * hv[j].y + hv[j].z * hv[j].z + hv[j].w * hv[j].w;
    }
#pragma unroll
    for (int off = 1; off < 16; off <<= 1) {
      s1 += __shfl_xor(s1, off);
      s2 += __shfl_xor(s2, off);
    }
    float mu = s1 * (1.f / 256.f);
    float var = s2 * (1.f / 256.f) - mu * mu;
    float rstd = rsqrtf(var + 1e-5f);
    float* op = out + (row0 + r) * 256 + q * 16;
#pragma unroll
    for (int j = 0; j < 4; ++j) {
      const float* gp = ln_g + q * 16 + j * 4;
      const float* bp = ln_b + q * 16 + j * 4;
      float4 o;
      o.x = fmaf((hv[j].x - mu) * rstd, gp[0], bp[0]);
      o.y = fmaf((hv[j].y - mu) * rstd, gp[1], bp[1]);
      o.z = fmaf((hv[j].z - mu) * rstd, gp[2], bp[2]);
      o.w = fmaf((hv[j].w - mu) * rstd, gp[3], bp[3]);
      o.x = o.x > 0.f ? o.x : 0.f;
      o.y = o.y > 0.f ? o.y : 0.f;
      o.z = o.z > 0.f ? o.z : 0.f;
      o.w = o.w > 0.f ? o.w : 0.f;
      *(float4*)(op + j * 4) = o;
    }
  }
}

// ---------------- fallback: R5 fused scalar kernel (GW4-adapted; known-pass) ----------------

__launch_bounds__(256)
__global__ void k_main5(const float* __restrict__ xt_g, const float* __restrict__ xu_g,
                        const char* __restrict__ wsb,
                        const float* __restrict__ tg_b, const float* __restrict__ ug_b,
                        const float* __restrict__ ff_b, const float* __restrict__ ln_g,
                        const float* __restrict__ ln_b, float* __restrict__ out) {
  __shared__ float lds[8 * 768 + 8 * 512 + 8 * 256];  // 48 KB
  float* xt = lds;
  float* S = lds + 8 * 768;
  float* xu = lds + 8 * 768 + 8 * 512;

  const int t = threadIdx.x;
  const long row0 = (long)blockIdx.x * 8;

  {
    const float4* g = (const float4*)(xt_g + row0 * 768);
    float4* l = (float4*)xt;
#pragma unroll
    for (int it = 0; it < 6; ++it) l[it * 256 + t] = g[it * 256 + t];
    const float4* gu = (const float4*)(xu_g + row0 * 256);
    float4* lu = (float4*)xu;
#pragma unroll
    for (int it = 0; it < 2; ++it) lu[it * 256 + t] = gu[it * 256 + t];
  }
  __syncthreads();

  {
    const float4* W4 = (const float4*)(wsb + OFF_MT4);
    float acc[8];
#pragma unroll
    for (int r = 0; r < 8; ++r) acc[r] = 0.f;
    for (int k = 0; k < 768; k += 4) {
      float4 w = W4[(k >> 2) * 256 + t];
#pragma unroll
      for (int r = 0; r < 8; ++r) {
        float4 xv = *(const float4*)&xt[r * 768 + k];
        acc[r] = fmaf(w.x, xv.x, acc[r]);
        acc[r] = fmaf(w.y, xv.y, acc[r]);
        acc[r] = fmaf(w.z, xv.z, acc[r]);
        acc[r] = fmaf(w.w, xv.w, acc[r]);
      }
    }
    float bias = ((const float*)(wsb + OFF_BT))[t];
    int d = (t < 128) ? t : (256 + t);
#pragma unroll
    for (int r = 0; r < 8; ++r) S[r * 512 + d] = acc[r] + bias;
  }

  {
    const float4* W4 = (const float4*)(wsb + OFF_MU4);
    float acc[8];
#pragma unroll
    for (int r = 0; r < 8; ++r) acc[r] = 0.f;
    for (int k = 0; k < 256; k += 4) {
      float4 w = W4[(k >> 2) * 256 + t];
#pragma unroll
      for (int r = 0; r < 8; ++r) {
        float4 xv = *(const float4*)&xu[r * 256 + k];
        acc[r] = fmaf(w.x, xv.x, acc[r]);
        acc[r] = fmaf(w.y, xv.y, acc[r]);
        acc[r] = fmaf(w.z, xv.z, acc[r]);
        acc[r] = fmaf(w.w, xv.w, acc[r]);
      }
    }
    float bias = ((const float*)(wsb + OFF_BU))[t];
#pragma unroll
    for (int r = 0; r < 8; ++r) S[r * 512 + 128 + t] = acc[r] + bias;
  }
  __syncthreads();

  {
    int c = t & 127, half = t >> 7;
    const float4* W4 = (const float4*)(wsb + OFF_GW4);
    const int wcol = half * 128 + c;
    const int so = half * 256;
    float acc[8];
#pragma unroll
    for (int r = 0; r < 8; ++r) acc[r] = 0.f;
    for (int j = 0; j < 256; j += 4) {
      float4 w = W4[(j >> 2) * 256 + wcol];
#pragma unroll
      for (int r = 0; r < 8; ++r) {
        float4 sv = *(const float4*)&S[r * 512 + so + j];
        acc[r] = fmaf(w.x, sv.x, acc[r]);
        acc[r] = fmaf(w.y, sv.y, acc[r]);
        acc[r] = fmaf(w.z, sv.z, acc[r]);
        acc[r] = fmaf(w.w, sv.w, acc[r]);
      }
    }
    float gb = half ? ug_b[c] : tg_b[c];
    float* F = xu;
#pragma unroll
    for (int r = 0; r < 8; ++r) {
      float g = 1.f / (1.f + __expf(-(acc[r] + gb)));
      float a = S[r * 512 + so + c];
      float b = S[r * 512 + so + 128 + c];
      F[r * 256 + half * 128 + c] = fmaf(g, b - a, a);
    }
  }
  __syncthreads();

  {
    const float4* W4 = (const float4*)(wsb + OFF_FW4);
    const float* F = xu;
    float acc[8];
#pragma unroll
    for (int r = 0; r < 8; ++r) acc[r] = 0.f;
    for (int j = 0; j < 256; j += 4) {
      float4 w = W4[(j >> 2) * 256 + t];
#pragma unroll
      for (int r = 0; r < 8; ++r) {
        float4 fv = *(const float4*)&F[r * 256 + j];
        acc[r] = fmaf(w.x, fv.x, acc[r]);
        acc[r] = fmaf(w.y, fv.y, acc[r]);
        acc[r] = fmaf(w.z, fv.z, acc[r]);
        acc[r] = fmaf(w.w, fv.w, acc[r]);
      }
    }
    float* H = xt;
    float bias = ff_b[t];
#pragma unroll
    for (int r = 0; r < 8; ++r) H[r * 256 + t] = acc[r] + bias;
  }
  __syncthreads();

  {
    const float* H = xt;
    int r = t >> 5, q = t & 31;
    const float* Hr = H + r * 256 + q * 8;
    float s1 = 0.f, s2 = 0.f;
#pragma unroll
    for (int i = 0; i < 8; ++i) {
      float v = Hr[i];
      s1 += v;
      s2 += v * v;
    }
#pragma unroll
    for (int off = 1; off < 32; off <<= 1) {
      s1 += __shfl_xor(s1, off);
      s2 += __shfl_xor(s2, off);
    }
    float mu = s1 * (1.f / 256.f);
    float var = s2 * (1.f / 256.f) - mu * mu;
    float rstd = rsqrtf(var + 1e-5f);
    float* op = out + (row0 + r) * 256 + q * 8;
#pragma unroll
    for (int i = 0; i < 8; ++i) {
      float v = (Hr[i] - mu) * rstd * ln_g[q * 8 + i] + ln_b[q * 8 + i];
      op[i] = v > 0.f ? v : 0.f;
    }
  }
}

}  // namespace

extern "C" void kernel_launch(void* const* d_in, const int* in_sizes, int n_in,
                              void* d_out, int out_size, void* d_ws, size_t ws_size,
                              hipStream_t stream) {
  const float* text = (const float*)d_in[0];
  const float* user = (const float*)d_in[1];
  const float* tm_w = (const float*)d_in[2];
  const float* tm_b = (const float*)d_in[3];
  const float* um_w = (const float*)d_in[4];
  const float* um_b = (const float*)d_in[5];
  const float* ipw = (const float*)d_in[6];
  const float* ipb = (const float*)d_in[7];
  const float* opw = (const float*)d_in[8];
  const float* opb = (const float*)d_in[9];
  const float* tg_w = (const float*)d_in[10];
  const float* tg_b = (const float*)d_in[11];
  const float* ug_w = (const float*)d_in[12];
  const float* ug_b = (const float*)d_in[13];
  const float* ff_w = (const float*)d_in[14];
  const float* ff_b = (const float*)d_in[15];
  const float* ln_g = (const float*)d_in[16];
  const float* ln_b = (const float*)d_in[17];
  char* wsb = (char*)d_ws;
  float* out = (float*)d_out;

  // common precompute
  k_combine<<<256, 256, 0, stream>>>(ipw, opw, wsb);
  k_combine_bias<<<2, 256, 0, stream>>>(ipb, opb, opw, wsb);
  k_bias_tu<<<2, 256, 0, stream>>>(tm_b, um_b, wsb);
  k_pack_gw4<<<256, 256, 0, stream>>>(tg_w, ug_w, wsb);
  k_transpose4<<<256, 256, 0, stream>>>(ff_w, (float*)(wsb + OFF_FW4), 256, 256);

  if ((long)ws_size >= WS_NEED) {
    // fast path: MFMA front (M=32) -> global S -> 2-col scalar back (no S staging)
    float* Sg = (float*)(wsb + OFF_S);
    k_mt_hl<<<768, 256, 0, stream>>>(tm_w, wsb);
    k_mu_hl<<<256, 256, 0, stream>>>(um_w, wsb);
    k_s12<<<2048, 512, 0, stream>>>(text, user, wsb, Sg);
    k_gfl2b<<<4096, 256, 0, stream>>>(Sg, wsb, tg_b, ug_b, ff_b, ln_g, ln_b, out);
  } else {
    // fallback: R5 fused scalar (known-pass)
    k_mt4<<<768, 256, 0, stream>>>(tm_w, wsb);
    k_mu4<<<256, 256, 0, stream>>>(um_w, wsb);
    k_main5<<<8192, 256, 0, stream>>>(text, user, wsb, tg_b, ug_b, ff_b, ln_g, ln_b, out);
  }
}

// Round 18
// 595.063 us; speedup vs baseline: 1.2521x; 1.1095x over previous
//
#include <hip/hip_runtime.h>
#include <hip/hip_bf16.h>

// MultiViewFusion — two-kernel split, round 18.
// Evidence ledger:
//   R5  PASS 0.0156 (1338us): scalar-f32 fused.
//   R6-R9 FAIL: MFMA acc->LDS->read corrupts. QUARANTINE: acc exits only via
//        VALU->global store. (Scalar-computed values in LDS are fine.)
//   R10 PASS + zero poisons: MFMA stages 1/2 coordinate-exact.
//   R13 646us / R14 547us: k_gfl2 (S staged in LDS, 2-col, 256t) = 285us best kB.
//   R16 PASS 745us: k_s12 M=32 = ~150us (validated best kA); k_gfl3 regressed.
//   R17 PASS 660us: dropping S LDS staging HURT (452us; latency-bound at 33%
//        occupancy). Staging pays for itself.
// R18: k_s12 R16-verbatim + k_gfl4 = R14's staged-2-col kB at 512 THREADS
//      (same 16 rows, same 48KB LDS, rh=t>>7 4-row groups): 8 waves/block ->
//      3 blocks/CU x 8 = 75% occupancy to hide ds_read latency. Per-element
//      FMA order identical to R14; LN uses R13's validated 32-lane reduce.

namespace {

typedef __attribute__((ext_vector_type(8))) short short8v;   // 8 bf16 = 4 VGPR
typedef __attribute__((ext_vector_type(4))) float floatx4;   // MFMA C/D

// workspace byte offsets (unchanged from R13..R17)
constexpr int OFF_CW  = 0;        // f32 CWt[4][128][128]
constexpr int OFF_CB  = 262144;   // f32 cv[4][128]
constexpr int OFF_BT  = 264192;   // f32 bT[256]  [ts|uc]
constexpr int OFF_BU  = 265216;   // f32 bU[256]  [tc|us]
constexpr int OFF_MTH = 266240;   // bf16 M_text hi packed [96][256][8]
constexpr int OFF_MTL = 659456;   // bf16 M_text lo
constexpr int OFF_MUH = 1052672;  // bf16 M_user hi packed [32][256][8]
constexpr int OFF_MUL = 1183744;  // bf16 M_user lo
constexpr int OFF_GW4 = 1314816;  // f32 gate W [64][256][4] (cols tg|ug)
constexpr int OFF_FW4 = 1576960;  // f32 ff  W  [64][256][4]
constexpr int OFF_MT4 = 1839104;  // f32 M_text pack [192][256][4]  (fallback)
constexpr int OFF_MU4 = 2625536;  // f32 M_user pack [64][256][4]   (fallback)
constexpr long OFF_S  = 2887680;  // f32 S [65536][512] = 134217728 B
constexpr long WS_NEED = OFF_S + 134217728L;

__device__ inline unsigned short f2b(float f) {
  __hip_bfloat16 h = __float2bfloat16(f);
  return __builtin_bit_cast(unsigned short, h);
}
__device__ inline float b2f(unsigned short u) {
  unsigned int v = ((unsigned int)u) << 16;
  return __builtin_bit_cast(float, v);
}
__device__ inline void split2(float v, unsigned short& h, unsigned short& l) {
  h = f2b(v);
  l = f2b(v - b2f(h));
}

// ---------------- precompute (tiny, L2-resident; validated) ----------------

__global__ void k_combine(const float* __restrict__ ipw, const float* __restrict__ opw,
                          char* __restrict__ wsb) {
  float* cw = (float*)(wsb + OFF_CW);
  int n = blockIdx.x * 256 + threadIdx.x;
  int i = n >> 14, o = (n >> 7) & 127, d = n & 127;
  const float* op = opw + i * 16384 + o * 128;
  const float* iv = ipw + i * 49152 + 256 * 128 + d;
  float s = 0.f;
#pragma unroll 4
  for (int m = 0; m < 128; ++m) s = fmaf(op[m], iv[m * 128], s);
  cw[i * 16384 + d * 128 + o] = s;
}

__global__ void k_combine_bias(const float* __restrict__ ipb, const float* __restrict__ opb,
                               const float* __restrict__ opw, char* __restrict__ wsb) {
  float* cb = (float*)(wsb + OFF_CB);
  int t = blockIdx.x * 256 + threadIdx.x;
  int i = t >> 7, o = t & 127;
  const float* op = opw + i * 16384 + o * 128;
  const float* ib = ipb + i * 384 + 256;
  float s = opb[i * 128 + o];
#pragma unroll 4
  for (int m = 0; m < 128; ++m) s = fmaf(op[m], ib[m], s);
  cb[t] = s;
}

// hi/lo bf16 pack for MFMA (fast path)
__global__ void k_mt_hl(const float* __restrict__ tm_w, char* __restrict__ wsb) {
  const float* cw = (const float*)(wsb + OFF_CW);
  unsigned short* dh = (unsigned short*)(wsb + OFF_MTH);
  unsigned short* dl = (unsigned short*)(wsb + OFF_MTL);
  int n = blockIdx.x * 256 + threadIdx.x;  // 768*256
  int k = n >> 8, c = n & 255;
  const float* p = cw + ((c >> 7) ? 3 : 0) * 16384 + (c & 127);
  float s = 0.f;
#pragma unroll 4
  for (int d = 0; d < 128; ++d) s = fmaf(p[d * 128], tm_w[d * 768 + k], s);
  unsigned short h, l;
  split2(s, h, l);
  int ofs = (((k >> 3) * 256 + c) << 3) + (k & 7);
  dh[ofs] = h;
  dl[ofs] = l;
}

__global__ void k_mu_hl(const float* __restrict__ um_w, char* __restrict__ wsb) {
  const float* cw = (const float*)(wsb + OFF_CW);
  unsigned short* dh = (unsigned short*)(wsb + OFF_MUH);
  unsigned short* dl = (unsigned short*)(wsb + OFF_MUL);
  int n = blockIdx.x * 256 + threadIdx.x;  // 256*256
  int k = n >> 8, c = n & 255;
  const float* p = cw + ((c >> 7) ? 1 : 2) * 16384 + (c & 127);
  float s = 0.f;
#pragma unroll 4
  for (int d = 0; d < 128; ++d) s = fmaf(p[d * 128], um_w[d * 256 + k], s);
  unsigned short h, l;
  split2(s, h, l);
  int ofs = (((k >> 3) * 256 + c) << 3) + (k & 7);
  dh[ofs] = h;
  dl[ofs] = l;
}

// f32 [K/4][256][4] packs (fallback scalar path)
__global__ void k_mt4(const float* __restrict__ tm_w, char* __restrict__ wsb) {
  const float* cw = (const float*)(wsb + OFF_CW);
  float* dst = (float*)(wsb + OFF_MT4);
  int n = blockIdx.x * 256 + threadIdx.x;  // 768*256
  int k = n >> 8, c = n & 255;
  const float* p = cw + ((c >> 7) ? 3 : 0) * 16384 + (c & 127);
  float s = 0.f;
#pragma unroll 4
  for (int d = 0; d < 128; ++d) s = fmaf(p[d * 128], tm_w[d * 768 + k], s);
  dst[(((k >> 2) * 256 + c) << 2) + (k & 3)] = s;
}

__global__ void k_mu4(const float* __restrict__ um_w, char* __restrict__ wsb) {
  const float* cw = (const float*)(wsb + OFF_CW);
  float* dst = (float*)(wsb + OFF_MU4);
  int n = blockIdx.x * 256 + threadIdx.x;  // 256*256
  int k = n >> 8, c = n & 255;
  const float* p = cw + ((c >> 7) ? 1 : 2) * 16384 + (c & 127);
  float s = 0.f;
#pragma unroll 4
  for (int d = 0; d < 128; ++d) s = fmaf(p[d * 128], um_w[d * 256 + k], s);
  dst[(((k >> 2) * 256 + c) << 2) + (k & 3)] = s;
}

__global__ void k_bias_tu(const float* __restrict__ tm_b, const float* __restrict__ um_b,
                          char* __restrict__ wsb) {
  const float* cw = (const float*)(wsb + OFF_CW);
  const float* cb = (const float*)(wsb + OFF_CB);
  float* bT = (float*)(wsb + OFF_BT);
  float* bU = (float*)(wsb + OFF_BU);
  int t = blockIdx.x * 256 + threadIdx.x;
  if (t < 256) {
    int sel = (t >> 7) ? 3 : 0;
    const float* p = cw + sel * 16384 + (t & 127);
    float s = cb[sel * 128 + (t & 127)];
#pragma unroll 4
    for (int d = 0; d < 128; ++d) s = fmaf(p[d * 128], tm_b[d], s);
    bT[t] = s;
  } else {
    int c = t - 256;
    int sel = (c >> 7) ? 1 : 2;
    const float* p = cw + sel * 16384 + (c & 127);
    float s = cb[sel * 128 + (c & 127)];
#pragma unroll 4
    for (int d = 0; d < 128; ++d) s = fmaf(p[d * 128], um_b[d], s);
    bU[c] = s;
  }
}

// combined gate pack: cols 0..127 = tg_w, 128..255 = ug_w
__global__ void k_pack_gw4(const float* __restrict__ tg_w, const float* __restrict__ ug_w,
                           char* __restrict__ wsb) {
  float* dst = (float*)(wsb + OFF_GW4);
  int idx = blockIdx.x * 256 + threadIdx.x;  // 65536
  int j = idx >> 8, n = idx & 255;
  float v = (n < 128) ? tg_w[n * 256 + j] : ug_w[(n - 128) * 256 + j];
  dst[(((j >> 2) * 256 + n) << 2) + (j & 3)] = v;
}

// dst[((k>>2)*R + o)*4 + (k&3)] = src[o*C + k]
__global__ void k_transpose4(const float* __restrict__ src, float* __restrict__ dst,
                             int R, int C) {
  int n = blockIdx.x * 256 + threadIdx.x;
  if (n >= R * C) return;
  int o = n / C, k = n % C;
  dst[(((k >> 2) * R + o) << 2) + (k & 3)] = src[n];
}

// ---------------- kA: MFMA stages 1/2 -> global S, M=32, K-halved staging ----------------
// (R16-verbatim; validated PASS, ~150us.)

#define SWZ(byte, row) ((byte) ^ (((row) & 7) << 4))

__launch_bounds__(512)
__global__ void k_s12(const float* __restrict__ xt_g, const float* __restrict__ xu_g,
                      const char* __restrict__ wsb, float* __restrict__ Sg) {
  __shared__ __align__(16) char sm[65536];
  constexpr int XTL = 24576;   // xt lo   (xt hi at 0; [32][384] bf16 = 24576 B each)
  constexpr int XUH = 49152;   // xu hi   ([32][128] bf16 = 8192 B each)
  constexpr int XUL = 57344;   // xu lo

  const int t = threadIdx.x;
  const int wave = t >> 6, lane = t & 63;
  const int lrow = lane & 15;
  const int lk8 = lane >> 4;
  const int n0w = wave * 32;
  const long row0 = (long)blockIdx.x * 32;

  const float* bT = (const float*)(wsb + OFF_BT);
  const float* bU = (const float*)(wsb + OFF_BU);

  floatx4 zero = {0.f, 0.f, 0.f, 0.f};
  floatx4 acc1[2][2] = {{zero, zero}, {zero, zero}};  // [rowgrp][nt]
  floatx4 acc2[2][2] = {{zero, zero}, {zero, zero}};

  for (int p = 0; p < 2; ++p) {
    if (p) __syncthreads();  // pass-0 LDS reads complete before overwrite

    // ---- stage xt K-window: 32 rows x 96 float4/row; ushort4 out -> rem*8 ----
#pragma unroll
    for (int it = 0; it < 6; ++it) {
      int idx = it * 512 + t;
      int row = idx / 96, rem = idx - row * 96;
      float4 v = *(const float4*)(xt_g + (row0 + row) * 768 + p * 384 + rem * 4);
      int b0 = row * 768 + rem * 8;
      ushort4 hh, ll;
      split2(v.x, hh.x, ll.x); split2(v.y, hh.y, ll.y);
      split2(v.z, hh.z, ll.z); split2(v.w, hh.w, ll.w);
      *(ushort4*)(sm + SWZ(b0, row)) = hh;
      *(ushort4*)(sm + XTL + SWZ(b0, row)) = ll;
    }
    // ---- stage xu K-window: 32 rows x 32 float4/row; ushort4 out -> rem*8 ----
#pragma unroll
    for (int it = 0; it < 2; ++it) {
      int idx = it * 512 + t;
      int row = idx >> 5, rem = idx & 31;
      float4 v = *(const float4*)(xu_g + (row0 + row) * 256 + p * 128 + rem * 4);
      int b0 = row * 256 + rem * 8;
      ushort4 hh, ll;
      split2(v.x, hh.x, ll.x); split2(v.y, hh.y, ll.y);
      split2(v.z, hh.z, ll.z); split2(v.w, hh.w, ll.w);
      *(ushort4*)(sm + XUH + SWZ(b0, row)) = hh;
      *(ushort4*)(sm + XUL + SWZ(b0, row)) = ll;
    }
    __syncthreads();

    // ---- stage 1 MFMA over this K-window (12 chunks of 32) ----
    {
      const char* wh = wsb + OFF_MTH;
      const char* wl = wsb + OFF_MTL;
#pragma unroll 4
      for (int kk = 0; kk < 384; kk += 32) {
        int kb = (kk + lk8 * 8) * 2;
        int k8 = ((p * 384 + kk) >> 3) + lk8;
        int o0 = (k8 * 256 + n0w + lrow) << 4;
        int o1 = (k8 * 256 + n0w + 16 + lrow) << 4;
        short8v bh0 = *(const short8v*)(wh + o0);
        short8v bh1 = *(const short8v*)(wh + o1);
        short8v bl0 = *(const short8v*)(wl + o0);
        short8v bl1 = *(const short8v*)(wl + o1);
#pragma unroll
        for (int rg = 0; rg < 2; ++rg) {
          int ar = rg * 16 + lrow;
          short8v ah = *(const short8v*)(sm + SWZ(ar * 768 + kb, ar));
          short8v al = *(const short8v*)(sm + XTL + SWZ(ar * 768 + kb, ar));
          acc1[rg][0] = __builtin_amdgcn_mfma_f32_16x16x32_bf16(ah, bh0, acc1[rg][0], 0, 0, 0);
          acc1[rg][0] = __builtin_amdgcn_mfma_f32_16x16x32_bf16(ah, bl0, acc1[rg][0], 0, 0, 0);
          acc1[rg][0] = __builtin_amdgcn_mfma_f32_16x16x32_bf16(al, bh0, acc1[rg][0], 0, 0, 0);
          acc1[rg][1] = __builtin_amdgcn_mfma_f32_16x16x32_bf16(ah, bh1, acc1[rg][1], 0, 0, 0);
          acc1[rg][1] = __builtin_amdgcn_mfma_f32_16x16x32_bf16(ah, bl1, acc1[rg][1], 0, 0, 0);
          acc1[rg][1] = __builtin_amdgcn_mfma_f32_16x16x32_bf16(al, bh1, acc1[rg][1], 0, 0, 0);
        }
      }
    }
    // ---- stage 2 MFMA over this K-window (4 chunks of 32) ----
    {
      const char* wh = wsb + OFF_MUH;
      const char* wl = wsb + OFF_MUL;
#pragma unroll
      for (int kk = 0; kk < 128; kk += 32) {
        int kb = (kk + lk8 * 8) * 2;
        int k8 = ((p * 128 + kk) >> 3) + lk8;
        int o0 = (k8 * 256 + n0w + lrow) << 4;
        int o1 = (k8 * 256 + n0w + 16 + lrow) << 4;
        short8v bh0 = *(const short8v*)(wh + o0);
        short8v bh1 = *(const short8v*)(wh + o1);
        short8v bl0 = *(const short8v*)(wl + o0);
        short8v bl1 = *(const short8v*)(wl + o1);
#pragma unroll
        for (int rg = 0; rg < 2; ++rg) {
          int ar = rg * 16 + lrow;
          short8v ah = *(const short8v*)(sm + XUH + SWZ(ar * 256 + kb, ar));
          short8v al = *(const short8v*)(sm + XUL + SWZ(ar * 256 + kb, ar));
          acc2[rg][0] = __builtin_amdgcn_mfma_f32_16x16x32_bf16(ah, bh0, acc2[rg][0], 0, 0, 0);
          acc2[rg][0] = __builtin_amdgcn_mfma_f32_16x16x32_bf16(ah, bl0, acc2[rg][0], 0, 0, 0);
          acc2[rg][0] = __builtin_amdgcn_mfma_f32_16x16x32_bf16(al, bh0, acc2[rg][0], 0, 0, 0);
          acc2[rg][1] = __builtin_amdgcn_mfma_f32_16x16x32_bf16(ah, bh1, acc2[rg][1], 0, 0, 0);
          acc2[rg][1] = __builtin_amdgcn_mfma_f32_16x16x32_bf16(ah, bl1, acc2[rg][1], 0, 0, 0);
          acc2[rg][1] = __builtin_amdgcn_mfma_f32_16x16x32_bf16(al, bh1, acc2[rg][1], 0, 0, 0);
        }
      }
    }
  }

  // ---- epilogue: acc+bias -> GLOBAL S (quarantine-compliant) ----
  // C/D map: row = rg*16 + lk8*4 + reg, col = n0w + nt*16 + lrow.
#pragma unroll
  for (int rg = 0; rg < 2; ++rg)
#pragma unroll
    for (int nt = 0; nt < 2; ++nt) {
      int n = n0w + nt * 16 + lrow;
      float bvT = bT[n], bvU = bU[n];
      int scolT = (n < 128) ? n : 256 + n;  // ts | uc
      int scolU = 128 + n;                  // tc | us
#pragma unroll
      for (int reg = 0; reg < 4; ++reg) {
        long grow = row0 + rg * 16 + lk8 * 4 + reg;
        Sg[grow * 512 + scolT] = acc1[rg][nt][reg] + bvT;
        Sg[grow * 512 + scolU] = acc2[rg][nt][reg] + bvU;
      }
    }
}

// ---------------- kB: gates/mix/ff/LN — R14 staged-2-col at 512 threads ----------------
// 512 threads = 8 waves, 16 rows/block (4096 blocks), 48 KB LDS.
// thread: rh = t>>7 (4-row group), c0 = (t&127)*2.
// Per j-step/thread: 4 ds_read (broadcast) + 2 wloads + 32 FMA; FMA order per
// output element identical to R14's k_gfl2. 3 blocks/CU x 8 waves = 75% occ.

__launch_bounds__(512)
__global__ void k_gfl4(const float* __restrict__ Sg, const char* __restrict__ wsb,
                       const float* __restrict__ tg_b, const float* __restrict__ ug_b,
                       const float* __restrict__ ff_b, const float* __restrict__ ln_g,
                       const float* __restrict__ ln_b, float* __restrict__ out) {
  __shared__ float lds[16 * 512 + 16 * 256];  // S 32KB + F 16KB = 48KB
  float* S = lds;             // [16][512]
  float* F = lds + 8192;      // [16][256]
  float* H = lds;             // [16][256] overlays S (dead after phase 3)

  const int t = threadIdx.x;
  const long row0 = (long)blockIdx.x * 16;

  // ---- stage S from global (coalesced): 2048 float4 / 512 threads ----
  {
    const float4* g = (const float4*)(Sg + row0 * 512);
    float4* l = (float4*)S;
#pragma unroll
    for (int it = 0; it < 4; ++it) l[it * 512 + t] = g[it * 512 + t];
  }
  __syncthreads();

  const int rh = t >> 7, c0 = (t & 127) * 2;
  const int r0 = rh * 4;

  // ---- phase 3: gates + mix -> F ----
  {
    const int so3 = (c0 < 128) ? 0 : 256;  // tg: S[0:256]=[ts|tc]; ug: S[256:512]=[us|uc]
    const float4* GW = (const float4*)(wsb + OFF_GW4);
    float acc[4][2] = {};
    for (int j = 0; j < 256; j += 4) {
      float4 w0 = GW[(j >> 2) * 256 + c0];
      float4 w1 = GW[(j >> 2) * 256 + c0 + 1];
#pragma unroll
      for (int r = 0; r < 4; ++r) {
        float4 sv = *(const float4*)&S[(r0 + r) * 512 + so3 + j];  // broadcast
        acc[r][0] = fmaf(sv.x, w0.x, fmaf(sv.y, w0.y, fmaf(sv.z, w0.z, fmaf(sv.w, w0.w, acc[r][0]))));
        acc[r][1] = fmaf(sv.x, w1.x, fmaf(sv.y, w1.y, fmaf(sv.z, w1.z, fmaf(sv.w, w1.w, acc[r][1]))));
      }
    }
    float gb0 = (c0 < 128) ? tg_b[c0] : ug_b[c0 - 128];
    float gb1 = (c0 < 128) ? tg_b[c0 + 1] : ug_b[c0 - 127];
    int am = (c0 < 128) ? c0 : 128 + c0;  // self col in S
#pragma unroll
    for (int r = 0; r < 4; ++r) {
      int row = r0 + r;
      float g0 = 1.f / (1.f + __expf(-(acc[r][0] + gb0)));
      float g1 = 1.f / (1.f + __expf(-(acc[r][1] + gb1)));
      float a0 = S[row * 512 + am],     b0v = S[row * 512 + am + 128];
      float a1 = S[row * 512 + am + 1], b1v = S[row * 512 + am + 129];
      F[row * 256 + c0]     = fmaf(g0, b0v - a0, a0);
      F[row * 256 + c0 + 1] = fmaf(g1, b1v - a1, a1);
    }
  }
  __syncthreads();

  // ---- phase 4: ff GEMM -> H (overlays dead S) ----
  {
    const float4* FW = (const float4*)(wsb + OFF_FW4);
    float acc[4][2] = {};
    for (int j = 0; j < 256; j += 4) {
      float4 w0 = FW[(j >> 2) * 256 + c0];
      float4 w1 = FW[(j >> 2) * 256 + c0 + 1];
#pragma unroll
      for (int r = 0; r < 4; ++r) {
        float4 fv = *(const float4*)&F[(r0 + r) * 256 + j];  // broadcast
        acc[r][0] = fmaf(fv.x, w0.x, fmaf(fv.y, w0.y, fmaf(fv.z, w0.z, fmaf(fv.w, w0.w, acc[r][0]))));
        acc[r][1] = fmaf(fv.x, w1.x, fmaf(fv.y, w1.y, fmaf(fv.z, w1.z, fmaf(fv.w, w1.w, acc[r][1]))));
      }
    }
    float fb0 = ff_b[c0], fb1 = ff_b[c0 + 1];
#pragma unroll
    for (int r = 0; r < 4; ++r) {
      int row = r0 + r;
      H[row * 256 + c0]     = acc[r][0] + fb0;
      H[row * 256 + c0 + 1] = acc[r][1] + fb1;
    }
  }
  __syncthreads();

  // ---- phase 5: LayerNorm + ReLU + store. 32 threads/row, 8 elems (R13-validated) ----
  {
    int r = t >> 5, q = t & 31;
    const float* Hr = H + r * 256 + q * 8;
    float4 hv0 = *(const float4*)Hr;
    float4 hv1 = *(const float4*)(Hr + 4);
    float s1 = hv0.x + hv0.y + hv0.z + hv0.w + hv1.x + hv1.y + hv1.z + hv1.w;
    float s2 = hv0.x * hv0.x + hv0.y * hv0.y + hv0.z * hv0.z + hv0.w * hv0.w +
               hv1.x * hv1.x + hv1.y * hv1.y + hv1.z * hv1.z + hv1.w * hv1.w;
#pragma unroll
    for (int off = 1; off < 32; off <<= 1) {
      s1 += __shfl_xor(s1, off);
      s2 += __shfl_xor(s2, off);
    }
    float mu = s1 * (1.f / 256.f);
    float var = s2 * (1.f / 256.f) - mu * mu;
    float rstd = rsqrtf(var + 1e-5f);
    float* op = out + (row0 + r) * 256 + q * 8;
    float4 gv0 = *(const float4*)(ln_g + q * 8);
    float4 gv1 = *(const float4*)(ln_g + q * 8 + 4);
    float4 bv0 = *(const float4*)(ln_b + q * 8);
    float4 bv1 = *(const float4*)(ln_b + q * 8 + 4);
    float4 o0, o1;
    o0.x = fmaf((hv0.x - mu) * rstd, gv0.x, bv0.x);
    o0.y = fmaf((hv0.y - mu) * rstd, gv0.y, bv0.y);
    o0.z = fmaf((hv0.z - mu) * rstd, gv0.z, bv0.z);
    o0.w = fmaf((hv0.w - mu) * rstd, gv0.w, bv0.w);
    o1.x = fmaf((hv1.x - mu) * rstd, gv1.x, bv1.x);
    o1.y = fmaf((hv1.y - mu) * rstd, gv1.y, bv1.y);
    o1.z = fmaf((hv1.z - mu) * rstd, gv1.z, bv1.z);
    o1.w = fmaf((hv1.w - mu) * rstd, gv1.w, bv1.w);
    o0.x = o0.x > 0.f ? o0.x : 0.f;  o0.y = o0.y > 0.f ? o0.y : 0.f;
    o0.z = o0.z > 0.f ? o0.z : 0.f;  o0.w = o0.w > 0.f ? o0.w : 0.f;
    o1.x = o1.x > 0.f ? o1.x : 0.f;  o1.y = o1.y > 0.f ? o1.y : 0.f;
    o1.z = o1.z > 0.f ? o1.z : 0.f;  o1.w = o1.w > 0.f ? o1.w : 0.f;
    *(float4*)op = o0;
    *(float4*)(op + 4) = o1;
  }
}

// ---------------- fallback: R5 fused scalar kernel (GW4-adapted; known-pass) ----------------

__launch_bounds__(256)
__global__ void k_main5(const float* __restrict__ xt_g, const float* __restrict__ xu_g,
                        const char* __restrict__ wsb,
                        const float* __restrict__ tg_b, const float* __restrict__ ug_b,
                        const float* __restrict__ ff_b, const float* __restrict__ ln_g,
                        const float* __restrict__ ln_b, float* __restrict__ out) {
  __shared__ float lds[8 * 768 + 8 * 512 + 8 * 256];  // 48 KB
  float* xt = lds;
  float* S = lds + 8 * 768;
  float* xu = lds + 8 * 768 + 8 * 512;

  const int t = threadIdx.x;
  const long row0 = (long)blockIdx.x * 8;

  {
    const float4* g = (const float4*)(xt_g + row0 * 768);
    float4* l = (float4*)xt;
#pragma unroll
    for (int it = 0; it < 6; ++it) l[it * 256 + t] = g[it * 256 + t];
    const float4* gu = (const float4*)(xu_g + row0 * 256);
    float4* lu = (float4*)xu;
#pragma unroll
    for (int it = 0; it < 2; ++it) lu[it * 256 + t] = gu[it * 256 + t];
  }
  __syncthreads();

  {
    const float4* W4 = (const float4*)(wsb + OFF_MT4);
    float acc[8];
#pragma unroll
    for (int r = 0; r < 8; ++r) acc[r] = 0.f;
    for (int k = 0; k < 768; k += 4) {
      float4 w = W4[(k >> 2) * 256 + t];
#pragma unroll
      for (int r = 0; r < 8; ++r) {
        float4 xv = *(const float4*)&xt[r * 768 + k];
        acc[r] = fmaf(w.x, xv.x, acc[r]);
        acc[r] = fmaf(w.y, xv.y, acc[r]);
        acc[r] = fmaf(w.z, xv.z, acc[r]);
        acc[r] = fmaf(w.w, xv.w, acc[r]);
      }
    }
    float bias = ((const float*)(wsb + OFF_BT))[t];
    int d = (t < 128) ? t : (256 + t);
#pragma unroll
    for (int r = 0; r < 8; ++r) S[r * 512 + d] = acc[r] + bias;
  }

  {
    const float4* W4 = (const float4*)(wsb + OFF_MU4);
    float acc[8];
#pragma unroll
    for (int r = 0; r < 8; ++r) acc[r] = 0.f;
    for (int k = 0; k < 256; k += 4) {
      float4 w = W4[(k >> 2) * 256 + t];
#pragma unroll
      for (int r = 0; r < 8; ++r) {
        float4 xv = *(const float4*)&xu[r * 256 + k];
        acc[r] = fmaf(w.x, xv.x, acc[r]);
        acc[r] = fmaf(w.y, xv.y, acc[r]);
        acc[r] = fmaf(w.z, xv.z, acc[r]);
        acc[r] = fmaf(w.w, xv.w, acc[r]);
      }
    }
    float bias = ((const float*)(wsb + OFF_BU))[t];
#pragma unroll
    for (int r = 0; r < 8; ++r) S[r * 512 + 128 + t] = acc[r] + bias;
  }
  __syncthreads();

  {
    int c = t & 127, half = t >> 7;
    const float4* W4 = (const float4*)(wsb + OFF_GW4);
    const int wcol = half * 128 + c;
    const int so = half * 256;
    float acc[8];
#pragma unroll
    for (int r = 0; r < 8; ++r) acc[r] = 0.f;
    for (int j = 0; j < 256; j += 4) {
      float4 w = W4[(j >> 2) * 256 + wcol];
#pragma unroll
      for (int r = 0; r < 8; ++r) {
        float4 sv = *(const float4*)&S[r * 512 + so + j];
        acc[r] = fmaf(w.x, sv.x, acc[r]);
        acc[r] = fmaf(w.y, sv.y, acc[r]);
        acc[r] = fmaf(w.z, sv.z, acc[r]);
        acc[r] = fmaf(w.w, sv.w, acc[r]);
      }
    }
    float gb = half ? ug_b[c] : tg_b[c];
    float* F = xu;
#pragma unroll
    for (int r = 0; r < 8; ++r) {
      float g = 1.f / (1.f + __expf(-(acc[r] + gb)));
      float a = S[r * 512 + so + c];
      float b = S[r * 512 + so + 128 + c];
      F[r * 256 + half * 128 + c] = fmaf(g, b - a, a);
    }
  }
  __syncthreads();

  {
    const float4* W4 = (const float4*)(wsb + OFF_FW4);
    const float* F = xu;
    float acc[8];
#pragma unroll
    for (int r = 0; r < 8; ++r) acc[r] = 0.f;
    for (int j = 0; j < 256; j += 4) {
      float4 w = W4[(j >> 2) * 256 + t];
#pragma unroll
      for (int r = 0; r < 8; ++r) {
        float4 fv = *(const float4*)&F[r * 256 + j];
        acc[r] = fmaf(w.x, fv.x, acc[r]);
        acc[r] = fmaf(w.y, fv.y, acc[r]);
        acc[r] = fmaf(w.z, fv.z, acc[r]);
        acc[r] = fmaf(w.w, fv.w, acc[r]);
      }
    }
    float* H = xt;
    float bias = ff_b[t];
#pragma unroll
    for (int r = 0; r < 8; ++r) H[r * 256 + t] = acc[r] + bias;
  }
  __syncthreads();

  {
    const float* H = xt;
    int r = t >> 5, q = t & 31;
    const float* Hr = H + r * 256 + q * 8;
    float s1 = 0.f, s2 = 0.f;
#pragma unroll
    for (int i = 0; i < 8; ++i) {
      float v = Hr[i];
      s1 += v;
      s2 += v * v;
    }
#pragma unroll
    for (int off = 1; off < 32; off <<= 1) {
      s1 += __shfl_xor(s1, off);
      s2 += __shfl_xor(s2, off);
    }
    float mu = s1 * (1.f / 256.f);
    float var = s2 * (1.f / 256.f) - mu * mu;
    float rstd = rsqrtf(var + 1e-5f);
    float* op = out + (row0 + r) * 256 + q * 8;
#pragma unroll
    for (int i = 0; i < 8; ++i) {
      float v = (Hr[i] - mu) * rstd * ln_g[q * 8 + i] + ln_b[q * 8 + i];
      op[i] = v > 0.f ? v : 0.f;
    }
  }
}

}  // namespace

extern "C" void kernel_launch(void* const* d_in, const int* in_sizes, int n_in,
                              void* d_out, int out_size, void* d_ws, size_t ws_size,
                              hipStream_t stream) {
  const float* text = (const float*)d_in[0];
  const float* user = (const float*)d_in[1];
  const float* tm_w = (const float*)d_in[2];
  const float* tm_b = (const float*)d_in[3];
  const float* um_w = (const float*)d_in[4];
  const float* um_b = (const float*)d_in[5];
  const float* ipw = (const float*)d_in[6];
  const float* ipb = (const float*)d_in[7];
  const float* opw = (const float*)d_in[8];
  const float* opb = (const float*)d_in[9];
  const float* tg_w = (const float*)d_in[10];
  const float* tg_b = (const float*)d_in[11];
  const float* ug_w = (const float*)d_in[12];
  const float* ug_b = (const float*)d_in[13];
  const float* ff_w = (const float*)d_in[14];
  const float* ff_b = (const float*)d_in[15];
  const float* ln_g = (const float*)d_in[16];
  const float* ln_b = (const float*)d_in[17];
  char* wsb = (char*)d_ws;
  float* out = (float*)d_out;

  // common precompute
  k_combine<<<256, 256, 0, stream>>>(ipw, opw, wsb);
  k_combine_bias<<<2, 256, 0, stream>>>(ipb, opb, opw, wsb);
  k_bias_tu<<<2, 256, 0, stream>>>(tm_b, um_b, wsb);
  k_pack_gw4<<<256, 256, 0, stream>>>(tg_w, ug_w, wsb);
  k_transpose4<<<256, 256, 0, stream>>>(ff_w, (float*)(wsb + OFF_FW4), 256, 256);

  if ((long)ws_size >= WS_NEED) {
    // fast path: MFMA front (M=32) -> global S -> staged 2-col back @512t
    float* Sg = (float*)(wsb + OFF_S);
    k_mt_hl<<<768, 256, 0, stream>>>(tm_w, wsb);
    k_mu_hl<<<256, 256, 0, stream>>>(um_w, wsb);
    k_s12<<<2048, 512, 0, stream>>>(text, user, wsb, Sg);
    k_gfl4<<<4096, 512, 0, stream>>>(Sg, wsb, tg_b, ug_b, ff_b, ln_g, ln_b, out);
  } else {
    // fallback: R5 fused scalar (known-pass)
    k_mt4<<<768, 256, 0, stream>>>(tm_w, wsb);
    k_mu4<<<256, 256, 0, stream>>>(um_w, wsb);
    k_main5<<<8192, 256, 0, stream>>>(text, user, wsb, tg_b, ug_b, ff_b, ln_g, ln_b, out);
  }
}

// Round 19
// 539.157 us; speedup vs baseline: 1.3819x; 1.1037x over previous
//
#include <hip/hip_runtime.h>
#include <hip/hip_bf16.h>

// MultiViewFusion — two-kernel split, round 19: best-of-both recombination.
// Evidence ledger:
//   R5  PASS 0.0156 (1338us): scalar-f32 fused.
//   R6-R9 FAIL: MFMA acc->LDS->read corrupts. QUARANTINE: acc exits only via
//        VALU->global store. (Scalar-computed values in LDS are fine.)
//   R10 PASS + zero poisons: MFMA stages 1/2 coordinate-exact.
//   R14 PASS 547us: k_gfl2 (S staged LDS, 8-row x 2-col, 256t) = 285us —
//        empirical kB optimum (R16 4x4: 565; R17 no-staging: 452; R18 512t: 341).
//   R16 PASS 745us: k_s12 M=32 K-halved staging = ~150us — validated kA optimum.
// R19: k_s12 (R16-verbatim) + k_gfl2 (R14-verbatim). No new code.

namespace {

typedef __attribute__((ext_vector_type(8))) short short8v;   // 8 bf16 = 4 VGPR
typedef __attribute__((ext_vector_type(4))) float floatx4;   // MFMA C/D

// workspace byte offsets (unchanged from R13..R18)
constexpr int OFF_CW  = 0;        // f32 CWt[4][128][128]
constexpr int OFF_CB  = 262144;   // f32 cv[4][128]
constexpr int OFF_BT  = 264192;   // f32 bT[256]  [ts|uc]
constexpr int OFF_BU  = 265216;   // f32 bU[256]  [tc|us]
constexpr int OFF_MTH = 266240;   // bf16 M_text hi packed [96][256][8]
constexpr int OFF_MTL = 659456;   // bf16 M_text lo
constexpr int OFF_MUH = 1052672;  // bf16 M_user hi packed [32][256][8]
constexpr int OFF_MUL = 1183744;  // bf16 M_user lo
constexpr int OFF_GW4 = 1314816;  // f32 gate W [64][256][4] (cols tg|ug)
constexpr int OFF_FW4 = 1576960;  // f32 ff  W  [64][256][4]
constexpr int OFF_MT4 = 1839104;  // f32 M_text pack [192][256][4]  (fallback)
constexpr int OFF_MU4 = 2625536;  // f32 M_user pack [64][256][4]   (fallback)
constexpr long OFF_S  = 2887680;  // f32 S [65536][512] = 134217728 B
constexpr long WS_NEED = OFF_S + 134217728L;

__device__ inline unsigned short f2b(float f) {
  __hip_bfloat16 h = __float2bfloat16(f);
  return __builtin_bit_cast(unsigned short, h);
}
__device__ inline float b2f(unsigned short u) {
  unsigned int v = ((unsigned int)u) << 16;
  return __builtin_bit_cast(float, v);
}
__device__ inline void split2(float v, unsigned short& h, unsigned short& l) {
  h = f2b(v);
  l = f2b(v - b2f(h));
}

// ---------------- precompute (tiny, L2-resident; validated) ----------------

__global__ void k_combine(const float* __restrict__ ipw, const float* __restrict__ opw,
                          char* __restrict__ wsb) {
  float* cw = (float*)(wsb + OFF_CW);
  int n = blockIdx.x * 256 + threadIdx.x;
  int i = n >> 14, o = (n >> 7) & 127, d = n & 127;
  const float* op = opw + i * 16384 + o * 128;
  const float* iv = ipw + i * 49152 + 256 * 128 + d;
  float s = 0.f;
#pragma unroll 4
  for (int m = 0; m < 128; ++m) s = fmaf(op[m], iv[m * 128], s);
  cw[i * 16384 + d * 128 + o] = s;
}

__global__ void k_combine_bias(const float* __restrict__ ipb, const float* __restrict__ opb,
                               const float* __restrict__ opw, char* __restrict__ wsb) {
  float* cb = (float*)(wsb + OFF_CB);
  int t = blockIdx.x * 256 + threadIdx.x;
  int i = t >> 7, o = t & 127;
  const float* op = opw + i * 16384 + o * 128;
  const float* ib = ipb + i * 384 + 256;
  float s = opb[i * 128 + o];
#pragma unroll 4
  for (int m = 0; m < 128; ++m) s = fmaf(op[m], ib[m], s);
  cb[t] = s;
}

// hi/lo bf16 pack for MFMA (fast path)
__global__ void k_mt_hl(const float* __restrict__ tm_w, char* __restrict__ wsb) {
  const float* cw = (const float*)(wsb + OFF_CW);
  unsigned short* dh = (unsigned short*)(wsb + OFF_MTH);
  unsigned short* dl = (unsigned short*)(wsb + OFF_MTL);
  int n = blockIdx.x * 256 + threadIdx.x;  // 768*256
  int k = n >> 8, c = n & 255;
  const float* p = cw + ((c >> 7) ? 3 : 0) * 16384 + (c & 127);
  float s = 0.f;
#pragma unroll 4
  for (int d = 0; d < 128; ++d) s = fmaf(p[d * 128], tm_w[d * 768 + k], s);
  unsigned short h, l;
  split2(s, h, l);
  int ofs = (((k >> 3) * 256 + c) << 3) + (k & 7);
  dh[ofs] = h;
  dl[ofs] = l;
}

__global__ void k_mu_hl(const float* __restrict__ um_w, char* __restrict__ wsb) {
  const float* cw = (const float*)(wsb + OFF_CW);
  unsigned short* dh = (unsigned short*)(wsb + OFF_MUH);
  unsigned short* dl = (unsigned short*)(wsb + OFF_MUL);
  int n = blockIdx.x * 256 + threadIdx.x;  // 256*256
  int k = n >> 8, c = n & 255;
  const float* p = cw + ((c >> 7) ? 1 : 2) * 16384 + (c & 127);
  float s = 0.f;
#pragma unroll 4
  for (int d = 0; d < 128; ++d) s = fmaf(p[d * 128], um_w[d * 256 + k], s);
  unsigned short h, l;
  split2(s, h, l);
  int ofs = (((k >> 3) * 256 + c) << 3) + (k & 7);
  dh[ofs] = h;
  dl[ofs] = l;
}

// f32 [K/4][256][4] packs (fallback scalar path)
__global__ void k_mt4(const float* __restrict__ tm_w, char* __restrict__ wsb) {
  const float* cw = (const float*)(wsb + OFF_CW);
  float* dst = (float*)(wsb + OFF_MT4);
  int n = blockIdx.x * 256 + threadIdx.x;  // 768*256
  int k = n >> 8, c = n & 255;
  const float* p = cw + ((c >> 7) ? 3 : 0) * 16384 + (c & 127);
  float s = 0.f;
#pragma unroll 4
  for (int d = 0; d < 128; ++d) s = fmaf(p[d * 128], tm_w[d * 768 + k], s);
  dst[(((k >> 2) * 256 + c) << 2) + (k & 3)] = s;
}

__global__ void k_mu4(const float* __restrict__ um_w, char* __restrict__ wsb) {
  const float* cw = (const float*)(wsb + OFF_CW);
  float* dst = (float*)(wsb + OFF_MU4);
  int n = blockIdx.x * 256 + threadIdx.x;  // 256*256
  int k = n >> 8, c = n & 255;
  const float* p = cw + ((c >> 7) ? 1 : 2) * 16384 + (c & 127);
  float s = 0.f;
#pragma unroll 4
  for (int d = 0; d < 128; ++d) s = fmaf(p[d * 128], um_w[d * 256 + k], s);
  dst[(((k >> 2) * 256 + c) << 2) + (k & 3)] = s;
}

__global__ void k_bias_tu(const float* __restrict__ tm_b, const float* __restrict__ um_b,
                          char* __restrict__ wsb) {
  const float* cw = (const float*)(wsb + OFF_CW);
  const float* cb = (const float*)(wsb + OFF_CB);
  float* bT = (float*)(wsb + OFF_BT);
  float* bU = (float*)(wsb + OFF_BU);
  int t = blockIdx.x * 256 + threadIdx.x;
  if (t < 256) {
    int sel = (t >> 7) ? 3 : 0;
    const float* p = cw + sel * 16384 + (t & 127);
    float s = cb[sel * 128 + (t & 127)];
#pragma unroll 4
    for (int d = 0; d < 128; ++d) s = fmaf(p[d * 128], tm_b[d], s);
    bT[t] = s;
  } else {
    int c = t - 256;
    int sel = (c >> 7) ? 1 : 2;
    const float* p = cw + sel * 16384 + (c & 127);
    float s = cb[sel * 128 + (c & 127)];
#pragma unroll 4
    for (int d = 0; d < 128; ++d) s = fmaf(p[d * 128], um_b[d], s);
    bU[c] = s;
  }
}

// combined gate pack: cols 0..127 = tg_w, 128..255 = ug_w
__global__ void k_pack_gw4(const float* __restrict__ tg_w, const float* __restrict__ ug_w,
                           char* __restrict__ wsb) {
  float* dst = (float*)(wsb + OFF_GW4);
  int idx = blockIdx.x * 256 + threadIdx.x;  // 65536
  int j = idx >> 8, n = idx & 255;
  float v = (n < 128) ? tg_w[n * 256 + j] : ug_w[(n - 128) * 256 + j];
  dst[(((j >> 2) * 256 + n) << 2) + (j & 3)] = v;
}

// dst[((k>>2)*R + o)*4 + (k&3)] = src[o*C + k]
__global__ void k_transpose4(const float* __restrict__ src, float* __restrict__ dst,
                             int R, int C) {
  int n = blockIdx.x * 256 + threadIdx.x;
  if (n >= R * C) return;
  int o = n / C, k = n % C;
  dst[(((k >> 2) * R + o) << 2) + (k & 3)] = src[n];
}

// ---------------- kA: MFMA stages 1/2 -> global S, M=32, K-halved staging ----------------
// (R16-verbatim; validated PASS, ~150us.)

#define SWZ(byte, row) ((byte) ^ (((row) & 7) << 4))

__launch_bounds__(512)
__global__ void k_s12(const float* __restrict__ xt_g, const float* __restrict__ xu_g,
                      const char* __restrict__ wsb, float* __restrict__ Sg) {
  __shared__ __align__(16) char sm[65536];
  constexpr int XTL = 24576;   // xt lo   (xt hi at 0; [32][384] bf16 = 24576 B each)
  constexpr int XUH = 49152;   // xu hi   ([32][128] bf16 = 8192 B each)
  constexpr int XUL = 57344;   // xu lo

  const int t = threadIdx.x;
  const int wave = t >> 6, lane = t & 63;
  const int lrow = lane & 15;
  const int lk8 = lane >> 4;
  const int n0w = wave * 32;
  const long row0 = (long)blockIdx.x * 32;

  const float* bT = (const float*)(wsb + OFF_BT);
  const float* bU = (const float*)(wsb + OFF_BU);

  floatx4 zero = {0.f, 0.f, 0.f, 0.f};
  floatx4 acc1[2][2] = {{zero, zero}, {zero, zero}};  // [rowgrp][nt]
  floatx4 acc2[2][2] = {{zero, zero}, {zero, zero}};

  for (int p = 0; p < 2; ++p) {
    if (p) __syncthreads();  // pass-0 LDS reads complete before overwrite

    // ---- stage xt K-window: 32 rows x 96 float4/row; ushort4 out -> rem*8 ----
#pragma unroll
    for (int it = 0; it < 6; ++it) {
      int idx = it * 512 + t;
      int row = idx / 96, rem = idx - row * 96;
      float4 v = *(const float4*)(xt_g + (row0 + row) * 768 + p * 384 + rem * 4);
      int b0 = row * 768 + rem * 8;
      ushort4 hh, ll;
      split2(v.x, hh.x, ll.x); split2(v.y, hh.y, ll.y);
      split2(v.z, hh.z, ll.z); split2(v.w, hh.w, ll.w);
      *(ushort4*)(sm + SWZ(b0, row)) = hh;
      *(ushort4*)(sm + XTL + SWZ(b0, row)) = ll;
    }
    // ---- stage xu K-window: 32 rows x 32 float4/row; ushort4 out -> rem*8 ----
#pragma unroll
    for (int it = 0; it < 2; ++it) {
      int idx = it * 512 + t;
      int row = idx >> 5, rem = idx & 31;
      float4 v = *(const float4*)(xu_g + (row0 + row) * 256 + p * 128 + rem * 4);
      int b0 = row * 256 + rem * 8;
      ushort4 hh, ll;
      split2(v.x, hh.x, ll.x); split2(v.y, hh.y, ll.y);
      split2(v.z, hh.z, ll.z); split2(v.w, hh.w, ll.w);
      *(ushort4*)(sm + XUH + SWZ(b0, row)) = hh;
      *(ushort4*)(sm + XUL + SWZ(b0, row)) = ll;
    }
    __syncthreads();

    // ---- stage 1 MFMA over this K-window (12 chunks of 32) ----
    {
      const char* wh = wsb + OFF_MTH;
      const char* wl = wsb + OFF_MTL;
#pragma unroll 4
      for (int kk = 0; kk < 384; kk += 32) {
        int kb = (kk + lk8 * 8) * 2;
        int k8 = ((p * 384 + kk) >> 3) + lk8;
        int o0 = (k8 * 256 + n0w + lrow) << 4;
        int o1 = (k8 * 256 + n0w + 16 + lrow) << 4;
        short8v bh0 = *(const short8v*)(wh + o0);
        short8v bh1 = *(const short8v*)(wh + o1);
        short8v bl0 = *(const short8v*)(wl + o0);
        short8v bl1 = *(const short8v*)(wl + o1);
#pragma unroll
        for (int rg = 0; rg < 2; ++rg) {
          int ar = rg * 16 + lrow;
          short8v ah = *(const short8v*)(sm + SWZ(ar * 768 + kb, ar));
          short8v al = *(const short8v*)(sm + XTL + SWZ(ar * 768 + kb, ar));
          acc1[rg][0] = __builtin_amdgcn_mfma_f32_16x16x32_bf16(ah, bh0, acc1[rg][0], 0, 0, 0);
          acc1[rg][0] = __builtin_amdgcn_mfma_f32_16x16x32_bf16(ah, bl0, acc1[rg][0], 0, 0, 0);
          acc1[rg][0] = __builtin_amdgcn_mfma_f32_16x16x32_bf16(al, bh0, acc1[rg][0], 0, 0, 0);
          acc1[rg][1] = __builtin_amdgcn_mfma_f32_16x16x32_bf16(ah, bh1, acc1[rg][1], 0, 0, 0);
          acc1[rg][1] = __builtin_amdgcn_mfma_f32_16x16x32_bf16(ah, bl1, acc1[rg][1], 0, 0, 0);
          acc1[rg][1] = __builtin_amdgcn_mfma_f32_16x16x32_bf16(al, bh1, acc1[rg][1], 0, 0, 0);
        }
      }
    }
    // ---- stage 2 MFMA over this K-window (4 chunks of 32) ----
    {
      const char* wh = wsb + OFF_MUH;
      const char* wl = wsb + OFF_MUL;
#pragma unroll
      for (int kk = 0; kk < 128; kk += 32) {
        int kb = (kk + lk8 * 8) * 2;
        int k8 = ((p * 128 + kk) >> 3) + lk8;
        int o0 = (k8 * 256 + n0w + lrow) << 4;
        int o1 = (k8 * 256 + n0w + 16 + lrow) << 4;
        short8v bh0 = *(const short8v*)(wh + o0);
        short8v bh1 = *(const short8v*)(wh + o1);
        short8v bl0 = *(const short8v*)(wl + o0);
        short8v bl1 = *(const short8v*)(wl + o1);
#pragma unroll
        for (int rg = 0; rg < 2; ++rg) {
          int ar = rg * 16 + lrow;
          short8v ah = *(const short8v*)(sm + XUH + SWZ(ar * 256 + kb, ar));
          short8v al = *(const short8v*)(sm + XUL + SWZ(ar * 256 + kb, ar));
          acc2[rg][0] = __builtin_amdgcn_mfma_f32_16x16x32_bf16(ah, bh0, acc2[rg][0], 0, 0, 0);
          acc2[rg][0] = __builtin_amdgcn_mfma_f32_16x16x32_bf16(ah, bl0, acc2[rg][0], 0, 0, 0);
          acc2[rg][0] = __builtin_amdgcn_mfma_f32_16x16x32_bf16(al, bh0, acc2[rg][0], 0, 0, 0);
          acc2[rg][1] = __builtin_amdgcn_mfma_f32_16x16x32_bf16(ah, bh1, acc2[rg][1], 0, 0, 0);
          acc2[rg][1] = __builtin_amdgcn_mfma_f32_16x16x32_bf16(ah, bl1, acc2[rg][1], 0, 0, 0);
          acc2[rg][1] = __builtin_amdgcn_mfma_f32_16x16x32_bf16(al, bh1, acc2[rg][1], 0, 0, 0);
        }
      }
    }
  }

  // ---- epilogue: acc+bias -> GLOBAL S (quarantine-compliant) ----
  // C/D map: row = rg*16 + lk8*4 + reg, col = n0w + nt*16 + lrow.
#pragma unroll
  for (int rg = 0; rg < 2; ++rg)
#pragma unroll
    for (int nt = 0; nt < 2; ++nt) {
      int n = n0w + nt * 16 + lrow;
      float bvT = bT[n], bvU = bU[n];
      int scolT = (n < 128) ? n : 256 + n;  // ts | uc
      int scolU = 128 + n;                  // tc | us
#pragma unroll
      for (int reg = 0; reg < 4; ++reg) {
        long grow = row0 + rg * 16 + lk8 * 4 + reg;
        Sg[grow * 512 + scolT] = acc1[rg][nt][reg] + bvT;
        Sg[grow * 512 + scolU] = acc2[rg][nt][reg] + bvU;
      }
    }
}

// ---------------- kB: gates/mix/ff/LN from global S (R14-verbatim k_gfl2) ----------------
// 256 threads, 16 rows/block (4096 blocks), 48 KB LDS.
// thread: rh = t>>7 (8-row half), c0 = (t&127)*2 (adjacent col pair).

__launch_bounds__(256)
__global__ void k_gfl2(const float* __restrict__ Sg, const char* __restrict__ wsb,
                       const float* __restrict__ tg_b, const float* __restrict__ ug_b,
                       const float* __restrict__ ff_b, const float* __restrict__ ln_g,
                       const float* __restrict__ ln_b, float* __restrict__ out) {
  __shared__ float lds[16 * 512 + 16 * 256];  // S 32KB + F 16KB = 48KB
  float* S = lds;             // [16][512]
  float* F = lds + 8192;      // [16][256]
  float* H = lds;             // [16][256] overlays S (dead after phase 3)

  const int t = threadIdx.x;
  const long row0 = (long)blockIdx.x * 16;

  // ---- stage S from global (coalesced): 16*512 floats = 2048 float4 ----
  {
    const float4* g = (const float4*)(Sg + row0 * 512);
    float4* l = (float4*)S;
#pragma unroll
    for (int it = 0; it < 8; ++it) l[it * 256 + t] = g[it * 256 + t];
  }
  __syncthreads();

  const int rh = t >> 7, c0 = (t & 127) * 2;
  const int r0 = rh * 8;

  // ---- phase 3: gates + mix -> F ----
  {
    const int so3 = (c0 < 128) ? 0 : 256;  // tg: S[0:256]=[ts|tc]; ug: S[256:512]=[us|uc]
    const float4* GW = (const float4*)(wsb + OFF_GW4);
    float acc[8][2] = {};
    for (int j = 0; j < 256; j += 4) {
      float4 w0 = GW[(j >> 2) * 256 + c0];
      float4 w1 = GW[(j >> 2) * 256 + c0 + 1];
#pragma unroll
      for (int r = 0; r < 8; ++r) {
        float4 sv = *(const float4*)&S[(r0 + r) * 512 + so3 + j];  // wave-uniform broadcast
        acc[r][0] = fmaf(sv.x, w0.x, fmaf(sv.y, w0.y, fmaf(sv.z, w0.z, fmaf(sv.w, w0.w, acc[r][0]))));
        acc[r][1] = fmaf(sv.x, w1.x, fmaf(sv.y, w1.y, fmaf(sv.z, w1.z, fmaf(sv.w, w1.w, acc[r][1]))));
      }
    }
    float gb0 = (c0 < 128) ? tg_b[c0] : ug_b[c0 - 128];
    float gb1 = (c0 < 128) ? tg_b[c0 + 1] : ug_b[c0 - 127];
    int am = (c0 < 128) ? c0 : 128 + c0;  // self col in S
#pragma unroll
    for (int r = 0; r < 8; ++r) {
      int row = r0 + r;
      float g0 = 1.f / (1.f + __expf(-(acc[r][0] + gb0)));
      float g1 = 1.f / (1.f + __expf(-(acc[r][1] + gb1)));
      float a0 = S[row * 512 + am],     b0v = S[row * 512 + am + 128];
      float a1 = S[row * 512 + am + 1], b1v = S[row * 512 + am + 129];
      F[row * 256 + c0]     = fmaf(g0, b0v - a0, a0);
      F[row * 256 + c0 + 1] = fmaf(g1, b1v - a1, a1);
    }
  }
  __syncthreads();

  // ---- phase 4: ff GEMM -> H (overlays dead S) ----
  {
    const float4* FW = (const float4*)(wsb + OFF_FW4);
    float acc[8][2] = {};
    for (int j = 0; j < 256; j += 4) {
      float4 w0 = FW[(j >> 2) * 256 + c0];
      float4 w1 = FW[(j >> 2) * 256 + c0 + 1];
#pragma unroll
      for (int r = 0; r < 8; ++r) {
        float4 fv = *(const float4*)&F[(r0 + r) * 256 + j];  // broadcast
        acc[r][0] = fmaf(fv.x, w0.x, fmaf(fv.y, w0.y, fmaf(fv.z, w0.z, fmaf(fv.w, w0.w, acc[r][0]))));
        acc[r][1] = fmaf(fv.x, w1.x, fmaf(fv.y, w1.y, fmaf(fv.z, w1.z, fmaf(fv.w, w1.w, acc[r][1]))));
      }
    }
    float fb0 = ff_b[c0], fb1 = ff_b[c0 + 1];
#pragma unroll
    for (int r = 0; r < 8; ++r) {
      int row = r0 + r;
      H[row * 256 + c0]     = acc[r][0] + fb0;
      H[row * 256 + c0 + 1] = acc[r][1] + fb1;
    }
  }
  __syncthreads();

  // ---- phase 5: LayerNorm + ReLU + store. 16 threads/row, 16 elems each ----
  {
    int r = t >> 4, q = t & 15;
    const float* Hr = H + r * 256 + q * 16;
    float4 hv[4];
    float s1 = 0.f, s2 = 0.f;
#pragma unroll
    for (int j = 0; j < 4; ++j) {
      hv[j] = *(const float4*)(Hr + j * 4);
      s1 += hv[j].x + hv[j].y + hv[j].z + hv[j].w;
      s2 += hv[j].x * hv[j].x + hv[j].y * hv[j].y + hv[j].z * hv[j].z + hv[j].w * hv[j].w;
    }
#pragma unroll
    for (int off = 1; off < 16; off <<= 1) {
      s1 += __shfl_xor(s1, off);
      s2 += __shfl_xor(s2, off);
    }
    float mu = s1 * (1.f / 256.f);
    float var = s2 * (1.f / 256.f) - mu * mu;
    float rstd = rsqrtf(var + 1e-5f);
    float* op = out + (row0 + r) * 256 + q * 16;
#pragma unroll
    for (int j = 0; j < 4; ++j) {
      const float* gp = ln_g + q * 16 + j * 4;
      const float* bp = ln_b + q * 16 + j * 4;
      float4 o;
      o.x = fmaf((hv[j].x - mu) * rstd, gp[0], bp[0]);
      o.y = fmaf((hv[j].y - mu) * rstd, gp[1], bp[1]);
      o.z = fmaf((hv[j].z - mu) * rstd, gp[2], bp[2]);
      o.w = fmaf((hv[j].w - mu) * rstd, gp[3], bp[3]);
      o.x = o.x > 0.f ? o.x : 0.f;
      o.y = o.y > 0.f ? o.y : 0.f;
      o.z = o.z > 0.f ? o.z : 0.f;
      o.w = o.w > 0.f ? o.w : 0.f;
      *(float4*)(op + j * 4) = o;
    }
  }
}

// ---------------- fallback: R5 fused scalar kernel (GW4-adapted; known-pass) ----------------

__launch_bounds__(256)
__global__ void k_main5(const float* __restrict__ xt_g, const float* __restrict__ xu_g,
                        const char* __restrict__ wsb,
                        const float* __restrict__ tg_b, const float* __restrict__ ug_b,
                        const float* __restrict__ ff_b, const float* __restrict__ ln_g,
                        const float* __restrict__ ln_b, float* __restrict__ out) {
  __shared__ float lds[8 * 768 + 8 * 512 + 8 * 256];  // 48 KB
  float* xt = lds;
  float* S = lds + 8 * 768;
  float* xu = lds + 8 * 768 + 8 * 512;

  const int t = threadIdx.x;
  const long row0 = (long)blockIdx.x * 8;

  {
    const float4* g = (const float4*)(xt_g + row0 * 768);
    float4* l = (float4*)xt;
#pragma unroll
    for (int it = 0; it < 6; ++it) l[it * 256 + t] = g[it * 256 + t];
    const float4* gu = (const float4*)(xu_g + row0 * 256);
    float4* lu = (float4*)xu;
#pragma unroll
    for (int it = 0; it < 2; ++it) lu[it * 256 + t] = gu[it * 256 + t];
  }
  __syncthreads();

  {
    const float4* W4 = (const float4*)(wsb + OFF_MT4);
    float acc[8];
#pragma unroll
    for (int r = 0; r < 8; ++r) acc[r] = 0.f;
    for (int k = 0; k < 768; k += 4) {
      float4 w = W4[(k >> 2) * 256 + t];
#pragma unroll
      for (int r = 0; r < 8; ++r) {
        float4 xv = *(const float4*)&xt[r * 768 + k];
        acc[r] = fmaf(w.x, xv.x, acc[r]);
        acc[r] = fmaf(w.y, xv.y, acc[r]);
        acc[r] = fmaf(w.z, xv.z, acc[r]);
        acc[r] = fmaf(w.w, xv.w, acc[r]);
      }
    }
    float bias = ((const float*)(wsb + OFF_BT))[t];
    int d = (t < 128) ? t : (256 + t);
#pragma unroll
    for (int r = 0; r < 8; ++r) S[r * 512 + d] = acc[r] + bias;
  }

  {
    const float4* W4 = (const float4*)(wsb + OFF_MU4);
    float acc[8];
#pragma unroll
    for (int r = 0; r < 8; ++r) acc[r] = 0.f;
    for (int k = 0; k < 256; k += 4) {
      float4 w = W4[(k >> 2) * 256 + t];
#pragma unroll
      for (int r = 0; r < 8; ++r) {
        float4 xv = *(const float4*)&xu[r * 256 + k];
        acc[r] = fmaf(w.x, xv.x, acc[r]);
        acc[r] = fmaf(w.y, xv.y, acc[r]);
        acc[r] = fmaf(w.z, xv.z, acc[r]);
        acc[r] = fmaf(w.w, xv.w, acc[r]);
      }
    }
    float bias = ((const float*)(wsb + OFF_BU))[t];
#pragma unroll
    for (int r = 0; r < 8; ++r) S[r * 512 + 128 + t] = acc[r] + bias;
  }
  __syncthreads();

  {
    int c = t & 127, half = t >> 7;
    const float4* W4 = (const float4*)(wsb + OFF_GW4);
    const int wcol = half * 128 + c;
    const int so = half * 256;
    float acc[8];
#pragma unroll
    for (int r = 0; r < 8; ++r) acc[r] = 0.f;
    for (int j = 0; j < 256; j += 4) {
      float4 w = W4[(j >> 2) * 256 + wcol];
#pragma unroll
      for (int r = 0; r < 8; ++r) {
        float4 sv = *(const float4*)&S[r * 512 + so + j];
        acc[r] = fmaf(w.x, sv.x, acc[r]);
        acc[r] = fmaf(w.y, sv.y, acc[r]);
        acc[r] = fmaf(w.z, sv.z, acc[r]);
        acc[r] = fmaf(w.w, sv.w, acc[r]);
      }
    }
    float gb = half ? ug_b[c] : tg_b[c];
    float* F = xu;
#pragma unroll
    for (int r = 0; r < 8; ++r) {
      float g = 1.f / (1.f + __expf(-(acc[r] + gb)));
      float a = S[r * 512 + so + c];
      float b = S[r * 512 + so + 128 + c];
      F[r * 256 + half * 128 + c] = fmaf(g, b - a, a);
    }
  }
  __syncthreads();

  {
    const float4* W4 = (const float4*)(wsb + OFF_FW4);
    const float* F = xu;
    float acc[8];
#pragma unroll
    for (int r = 0; r < 8; ++r) acc[r] = 0.f;
    for (int j = 0; j < 256; j += 4) {
      float4 w = W4[(j >> 2) * 256 + t];
#pragma unroll
      for (int r = 0; r < 8; ++r) {
        float4 fv = *(const float4*)&F[r * 256 + j];
        acc[r] = fmaf(w.x, fv.x, acc[r]);
        acc[r] = fmaf(w.y, fv.y, acc[r]);
        acc[r] = fmaf(w.z, fv.z, acc[r]);
        acc[r] = fmaf(w.w, fv.w, acc[r]);
      }
    }
    float* H = xt;
    float bias = ff_b[t];
#pragma unroll
    for (int r = 0; r < 8; ++r) H[r * 256 + t] = acc[r] + bias;
  }
  __syncthreads();

  {
    const float* H = xt;
    int r = t >> 5, q = t & 31;
    const float* Hr = H + r * 256 + q * 8;
    float s1 = 0.f, s2 = 0.f;
#pragma unroll
    for (int i = 0; i < 8; ++i) {
      float v = Hr[i];
      s1 += v;
      s2 += v * v;
    }
#pragma unroll
    for (int off = 1; off < 32; off <<= 1) {
      s1 += __shfl_xor(s1, off);
      s2 += __shfl_xor(s2, off);
    }
    float mu = s1 * (1.f / 256.f);
    float var = s2 * (1.f / 256.f) - mu * mu;
    float rstd = rsqrtf(var + 1e-5f);
    float* op = out + (row0 + r) * 256 + q * 8;
#pragma unroll
    for (int i = 0; i < 8; ++i) {
      float v = (Hr[i] - mu) * rstd * ln_g[q * 8 + i] + ln_b[q * 8 + i];
      op[i] = v > 0.f ? v : 0.f;
    }
  }
}

}  // namespace

extern "C" void kernel_launch(void* const* d_in, const int* in_sizes, int n_in,
                              void* d_out, int out_size, void* d_ws, size_t ws_size,
                              hipStream_t stream) {
  const float* text = (const float*)d_in[0];
  const float* user = (const float*)d_in[1];
  const float* tm_w = (const float*)d_in[2];
  const float* tm_b = (const float*)d_in[3];
  const float* um_w = (const float*)d_in[4];
  const float* um_b = (const float*)d_in[5];
  const float* ipw = (const float*)d_in[6];
  const float* ipb = (const float*)d_in[7];
  const float* opw = (const float*)d_in[8];
  const float* opb = (const float*)d_in[9];
  const float* tg_w = (const float*)d_in[10];
  const float* tg_b = (const float*)d_in[11];
  const float* ug_w = (const float*)d_in[12];
  const float* ug_b = (const float*)d_in[13];
  const float* ff_w = (const float*)d_in[14];
  const float* ff_b = (const float*)d_in[15];
  const float* ln_g = (const float*)d_in[16];
  const float* ln_b = (const float*)d_in[17];
  char* wsb = (char*)d_ws;
  float* out = (float*)d_out;

  // common precompute
  k_combine<<<256, 256, 0, stream>>>(ipw, opw, wsb);
  k_combine_bias<<<2, 256, 0, stream>>>(ipb, opb, opw, wsb);
  k_bias_tu<<<2, 256, 0, stream>>>(tm_b, um_b, wsb);
  k_pack_gw4<<<256, 256, 0, stream>>>(tg_w, ug_w, wsb);
  k_transpose4<<<256, 256, 0, stream>>>(ff_w, (float*)(wsb + OFF_FW4), 256, 256);

  if ((long)ws_size >= WS_NEED) {
    // fast path: MFMA front (M=32, ~150us) -> global S -> R14 kB (285us)
    float* Sg = (float*)(wsb + OFF_S);
    k_mt_hl<<<768, 256, 0, stream>>>(tm_w, wsb);
    k_mu_hl<<<256, 256, 0, stream>>>(um_w, wsb);
    k_s12<<<2048, 512, 0, stream>>>(text, user, wsb, Sg);
    k_gfl2<<<4096, 256, 0, stream>>>(Sg, wsb, tg_b, ug_b, ff_b, ln_g, ln_b, out);
  } else {
    // fallback: R5 fused scalar (known-pass)
    k_mt4<<<768, 256, 0, stream>>>(tm_w, wsb);
    k_mu4<<<256, 256, 0, stream>>>(um_w, wsb);
    k_main5<<<8192, 256, 0, stream>>>(text, user, wsb, tg_b, ug_b, ff_b, ln_g, ln_b, out);
  }
}

// Round 20
// 500.051 us; speedup vs baseline: 1.4900x; 1.0782x over previous
//
#include <hip/hip_runtime.h>
#include <hip/hip_bf16.h>

// MultiViewFusion — round 20: fold gate GEMM + sigmoid + mix into kA.
// Evidence ledger:
//   R5 PASS (1338us) scalar. R6-R9 FAIL: MFMA acc->LDS->read corrupts;
//   QUARANTINE: acc exits only via VALU->global. R10: MFMA front coordinate-
//   exact. R14/R19: k_gfl2 (285us) = kB optimum; R16/R19: k_s12 M=32 = kA
//   optimum. R19 PASS 539us (best).
// R20 algebra: gate logits are linear in (text,user):
//   tg_logit = text@(Wt1@Mts).T + user@(Wt2@Mtc).T + gb
//   ug_logit = text@(Wu2@Muc).T + user@(Wu1@Mus).T + gb
// The SAME MFMA lane holds ts/uc (acc1), tc/us (acc2), and the folded gate
// accs -> sigmoid+mix complete in kA's register epilogue; kA writes F (67MB)
// instead of S (134MB). Gate columns use single-term (A-hi x G-hi) MFMA;
// sigmoid slope x small |b-a| attenuates bf16 error (est absmax 0.02-0.05).
// kB = k_ffln: stage F -> ff GEMM (R14-validated 2-col) -> LN. 32KB LDS.

namespace {

typedef __attribute__((ext_vector_type(8))) short short8v;   // 8 bf16 = 4 VGPR
typedef __attribute__((ext_vector_type(4))) float floatx4;   // MFMA C/D

// workspace byte offsets
constexpr int OFF_CW  = 0;        // f32 CWt[4][128][128]
constexpr int OFF_CB  = 262144;   // f32 cv[4][128]
constexpr int OFF_BT  = 264192;   // f32 bT[256]  [ts|uc]
constexpr int OFF_BU  = 265216;   // f32 bU[256]  [tc|us]
constexpr int OFF_MTH = 266240;   // bf16 M_text hi packed [96][256][8]
constexpr int OFF_MTL = 659456;   // bf16 M_text lo
constexpr int OFF_MUH = 1052672;  // bf16 M_user hi packed [32][256][8]
constexpr int OFF_MUL = 1183744;  // bf16 M_user lo
constexpr int OFF_GW4 = 1314816;  // f32 gate W [64][256][4] (fallback only)
constexpr int OFF_FW4 = 1576960;  // f32 ff  W  [64][256][4]
constexpr int OFF_MT4 = 1839104;  // f32 M_text pack [192][256][4]
constexpr int OFF_MU4 = 2625536;  // f32 M_user pack [64][256][4]
constexpr int OFF_GTH = 2887680;  // bf16 Gt hi [96][256][8]  (gate text-part)
constexpr int OFF_GUH = 3280896;  // bf16 Gu hi [32][256][8]  (gate user-part)
constexpr int OFF_GB2 = 3411968;  // f32 gbias[256]
constexpr long OFF_F  = 3412992;  // f32 F [65536][256] = 67108864 B
constexpr long WS_NEED = OFF_F + 67108864L;

__device__ inline unsigned short f2b(float f) {
  __hip_bfloat16 h = __float2bfloat16(f);
  return __builtin_bit_cast(unsigned short, h);
}
__device__ inline float b2f(unsigned short u) {
  unsigned int v = ((unsigned int)u) << 16;
  return __builtin_bit_cast(float, v);
}
__device__ inline void split2(float v, unsigned short& h, unsigned short& l) {
  h = f2b(v);
  l = f2b(v - b2f(h));
}

// ---------------- precompute (tiny, L2-resident) ----------------

__global__ void k_combine(const float* __restrict__ ipw, const float* __restrict__ opw,
                          char* __restrict__ wsb) {
  float* cw = (float*)(wsb + OFF_CW);
  int n = blockIdx.x * 256 + threadIdx.x;
  int i = n >> 14, o = (n >> 7) & 127, d = n & 127;
  const float* op = opw + i * 16384 + o * 128;
  const float* iv = ipw + i * 49152 + 256 * 128 + d;
  float s = 0.f;
#pragma unroll 4
  for (int m = 0; m < 128; ++m) s = fmaf(op[m], iv[m * 128], s);
  cw[i * 16384 + d * 128 + o] = s;
}

__global__ void k_combine_bias(const float* __restrict__ ipb, const float* __restrict__ opb,
                               const float* __restrict__ opw, char* __restrict__ wsb) {
  float* cb = (float*)(wsb + OFF_CB);
  int t = blockIdx.x * 256 + threadIdx.x;
  int i = t >> 7, o = t & 127;
  const float* op = opw + i * 16384 + o * 128;
  const float* ib = ipb + i * 384 + 256;
  float s = opb[i * 128 + o];
#pragma unroll 4
  for (int m = 0; m < 128; ++m) s = fmaf(op[m], ib[m], s);
  cb[t] = s;
}

// hi/lo bf16 packs for MFMA S-columns
__global__ void k_mt_hl(const float* __restrict__ tm_w, char* __restrict__ wsb) {
  const float* cw = (const float*)(wsb + OFF_CW);
  unsigned short* dh = (unsigned short*)(wsb + OFF_MTH);
  unsigned short* dl = (unsigned short*)(wsb + OFF_MTL);
  int n = blockIdx.x * 256 + threadIdx.x;  // 768*256
  int k = n >> 8, c = n & 255;
  const float* p = cw + ((c >> 7) ? 3 : 0) * 16384 + (c & 127);
  float s = 0.f;
#pragma unroll 4
  for (int d = 0; d < 128; ++d) s = fmaf(p[d * 128], tm_w[d * 768 + k], s);
  unsigned short h, l;
  split2(s, h, l);
  int ofs = (((k >> 3) * 256 + c) << 3) + (k & 7);
  dh[ofs] = h;
  dl[ofs] = l;
}

__global__ void k_mu_hl(const float* __restrict__ um_w, char* __restrict__ wsb) {
  const float* cw = (const float*)(wsb + OFF_CW);
  unsigned short* dh = (unsigned short*)(wsb + OFF_MUH);
  unsigned short* dl = (unsigned short*)(wsb + OFF_MUL);
  int n = blockIdx.x * 256 + threadIdx.x;  // 256*256
  int k = n >> 8, c = n & 255;
  const float* p = cw + ((c >> 7) ? 1 : 2) * 16384 + (c & 127);
  float s = 0.f;
#pragma unroll 4
  for (int d = 0; d < 128; ++d) s = fmaf(p[d * 128], um_w[d * 256 + k], s);
  unsigned short h, l;
  split2(s, h, l);
  int ofs = (((k >> 3) * 256 + c) << 3) + (k & 7);
  dh[ofs] = h;
  dl[ofs] = l;
}

// f32 [K/4][256][4] packs (used by gate fold AND fallback)
__global__ void k_mt4(const float* __restrict__ tm_w, char* __restrict__ wsb) {
  const float* cw = (const float*)(wsb + OFF_CW);
  float* dst = (float*)(wsb + OFF_MT4);
  int n = blockIdx.x * 256 + threadIdx.x;  // 768*256
  int k = n >> 8, c = n & 255;
  const float* p = cw + ((c >> 7) ? 3 : 0) * 16384 + (c & 127);
  float s = 0.f;
#pragma unroll 4
  for (int d = 0; d < 128; ++d) s = fmaf(p[d * 128], tm_w[d * 768 + k], s);
  dst[(((k >> 2) * 256 + c) << 2) + (k & 3)] = s;
}

__global__ void k_mu4(const float* __restrict__ um_w, char* __restrict__ wsb) {
  const float* cw = (const float*)(wsb + OFF_CW);
  float* dst = (float*)(wsb + OFF_MU4);
  int n = blockIdx.x * 256 + threadIdx.x;  // 256*256
  int k = n >> 8, c = n & 255;
  const float* p = cw + ((c >> 7) ? 1 : 2) * 16384 + (c & 127);
  float s = 0.f;
#pragma unroll 4
  for (int d = 0; d < 128; ++d) s = fmaf(p[d * 128], um_w[d * 256 + k], s);
  dst[(((k >> 2) * 256 + c) << 2) + (k & 3)] = s;
}

__global__ void k_bias_tu(const float* __restrict__ tm_b, const float* __restrict__ um_b,
                          char* __restrict__ wsb) {
  const float* cw = (const float*)(wsb + OFF_CW);
  const float* cb = (const float*)(wsb + OFF_CB);
  float* bT = (float*)(wsb + OFF_BT);
  float* bU = (float*)(wsb + OFF_BU);
  int t = blockIdx.x * 256 + threadIdx.x;
  if (t < 256) {
    int sel = (t >> 7) ? 3 : 0;
    const float* p = cw + sel * 16384 + (t & 127);
    float s = cb[sel * 128 + (t & 127)];
#pragma unroll 4
    for (int d = 0; d < 128; ++d) s = fmaf(p[d * 128], tm_b[d], s);
    bT[t] = s;
  } else {
    int c = t - 256;
    int sel = (c >> 7) ? 1 : 2;
    const float* p = cw + sel * 16384 + (c & 127);
    float s = cb[sel * 128 + (c & 127)];
#pragma unroll 4
    for (int d = 0; d < 128; ++d) s = fmaf(p[d * 128], um_b[d], s);
    bU[c] = s;
  }
}

// Gt[n][k] (text gate part), bf16 hi pack [96][256][8].
// n<128: sum_m tg_w[n][m]   * Mts[m][k]  (Mts = MT4 col m)
// n>=128: sum_m ug_w[n'][128+m] * Muc[m][k]  (Muc = MT4 col 128+m)
__global__ void k_gt(const float* __restrict__ tg_w, const float* __restrict__ ug_w,
                     char* __restrict__ wsb) {
  const float* mt = (const float*)(wsb + OFF_MT4);
  unsigned short* dst = (unsigned short*)(wsb + OFF_GTH);
  int idx = blockIdx.x * 256 + threadIdx.x;  // 768*256
  int k = idx >> 8, n = idx & 255;
  const float* mb = mt + (((k >> 2) * 256) << 2) + (k & 3);  // + m*4
  float s = 0.f;
  if (n < 128) {
    const float* w = tg_w + n * 256;
#pragma unroll 4
    for (int m = 0; m < 128; ++m) s = fmaf(w[m], mb[m * 4], s);
  } else {
    const float* w = ug_w + (n - 128) * 256 + 128;
#pragma unroll 4
    for (int m = 0; m < 128; ++m) s = fmaf(w[m], mb[(128 + m) * 4], s);
  }
  dst[(((k >> 3) * 256 + n) << 3) + (k & 7)] = f2b(s);
}

// Gu[n][k] (user gate part), bf16 hi pack [32][256][8].
// n<128: sum_m tg_w[n][128+m] * Mtc[m][k]  (Mtc = MU4 col m)
// n>=128: sum_m ug_w[n'][m]   * Mus[m][k]  (Mus = MU4 col 128+m)
__global__ void k_gu(const float* __restrict__ tg_w, const float* __restrict__ ug_w,
                     char* __restrict__ wsb) {
  const float* mu = (const float*)(wsb + OFF_MU4);
  unsigned short* dst = (unsigned short*)(wsb + OFF_GUH);
  int idx = blockIdx.x * 256 + threadIdx.x;  // 256*256
  int k = idx >> 8, n = idx & 255;
  const float* mb = mu + (((k >> 2) * 256) << 2) + (k & 3);
  float s = 0.f;
  if (n < 128) {
    const float* w = tg_w + n * 256 + 128;
#pragma unroll 4
    for (int m = 0; m < 128; ++m) s = fmaf(w[m], mb[m * 4], s);
  } else {
    const float* w = ug_w + (n - 128) * 256;
#pragma unroll 4
    for (int m = 0; m < 128; ++m) s = fmaf(w[m], mb[(128 + m) * 4], s);
  }
  dst[(((k >> 3) * 256 + n) << 3) + (k & 7)] = f2b(s);
}

// gbias[n]: n<128: tg_b[n] + tg_w[n][:128].bT[:128] + tg_w[n][128:].bU[:128]
//           n>=128: ug_b[n'] + ug_w[n'][:128].bU[128:] + ug_w[n'][128:].bT[128:]
__global__ void k_gbias(const float* __restrict__ tg_w, const float* __restrict__ tg_b,
                        const float* __restrict__ ug_w, const float* __restrict__ ug_b,
                        char* __restrict__ wsb) {
  const float* bT = (const float*)(wsb + OFF_BT);
  const float* bU = (const float*)(wsb + OFF_BU);
  float* gb2 = (float*)(wsb + OFF_GB2);
  int n = threadIdx.x;  // 256
  float s;
  if (n < 128) {
    s = tg_b[n];
    const float* w = tg_w + n * 256;
#pragma unroll 4
    for (int m = 0; m < 128; ++m) s = fmaf(w[m], bT[m], s);
#pragma unroll 4
    for (int m = 0; m < 128; ++m) s = fmaf(w[128 + m], bU[m], s);
  } else {
    int np = n - 128;
    s = ug_b[np];
    const float* w = ug_w + np * 256;
#pragma unroll 4
    for (int m = 0; m < 128; ++m) s = fmaf(w[m], bU[128 + m], s);
#pragma unroll 4
    for (int m = 0; m < 128; ++m) s = fmaf(w[128 + m], bT[128 + m], s);
  }
  gb2[n] = s;
}

// combined gate pack (fallback only)
__global__ void k_pack_gw4(const float* __restrict__ tg_w, const float* __restrict__ ug_w,
                           char* __restrict__ wsb) {
  float* dst = (float*)(wsb + OFF_GW4);
  int idx = blockIdx.x * 256 + threadIdx.x;
  int j = idx >> 8, n = idx & 255;
  float v = (n < 128) ? tg_w[n * 256 + j] : ug_w[(n - 128) * 256 + j];
  dst[(((j >> 2) * 256 + n) << 2) + (j & 3)] = v;
}

__global__ void k_transpose4(const float* __restrict__ src, float* __restrict__ dst,
                             int R, int C) {
  int n = blockIdx.x * 256 + threadIdx.x;
  if (n >= R * C) return;
  int o = n / C, k = n % C;
  dst[(((k >> 2) * R + o) << 2) + (k & 3)] = src[n];
}

// ---------------- kA: MFMA stages 1/2 + folded gates -> F global ----------------
// R16 k_s12 structure + 2 gate MFMA per chunk per rg (A-hi x G-hi single term).
// Epilogue: logit = accG1+accG2+gbias -> sigmoid -> mix -> F[row][n] (global).

#define SWZ(byte, row) ((byte) ^ (((row) & 7) << 4))

__launch_bounds__(512)
__global__ void k_s12g(const float* __restrict__ xt_g, const float* __restrict__ xu_g,
                       const char* __restrict__ wsb, float* __restrict__ Fg) {
  __shared__ __align__(16) char sm[65536];
  constexpr int XTL = 24576;
  constexpr int XUH = 49152;
  constexpr int XUL = 57344;

  const int t = threadIdx.x;
  const int wave = t >> 6, lane = t & 63;
  const int lrow = lane & 15;
  const int lk8 = lane >> 4;
  const int n0w = wave * 32;
  const long row0 = (long)blockIdx.x * 32;

  const float* bT = (const float*)(wsb + OFF_BT);
  const float* bU = (const float*)(wsb + OFF_BU);
  const float* gb2 = (const float*)(wsb + OFF_GB2);

  floatx4 zero = {0.f, 0.f, 0.f, 0.f};
  floatx4 acc1[2][2] = {{zero, zero}, {zero, zero}};  // [rowgrp][nt] text-side (ts|uc)
  floatx4 acc2[2][2] = {{zero, zero}, {zero, zero}};  // user-side (tc|us)
  floatx4 accG1[2][2] = {{zero, zero}, {zero, zero}}; // gate text part
  floatx4 accG2[2][2] = {{zero, zero}, {zero, zero}}; // gate user part

  for (int p = 0; p < 2; ++p) {
    if (p) __syncthreads();

    // ---- stage xt K-window (R16-verbatim, rem*8) ----
#pragma unroll
    for (int it = 0; it < 6; ++it) {
      int idx = it * 512 + t;
      int row = idx / 96, rem = idx - row * 96;
      float4 v = *(const float4*)(xt_g + (row0 + row) * 768 + p * 384 + rem * 4);
      int b0 = row * 768 + rem * 8;
      ushort4 hh, ll;
      split2(v.x, hh.x, ll.x); split2(v.y, hh.y, ll.y);
      split2(v.z, hh.z, ll.z); split2(v.w, hh.w, ll.w);
      *(ushort4*)(sm + SWZ(b0, row)) = hh;
      *(ushort4*)(sm + XTL + SWZ(b0, row)) = ll;
    }
    // ---- stage xu K-window ----
#pragma unroll
    for (int it = 0; it < 2; ++it) {
      int idx = it * 512 + t;
      int row = idx >> 5, rem = idx & 31;
      float4 v = *(const float4*)(xu_g + (row0 + row) * 256 + p * 128 + rem * 4);
      int b0 = row * 256 + rem * 8;
      ushort4 hh, ll;
      split2(v.x, hh.x, ll.x); split2(v.y, hh.y, ll.y);
      split2(v.z, hh.z, ll.z); split2(v.w, hh.w, ll.w);
      *(ushort4*)(sm + XUH + SWZ(b0, row)) = hh;
      *(ushort4*)(sm + XUL + SWZ(b0, row)) = ll;
    }
    __syncthreads();

    // ---- stage 1 MFMA (S cols 3-term + gate cols 1-term) ----
    {
      const char* wh = wsb + OFF_MTH;
      const char* wl = wsb + OFF_MTL;
      const char* gt = wsb + OFF_GTH;
#pragma unroll 4
      for (int kk = 0; kk < 384; kk += 32) {
        int kb = (kk + lk8 * 8) * 2;
        int k8 = ((p * 384 + kk) >> 3) + lk8;
        int o0 = (k8 * 256 + n0w + lrow) << 4;
        int o1 = (k8 * 256 + n0w + 16 + lrow) << 4;
        short8v bh0 = *(const short8v*)(wh + o0);
        short8v bh1 = *(const short8v*)(wh + o1);
        short8v bl0 = *(const short8v*)(wl + o0);
        short8v bl1 = *(const short8v*)(wl + o1);
        short8v g0 = *(const short8v*)(gt + o0);
        short8v g1 = *(const short8v*)(gt + o1);
#pragma unroll
        for (int rg = 0; rg < 2; ++rg) {
          int ar = rg * 16 + lrow;
          short8v ah = *(const short8v*)(sm + SWZ(ar * 768 + kb, ar));
          short8v al = *(const short8v*)(sm + XTL + SWZ(ar * 768 + kb, ar));
          acc1[rg][0] = __builtin_amdgcn_mfma_f32_16x16x32_bf16(ah, bh0, acc1[rg][0], 0, 0, 0);
          acc1[rg][0] = __builtin_amdgcn_mfma_f32_16x16x32_bf16(ah, bl0, acc1[rg][0], 0, 0, 0);
          acc1[rg][0] = __builtin_amdgcn_mfma_f32_16x16x32_bf16(al, bh0, acc1[rg][0], 0, 0, 0);
          acc1[rg][1] = __builtin_amdgcn_mfma_f32_16x16x32_bf16(ah, bh1, acc1[rg][1], 0, 0, 0);
          acc1[rg][1] = __builtin_amdgcn_mfma_f32_16x16x32_bf16(ah, bl1, acc1[rg][1], 0, 0, 0);
          acc1[rg][1] = __builtin_amdgcn_mfma_f32_16x16x32_bf16(al, bh1, acc1[rg][1], 0, 0, 0);
          accG1[rg][0] = __builtin_amdgcn_mfma_f32_16x16x32_bf16(ah, g0, accG1[rg][0], 0, 0, 0);
          accG1[rg][1] = __builtin_amdgcn_mfma_f32_16x16x32_bf16(ah, g1, accG1[rg][1], 0, 0, 0);
        }
      }
    }
    // ---- stage 2 MFMA ----
    {
      const char* wh = wsb + OFF_MUH;
      const char* wl = wsb + OFF_MUL;
      const char* gu = wsb + OFF_GUH;
#pragma unroll
      for (int kk = 0; kk < 128; kk += 32) {
        int kb = (kk + lk8 * 8) * 2;
        int k8 = ((p * 128 + kk) >> 3) + lk8;
        int o0 = (k8 * 256 + n0w + lrow) << 4;
        int o1 = (k8 * 256 + n0w + 16 + lrow) << 4;
        short8v bh0 = *(const short8v*)(wh + o0);
        short8v bh1 = *(const short8v*)(wh + o1);
        short8v bl0 = *(const short8v*)(wl + o0);
        short8v bl1 = *(const short8v*)(wl + o1);
        short8v g0 = *(const short8v*)(gu + o0);
        short8v g1 = *(const short8v*)(gu + o1);
#pragma unroll
        for (int rg = 0; rg < 2; ++rg) {
          int ar = rg * 16 + lrow;
          short8v ah = *(const short8v*)(sm + XUH + SWZ(ar * 256 + kb, ar));
          short8v al = *(const short8v*)(sm + XUL + SWZ(ar * 256 + kb, ar));
          acc2[rg][0] = __builtin_amdgcn_mfma_f32_16x16x32_bf16(ah, bh0, acc2[rg][0], 0, 0, 0);
          acc2[rg][0] = __builtin_amdgcn_mfma_f32_16x16x32_bf16(ah, bl0, acc2[rg][0], 0, 0, 0);
          acc2[rg][0] = __builtin_amdgcn_mfma_f32_16x16x32_bf16(al, bh0, acc2[rg][0], 0, 0, 0);
          acc2[rg][1] = __builtin_amdgcn_mfma_f32_16x16x32_bf16(ah, bh1, acc2[rg][1], 0, 0, 0);
          acc2[rg][1] = __builtin_amdgcn_mfma_f32_16x16x32_bf16(ah, bl1, acc2[rg][1], 0, 0, 0);
          acc2[rg][1] = __builtin_amdgcn_mfma_f32_16x16x32_bf16(al, bh1, acc2[rg][1], 0, 0, 0);
          accG2[rg][0] = __builtin_amdgcn_mfma_f32_16x16x32_bf16(ah, g0, accG2[rg][0], 0, 0, 0);
          accG2[rg][1] = __builtin_amdgcn_mfma_f32_16x16x32_bf16(ah, g1, accG2[rg][1], 0, 0, 0);
        }
      }
    }
  }

  // ---- epilogue: sigmoid + mix in-register -> F global (quarantine-compliant) ----
  // lane holds: acc1 = ts(n<128)|uc(n>=128) nobias; acc2 = tc|us nobias;
  // logit = accG1 + accG2 + gbias[n]. F col = n for both halves.
#pragma unroll
  for (int rg = 0; rg < 2; ++rg)
#pragma unroll
    for (int nt = 0; nt < 2; ++nt) {
      int n = n0w + nt * 16 + lrow;
      float bvT = bT[n], bvU = bU[n], gbn = gb2[n];
#pragma unroll
      for (int reg = 0; reg < 4; ++reg) {
        long row = row0 + rg * 16 + lk8 * 4 + reg;
        float a1 = acc1[rg][nt][reg] + bvT;  // ts | uc
        float a2 = acc2[rg][nt][reg] + bvU;  // tc | us
        float logit = accG1[rg][nt][reg] + accG2[rg][nt][reg] + gbn;
        float g = 1.f / (1.f + __expf(-logit));
        float f = (n < 128) ? fmaf(g, a2 - a1, a1)   // self=ts, cross=tc
                            : fmaf(g, a1 - a2, a2);  // self=us, cross=uc
        Fg[row * 256 + n] = f;
      }
    }
}

// ---------------- kB: ff GEMM + LN from global F (R14 phase-4/5 verbatim) ----------------
// 256 threads, 16 rows/block (4096 blocks), 32 KB LDS -> 5 blocks/CU.

__launch_bounds__(256)
__global__ void k_ffln(const float* __restrict__ Fg, const char* __restrict__ wsb,
                       const float* __restrict__ ff_b, const float* __restrict__ ln_g,
                       const float* __restrict__ ln_b, float* __restrict__ out) {
  __shared__ float lds[16 * 256 + 16 * 256];  // F 16KB + H 16KB
  float* F = lds;
  float* H = lds + 4096;

  const int t = threadIdx.x;
  const long row0 = (long)blockIdx.x * 16;

  // ---- stage F from global (coalesced): 1024 float4 ----
  {
    const float4* g = (const float4*)(Fg + row0 * 256);
    float4* l = (float4*)F;
#pragma unroll
    for (int it = 0; it < 4; ++it) l[it * 256 + t] = g[it * 256 + t];
  }
  __syncthreads();

  const int rh = t >> 7, c0 = (t & 127) * 2;
  const int r0 = rh * 8;

  // ---- ff GEMM -> H (R14 k_gfl2 phase-4 verbatim) ----
  {
    const float4* FW = (const float4*)(wsb + OFF_FW4);
    float acc[8][2] = {};
    for (int j = 0; j < 256; j += 4) {
      float4 w0 = FW[(j >> 2) * 256 + c0];
      float4 w1 = FW[(j >> 2) * 256 + c0 + 1];
#pragma unroll
      for (int r = 0; r < 8; ++r) {
        float4 fv = *(const float4*)&F[(r0 + r) * 256 + j];  // broadcast
        acc[r][0] = fmaf(fv.x, w0.x, fmaf(fv.y, w0.y, fmaf(fv.z, w0.z, fmaf(fv.w, w0.w, acc[r][0]))));
        acc[r][1] = fmaf(fv.x, w1.x, fmaf(fv.y, w1.y, fmaf(fv.z, w1.z, fmaf(fv.w, w1.w, acc[r][1]))));
      }
    }
    float fb0 = ff_b[c0], fb1 = ff_b[c0 + 1];
#pragma unroll
    for (int r = 0; r < 8; ++r) {
      int row = r0 + r;
      H[row * 256 + c0]     = acc[r][0] + fb0;
      H[row * 256 + c0 + 1] = acc[r][1] + fb1;
    }
  }
  __syncthreads();

  // ---- LayerNorm + ReLU + store (R14 phase-5 verbatim) ----
  {
    int r = t >> 4, q = t & 15;
    const float* Hr = H + r * 256 + q * 16;
    float4 hv[4];
    float s1 = 0.f, s2 = 0.f;
#pragma unroll
    for (int j = 0; j < 4; ++j) {
      hv[j] = *(const float4*)(Hr + j * 4);
      s1 += hv[j].x + hv[j].y + hv[j].z + hv[j].w;
      s2 += hv[j].x * hv[j].x + hv[j].y * hv[j].y + hv[j].z * hv[j].z + hv[j].w * hv[j].w;
    }
#pragma unroll
    for (int off = 1; off < 16; off <<= 1) {
      s1 += __shfl_xor(s1, off);
      s2 += __shfl_xor(s2, off);
    }
    float mu = s1 * (1.f / 256.f);
    float var = s2 * (1.f / 256.f) - mu * mu;
    float rstd = rsqrtf(var + 1e-5f);
    float* op = out + (row0 + r) * 256 + q * 16;
#pragma unroll
    for (int j = 0; j < 4; ++j) {
      const float* gp = ln_g + q * 16 + j * 4;
      const float* bp = ln_b + q * 16 + j * 4;
      float4 o;
      o.x = fmaf((hv[j].x - mu) * rstd, gp[0], bp[0]);
      o.y = fmaf((hv[j].y - mu) * rstd, gp[1], bp[1]);
      o.z = fmaf((hv[j].z - mu) * rstd, gp[2], bp[2]);
      o.w = fmaf((hv[j].w - mu) * rstd, gp[3], bp[3]);
      o.x = o.x > 0.f ? o.x : 0.f;
      o.y = o.y > 0.f ? o.y : 0.f;
      o.z = o.z > 0.f ? o.z : 0.f;
      o.w = o.w > 0.f ? o.w : 0.f;
      *(float4*)(op + j * 4) = o;
    }
  }
}

// ---------------- fallback: R5 fused scalar kernel (known-pass) ----------------

__launch_bounds__(256)
__global__ void k_main5(const float* __restrict__ xt_g, const float* __restrict__ xu_g,
                        const char* __restrict__ wsb,
                        const float* __restrict__ tg_b, const float* __restrict__ ug_b,
                        const float* __restrict__ ff_b, const float* __restrict__ ln_g,
                        const float* __restrict__ ln_b, float* __restrict__ out) {
  __shared__ float lds[8 * 768 + 8 * 512 + 8 * 256];  // 48 KB
  float* xt = lds;
  float* S = lds + 8 * 768;
  float* xu = lds + 8 * 768 + 8 * 512;

  const int t = threadIdx.x;
  const long row0 = (long)blockIdx.x * 8;

  {
    const float4* g = (const float4*)(xt_g + row0 * 768);
    float4* l = (float4*)xt;
#pragma unroll
    for (int it = 0; it < 6; ++it) l[it * 256 + t] = g[it * 256 + t];
    const float4* gu = (const float4*)(xu_g + row0 * 256);
    float4* lu = (float4*)xu;
#pragma unroll
    for (int it = 0; it < 2; ++it) lu[it * 256 + t] = gu[it * 256 + t];
  }
  __syncthreads();

  {
    const float4* W4 = (const float4*)(wsb + OFF_MT4);
    float acc[8];
#pragma unroll
    for (int r = 0; r < 8; ++r) acc[r] = 0.f;
    for (int k = 0; k < 768; k += 4) {
      float4 w = W4[(k >> 2) * 256 + t];
#pragma unroll
      for (int r = 0; r < 8; ++r) {
        float4 xv = *(const float4*)&xt[r * 768 + k];
        acc[r] = fmaf(w.x, xv.x, acc[r]);
        acc[r] = fmaf(w.y, xv.y, acc[r]);
        acc[r] = fmaf(w.z, xv.z, acc[r]);
        acc[r] = fmaf(w.w, xv.w, acc[r]);
      }
    }
    float bias = ((const float*)(wsb + OFF_BT))[t];
    int d = (t < 128) ? t : (256 + t);
#pragma unroll
    for (int r = 0; r < 8; ++r) S[r * 512 + d] = acc[r] + bias;
  }

  {
    const float4* W4 = (const float4*)(wsb + OFF_MU4);
    float acc[8];
#pragma unroll
    for (int r = 0; r < 8; ++r) acc[r] = 0.f;
    for (int k = 0; k < 256; k += 4) {
      float4 w = W4[(k >> 2) * 256 + t];
#pragma unroll
      for (int r = 0; r < 8; ++r) {
        float4 xv = *(const float4*)&xu[r * 256 + k];
        acc[r] = fmaf(w.x, xv.x, acc[r]);
        acc[r] = fmaf(w.y, xv.y, acc[r]);
        acc[r] = fmaf(w.z, xv.z, acc[r]);
        acc[r] = fmaf(w.w, xv.w, acc[r]);
      }
    }
    float bias = ((const float*)(wsb + OFF_BU))[t];
#pragma unroll
    for (int r = 0; r < 8; ++r) S[r * 512 + 128 + t] = acc[r] + bias;
  }
  __syncthreads();

  {
    int c = t & 127, half = t >> 7;
    const float4* W4 = (const float4*)(wsb + OFF_GW4);
    const int wcol = half * 128 + c;
    const int so = half * 256;
    float acc[8];
#pragma unroll
    for (int r = 0; r < 8; ++r) acc[r] = 0.f;
    for (int j = 0; j < 256; j += 4) {
      float4 w = W4[(j >> 2) * 256 + wcol];
#pragma unroll
      for (int r = 0; r < 8; ++r) {
        float4 sv = *(const float4*)&S[r * 512 + so + j];
        acc[r] = fmaf(w.x, sv.x, acc[r]);
        acc[r] = fmaf(w.y, sv.y, acc[r]);
        acc[r] = fmaf(w.z, sv.z, acc[r]);
        acc[r] = fmaf(w.w, sv.w, acc[r]);
      }
    }
    float gb = half ? ug_b[c] : tg_b[c];
    float* F = xu;
#pragma unroll
    for (int r = 0; r < 8; ++r) {
      float g = 1.f / (1.f + __expf(-(acc[r] + gb)));
      float a = S[r * 512 + so + c];
      float b = S[r * 512 + so + 128 + c];
      F[r * 256 + half * 128 + c] = fmaf(g, b - a, a);
    }
  }
  __syncthreads();

  {
    const float4* W4 = (const float4*)(wsb + OFF_FW4);
    const float* F = xu;
    float acc[8];
#pragma unroll
    for (int r = 0; r < 8; ++r) acc[r] = 0.f;
    for (int j = 0; j < 256; j += 4) {
      float4 w = W4[(j >> 2) * 256 + t];
#pragma unroll
      for (int r = 0; r < 8; ++r) {
        float4 fv = *(const float4*)&F[r * 256 + j];
        acc[r] = fmaf(w.x, fv.x, acc[r]);
        acc[r] = fmaf(w.y, fv.y, acc[r]);
        acc[r] = fmaf(w.z, fv.z, acc[r]);
        acc[r] = fmaf(w.w, fv.w, acc[r]);
      }
    }
    float* H = xt;
    float bias = ff_b[t];
#pragma unroll
    for (int r = 0; r < 8; ++r) H[r * 256 + t] = acc[r] + bias;
  }
  __syncthreads();

  {
    const float* H = xt;
    int r = t >> 5, q = t & 31;
    const float* Hr = H + r * 256 + q * 8;
    float s1 = 0.f, s2 = 0.f;
#pragma unroll
    for (int i = 0; i < 8; ++i) {
      float v = Hr[i];
      s1 += v;
      s2 += v * v;
    }
#pragma unroll
    for (int off = 1; off < 32; off <<= 1) {
      s1 += __shfl_xor(s1, off);
      s2 += __shfl_xor(s2, off);
    }
    float mu = s1 * (1.f / 256.f);
    float var = s2 * (1.f / 256.f) - mu * mu;
    float rstd = rsqrtf(var + 1e-5f);
    float* op = out + (row0 + r) * 256 + q * 8;
#pragma unroll
    for (int i = 0; i < 8; ++i) {
      float v = (Hr[i] - mu) * rstd * ln_g[q * 8 + i] + ln_b[q * 8 + i];
      op[i] = v > 0.f ? v : 0.f;
    }
  }
}

}  // namespace

extern "C" void kernel_launch(void* const* d_in, const int* in_sizes, int n_in,
                              void* d_out, int out_size, void* d_ws, size_t ws_size,
                              hipStream_t stream) {
  const float* text = (const float*)d_in[0];
  const float* user = (const float*)d_in[1];
  const float* tm_w = (const float*)d_in[2];
  const float* tm_b = (const float*)d_in[3];
  const float* um_w = (const float*)d_in[4];
  const float* um_b = (const float*)d_in[5];
  const float* ipw = (const float*)d_in[6];
  const float* ipb = (const float*)d_in[7];
  const float* opw = (const float*)d_in[8];
  const float* opb = (const float*)d_in[9];
  const float* tg_w = (const float*)d_in[10];
  const float* tg_b = (const float*)d_in[11];
  const float* ug_w = (const float*)d_in[12];
  const float* ug_b = (const float*)d_in[13];
  const float* ff_w = (const float*)d_in[14];
  const float* ff_b = (const float*)d_in[15];
  const float* ln_g = (const float*)d_in[16];
  const float* ln_b = (const float*)d_in[17];
  char* wsb = (char*)d_ws;
  float* out = (float*)d_out;

  // common precompute
  k_combine<<<256, 256, 0, stream>>>(ipw, opw, wsb);
  k_combine_bias<<<2, 256, 0, stream>>>(ipb, opb, opw, wsb);
  k_bias_tu<<<2, 256, 0, stream>>>(tm_b, um_b, wsb);
  k_mt4<<<768, 256, 0, stream>>>(tm_w, wsb);
  k_mu4<<<256, 256, 0, stream>>>(um_w, wsb);
  k_transpose4<<<256, 256, 0, stream>>>(ff_w, (float*)(wsb + OFF_FW4), 256, 256);

  if ((long)ws_size >= WS_NEED) {
    // fast path: gate-folded MFMA front -> F global -> ff+LN back
    float* Fg = (float*)(wsb + OFF_F);
    k_mt_hl<<<768, 256, 0, stream>>>(tm_w, wsb);
    k_mu_hl<<<256, 256, 0, stream>>>(um_w, wsb);
    k_gt<<<768, 256, 0, stream>>>(tg_w, ug_w, wsb);
    k_gu<<<256, 256, 0, stream>>>(tg_w, ug_w, wsb);
    k_gbias<<<1, 256, 0, stream>>>(tg_w, tg_b, ug_w, ug_b, wsb);
    k_s12g<<<2048, 512, 0, stream>>>(text, user, wsb, Fg);
    k_ffln<<<4096, 256, 0, stream>>>(Fg, wsb, ff_b, ln_g, ln_b, out);
  } else {
    // fallback: R5 fused scalar (known-pass)
    k_pack_gw4<<<256, 256, 0, stream>>>(tg_w, ug_w, wsb);
    k_main5<<<8192, 256, 0, stream>>>(text, user, wsb, tg_b, ug_b, ff_b, ln_g, ln_b, out);
  }
}

// Round 21
// 419.987 us; speedup vs baseline: 1.7741x; 1.1906x over previous
//
#include <hip/hip_runtime.h>
#include <hip/hip_bf16.h>

// MultiViewFusion — round 21: MFMA everywhere (ff GEMM converted).
// Evidence ledger:
//   R5 PASS scalar (1338us). R6-R9 FAIL: MFMA acc->LDS->read corrupts;
//   QUARANTINE: MFMA acc exits only via VALU->global. Scalar data in LDS fine.
//   R10: MFMA front coordinate-exact. R19 PASS 539us. R20 PASS 500us (best):
//   gate fold into kA validated (absmax unchanged 0.015625); k_s12g=281us,
//   k_ffln~160us with scalar ff GEMM = last non-MFMA GEMM.
// R21: k_ff32 = k_s12-stage-2 clone for ff (M=32, 512t, F staged hi/lo bf16
//   in 32KB LDS, 3-term MFMA vs FFH/FFL packs, K=256): acc+ff_b -> H written
//   OVER the F region (row-disjoint, read-before-write per block). k_ln reads
//   H -> LN/ReLU -> out (R14-validated pattern, global input).

namespace {

typedef __attribute__((ext_vector_type(8))) short short8v;   // 8 bf16 = 4 VGPR
typedef __attribute__((ext_vector_type(4))) float floatx4;   // MFMA C/D

// workspace byte offsets
constexpr int OFF_CW  = 0;        // f32 CWt[4][128][128]
constexpr int OFF_CB  = 262144;   // f32 cv[4][128]
constexpr int OFF_BT  = 264192;   // f32 bT[256]  [ts|uc]
constexpr int OFF_BU  = 265216;   // f32 bU[256]  [tc|us]
constexpr int OFF_MTH = 266240;   // bf16 M_text hi packed [96][256][8]
constexpr int OFF_MTL = 659456;   // bf16 M_text lo
constexpr int OFF_MUH = 1052672;  // bf16 M_user hi packed [32][256][8]
constexpr int OFF_MUL = 1183744;  // bf16 M_user lo
constexpr int OFF_GW4 = 1314816;  // f32 gate W [64][256][4] (fallback only)
constexpr int OFF_FW4 = 1576960;  // f32 ff  W  [64][256][4] (fallback only)
constexpr int OFF_MT4 = 1839104;  // f32 M_text pack [192][256][4]
constexpr int OFF_MU4 = 2625536;  // f32 M_user pack [64][256][4]
constexpr int OFF_GTH = 2887680;  // bf16 Gt hi [96][256][8]  (gate text-part)
constexpr int OFF_GUH = 3280896;  // bf16 Gu hi [32][256][8]  (gate user-part)
constexpr int OFF_GB2 = 3411968;  // f32 gbias[256]
constexpr int OFF_FFH = 3412992;  // bf16 ff hi packed [32][256][8]
constexpr int OFF_FFL = 3544064;  // bf16 ff lo
constexpr long OFF_F  = 3675136;  // f32 F [65536][256] = 67108864 B; H overlays F
constexpr long WS_NEED = OFF_F + 67108864L;

__device__ inline unsigned short f2b(float f) {
  __hip_bfloat16 h = __float2bfloat16(f);
  return __builtin_bit_cast(unsigned short, h);
}
__device__ inline float b2f(unsigned short u) {
  unsigned int v = ((unsigned int)u) << 16;
  return __builtin_bit_cast(float, v);
}
__device__ inline void split2(float v, unsigned short& h, unsigned short& l) {
  h = f2b(v);
  l = f2b(v - b2f(h));
}

// ---------------- precompute (tiny, L2-resident) ----------------

__global__ void k_combine(const float* __restrict__ ipw, const float* __restrict__ opw,
                          char* __restrict__ wsb) {
  float* cw = (float*)(wsb + OFF_CW);
  int n = blockIdx.x * 256 + threadIdx.x;
  int i = n >> 14, o = (n >> 7) & 127, d = n & 127;
  const float* op = opw + i * 16384 + o * 128;
  const float* iv = ipw + i * 49152 + 256 * 128 + d;
  float s = 0.f;
#pragma unroll 4
  for (int m = 0; m < 128; ++m) s = fmaf(op[m], iv[m * 128], s);
  cw[i * 16384 + d * 128 + o] = s;
}

__global__ void k_combine_bias(const float* __restrict__ ipb, const float* __restrict__ opb,
                               const float* __restrict__ opw, char* __restrict__ wsb) {
  float* cb = (float*)(wsb + OFF_CB);
  int t = blockIdx.x * 256 + threadIdx.x;
  int i = t >> 7, o = t & 127;
  const float* op = opw + i * 16384 + o * 128;
  const float* ib = ipb + i * 384 + 256;
  float s = opb[i * 128 + o];
#pragma unroll 4
  for (int m = 0; m < 128; ++m) s = fmaf(op[m], ib[m], s);
  cb[t] = s;
}

__global__ void k_mt_hl(const float* __restrict__ tm_w, char* __restrict__ wsb) {
  const float* cw = (const float*)(wsb + OFF_CW);
  unsigned short* dh = (unsigned short*)(wsb + OFF_MTH);
  unsigned short* dl = (unsigned short*)(wsb + OFF_MTL);
  int n = blockIdx.x * 256 + threadIdx.x;  // 768*256
  int k = n >> 8, c = n & 255;
  const float* p = cw + ((c >> 7) ? 3 : 0) * 16384 + (c & 127);
  float s = 0.f;
#pragma unroll 4
  for (int d = 0; d < 128; ++d) s = fmaf(p[d * 128], tm_w[d * 768 + k], s);
  unsigned short h, l;
  split2(s, h, l);
  int ofs = (((k >> 3) * 256 + c) << 3) + (k & 7);
  dh[ofs] = h;
  dl[ofs] = l;
}

__global__ void k_mu_hl(const float* __restrict__ um_w, char* __restrict__ wsb) {
  const float* cw = (const float*)(wsb + OFF_CW);
  unsigned short* dh = (unsigned short*)(wsb + OFF_MUH);
  unsigned short* dl = (unsigned short*)(wsb + OFF_MUL);
  int n = blockIdx.x * 256 + threadIdx.x;  // 256*256
  int k = n >> 8, c = n & 255;
  const float* p = cw + ((c >> 7) ? 1 : 2) * 16384 + (c & 127);
  float s = 0.f;
#pragma unroll 4
  for (int d = 0; d < 128; ++d) s = fmaf(p[d * 128], um_w[d * 256 + k], s);
  unsigned short h, l;
  split2(s, h, l);
  int ofs = (((k >> 3) * 256 + c) << 3) + (k & 7);
  dh[ofs] = h;
  dl[ofs] = l;
}

// ff hi/lo pack [32][256][8] from ff_w [256][256]
__global__ void k_ff_hl(const float* __restrict__ ff_w, char* __restrict__ wsb) {
  unsigned short* dh = (unsigned short*)(wsb + OFF_FFH);
  unsigned short* dl = (unsigned short*)(wsb + OFF_FFL);
  int idx = blockIdx.x * 256 + threadIdx.x;  // 65536
  int k = idx >> 8, n = idx & 255;
  unsigned short h, l;
  split2(ff_w[n * 256 + k], h, l);
  int ofs = (((k >> 3) * 256 + n) << 3) + (k & 7);
  dh[ofs] = h;
  dl[ofs] = l;
}

// f32 [K/4][256][4] packs
__global__ void k_mt4(const float* __restrict__ tm_w, char* __restrict__ wsb) {
  const float* cw = (const float*)(wsb + OFF_CW);
  float* dst = (float*)(wsb + OFF_MT4);
  int n = blockIdx.x * 256 + threadIdx.x;  // 768*256
  int k = n >> 8, c = n & 255;
  const float* p = cw + ((c >> 7) ? 3 : 0) * 16384 + (c & 127);
  float s = 0.f;
#pragma unroll 4
  for (int d = 0; d < 128; ++d) s = fmaf(p[d * 128], tm_w[d * 768 + k], s);
  dst[(((k >> 2) * 256 + c) << 2) + (k & 3)] = s;
}

__global__ void k_mu4(const float* __restrict__ um_w, char* __restrict__ wsb) {
  const float* cw = (const float*)(wsb + OFF_CW);
  float* dst = (float*)(wsb + OFF_MU4);
  int n = blockIdx.x * 256 + threadIdx.x;  // 256*256
  int k = n >> 8, c = n & 255;
  const float* p = cw + ((c >> 7) ? 1 : 2) * 16384 + (c & 127);
  float s = 0.f;
#pragma unroll 4
  for (int d = 0; d < 128; ++d) s = fmaf(p[d * 128], um_w[d * 256 + k], s);
  dst[(((k >> 2) * 256 + c) << 2) + (k & 3)] = s;
}

__global__ void k_bias_tu(const float* __restrict__ tm_b, const float* __restrict__ um_b,
                          char* __restrict__ wsb) {
  const float* cw = (const float*)(wsb + OFF_CW);
  const float* cb = (const float*)(wsb + OFF_CB);
  float* bT = (float*)(wsb + OFF_BT);
  float* bU = (float*)(wsb + OFF_BU);
  int t = blockIdx.x * 256 + threadIdx.x;
  if (t < 256) {
    int sel = (t >> 7) ? 3 : 0;
    const float* p = cw + sel * 16384 + (t & 127);
    float s = cb[sel * 128 + (t & 127)];
#pragma unroll 4
    for (int d = 0; d < 128; ++d) s = fmaf(p[d * 128], tm_b[d], s);
    bT[t] = s;
  } else {
    int c = t - 256;
    int sel = (c >> 7) ? 1 : 2;
    const float* p = cw + sel * 16384 + (c & 127);
    float s = cb[sel * 128 + (c & 127)];
#pragma unroll 4
    for (int d = 0; d < 128; ++d) s = fmaf(p[d * 128], um_b[d], s);
    bU[c] = s;
  }
}

// Gt[n][k] bf16 hi pack [96][256][8] (R20-validated)
__global__ void k_gt(const float* __restrict__ tg_w, const float* __restrict__ ug_w,
                     char* __restrict__ wsb) {
  const float* mt = (const float*)(wsb + OFF_MT4);
  unsigned short* dst = (unsigned short*)(wsb + OFF_GTH);
  int idx = blockIdx.x * 256 + threadIdx.x;  // 768*256
  int k = idx >> 8, n = idx & 255;
  const float* mb = mt + (((k >> 2) * 256) << 2) + (k & 3);
  float s = 0.f;
  if (n < 128) {
    const float* w = tg_w + n * 256;
#pragma unroll 4
    for (int m = 0; m < 128; ++m) s = fmaf(w[m], mb[m * 4], s);
  } else {
    const float* w = ug_w + (n - 128) * 256 + 128;
#pragma unroll 4
    for (int m = 0; m < 128; ++m) s = fmaf(w[m], mb[(128 + m) * 4], s);
  }
  dst[(((k >> 3) * 256 + n) << 3) + (k & 7)] = f2b(s);
}

// Gu[n][k] bf16 hi pack [32][256][8] (R20-validated)
__global__ void k_gu(const float* __restrict__ tg_w, const float* __restrict__ ug_w,
                     char* __restrict__ wsb) {
  const float* mu = (const float*)(wsb + OFF_MU4);
  unsigned short* dst = (unsigned short*)(wsb + OFF_GUH);
  int idx = blockIdx.x * 256 + threadIdx.x;  // 256*256
  int k = idx >> 8, n = idx & 255;
  const float* mb = mu + (((k >> 2) * 256) << 2) + (k & 3);
  float s = 0.f;
  if (n < 128) {
    const float* w = tg_w + n * 256 + 128;
#pragma unroll 4
    for (int m = 0; m < 128; ++m) s = fmaf(w[m], mb[m * 4], s);
  } else {
    const float* w = ug_w + (n - 128) * 256;
#pragma unroll 4
    for (int m = 0; m < 128; ++m) s = fmaf(w[m], mb[(128 + m) * 4], s);
  }
  dst[(((k >> 3) * 256 + n) << 3) + (k & 7)] = f2b(s);
}

__global__ void k_gbias(const float* __restrict__ tg_w, const float* __restrict__ tg_b,
                        const float* __restrict__ ug_w, const float* __restrict__ ug_b,
                        char* __restrict__ wsb) {
  const float* bT = (const float*)(wsb + OFF_BT);
  const float* bU = (const float*)(wsb + OFF_BU);
  float* gb2 = (float*)(wsb + OFF_GB2);
  int n = threadIdx.x;  // 256
  float s;
  if (n < 128) {
    s = tg_b[n];
    const float* w = tg_w + n * 256;
#pragma unroll 4
    for (int m = 0; m < 128; ++m) s = fmaf(w[m], bT[m], s);
#pragma unroll 4
    for (int m = 0; m < 128; ++m) s = fmaf(w[128 + m], bU[m], s);
  } else {
    int np = n - 128;
    s = ug_b[np];
    const float* w = ug_w + np * 256;
#pragma unroll 4
    for (int m = 0; m < 128; ++m) s = fmaf(w[m], bU[128 + m], s);
#pragma unroll 4
    for (int m = 0; m < 128; ++m) s = fmaf(w[128 + m], bT[128 + m], s);
  }
  gb2[n] = s;
}

// fallback packs
__global__ void k_pack_gw4(const float* __restrict__ tg_w, const float* __restrict__ ug_w,
                           char* __restrict__ wsb) {
  float* dst = (float*)(wsb + OFF_GW4);
  int idx = blockIdx.x * 256 + threadIdx.x;
  int j = idx >> 8, n = idx & 255;
  float v = (n < 128) ? tg_w[n * 256 + j] : ug_w[(n - 128) * 256 + j];
  dst[(((j >> 2) * 256 + n) << 2) + (j & 3)] = v;
}

__global__ void k_transpose4(const float* __restrict__ src, float* __restrict__ dst,
                             int R, int C) {
  int n = blockIdx.x * 256 + threadIdx.x;
  if (n >= R * C) return;
  int o = n / C, k = n % C;
  dst[(((k >> 2) * R + o) << 2) + (k & 3)] = src[n];
}

// ---------------- kA: MFMA stages 1/2 + folded gates -> F global (R20-verbatim) ----------------

#define SWZ(byte, row) ((byte) ^ (((row) & 7) << 4))

__launch_bounds__(512)
__global__ void k_s12g(const float* __restrict__ xt_g, const float* __restrict__ xu_g,
                       const char* __restrict__ wsb, float* __restrict__ Fg) {
  __shared__ __align__(16) char sm[65536];
  constexpr int XTL = 24576;
  constexpr int XUH = 49152;
  constexpr int XUL = 57344;

  const int t = threadIdx.x;
  const int wave = t >> 6, lane = t & 63;
  const int lrow = lane & 15;
  const int lk8 = lane >> 4;
  const int n0w = wave * 32;
  const long row0 = (long)blockIdx.x * 32;

  const float* bT = (const float*)(wsb + OFF_BT);
  const float* bU = (const float*)(wsb + OFF_BU);
  const float* gb2 = (const float*)(wsb + OFF_GB2);

  floatx4 zero = {0.f, 0.f, 0.f, 0.f};
  floatx4 acc1[2][2] = {{zero, zero}, {zero, zero}};
  floatx4 acc2[2][2] = {{zero, zero}, {zero, zero}};
  floatx4 accG1[2][2] = {{zero, zero}, {zero, zero}};
  floatx4 accG2[2][2] = {{zero, zero}, {zero, zero}};

  for (int p = 0; p < 2; ++p) {
    if (p) __syncthreads();

#pragma unroll
    for (int it = 0; it < 6; ++it) {
      int idx = it * 512 + t;
      int row = idx / 96, rem = idx - row * 96;
      float4 v = *(const float4*)(xt_g + (row0 + row) * 768 + p * 384 + rem * 4);
      int b0 = row * 768 + rem * 8;
      ushort4 hh, ll;
      split2(v.x, hh.x, ll.x); split2(v.y, hh.y, ll.y);
      split2(v.z, hh.z, ll.z); split2(v.w, hh.w, ll.w);
      *(ushort4*)(sm + SWZ(b0, row)) = hh;
      *(ushort4*)(sm + XTL + SWZ(b0, row)) = ll;
    }
#pragma unroll
    for (int it = 0; it < 2; ++it) {
      int idx = it * 512 + t;
      int row = idx >> 5, rem = idx & 31;
      float4 v = *(const float4*)(xu_g + (row0 + row) * 256 + p * 128 + rem * 4);
      int b0 = row * 256 + rem * 8;
      ushort4 hh, ll;
      split2(v.x, hh.x, ll.x); split2(v.y, hh.y, ll.y);
      split2(v.z, hh.z, ll.z); split2(v.w, hh.w, ll.w);
      *(ushort4*)(sm + XUH + SWZ(b0, row)) = hh;
      *(ushort4*)(sm + XUL + SWZ(b0, row)) = ll;
    }
    __syncthreads();

    {
      const char* wh = wsb + OFF_MTH;
      const char* wl = wsb + OFF_MTL;
      const char* gt = wsb + OFF_GTH;
#pragma unroll 4
      for (int kk = 0; kk < 384; kk += 32) {
        int kb = (kk + lk8 * 8) * 2;
        int k8 = ((p * 384 + kk) >> 3) + lk8;
        int o0 = (k8 * 256 + n0w + lrow) << 4;
        int o1 = (k8 * 256 + n0w + 16 + lrow) << 4;
        short8v bh0 = *(const short8v*)(wh + o0);
        short8v bh1 = *(const short8v*)(wh + o1);
        short8v bl0 = *(const short8v*)(wl + o0);
        short8v bl1 = *(const short8v*)(wl + o1);
        short8v g0 = *(const short8v*)(gt + o0);
        short8v g1 = *(const short8v*)(gt + o1);
#pragma unroll
        for (int rg = 0; rg < 2; ++rg) {
          int ar = rg * 16 + lrow;
          short8v ah = *(const short8v*)(sm + SWZ(ar * 768 + kb, ar));
          short8v al = *(const short8v*)(sm + XTL + SWZ(ar * 768 + kb, ar));
          acc1[rg][0] = __builtin_amdgcn_mfma_f32_16x16x32_bf16(ah, bh0, acc1[rg][0], 0, 0, 0);
          acc1[rg][0] = __builtin_amdgcn_mfma_f32_16x16x32_bf16(ah, bl0, acc1[rg][0], 0, 0, 0);
          acc1[rg][0] = __builtin_amdgcn_mfma_f32_16x16x32_bf16(al, bh0, acc1[rg][0], 0, 0, 0);
          acc1[rg][1] = __builtin_amdgcn_mfma_f32_16x16x32_bf16(ah, bh1, acc1[rg][1], 0, 0, 0);
          acc1[rg][1] = __builtin_amdgcn_mfma_f32_16x16x32_bf16(ah, bl1, acc1[rg][1], 0, 0, 0);
          acc1[rg][1] = __builtin_amdgcn_mfma_f32_16x16x32_bf16(al, bh1, acc1[rg][1], 0, 0, 0);
          accG1[rg][0] = __builtin_amdgcn_mfma_f32_16x16x32_bf16(ah, g0, accG1[rg][0], 0, 0, 0);
          accG1[rg][1] = __builtin_amdgcn_mfma_f32_16x16x32_bf16(ah, g1, accG1[rg][1], 0, 0, 0);
        }
      }
    }
    {
      const char* wh = wsb + OFF_MUH;
      const char* wl = wsb + OFF_MUL;
      const char* gu = wsb + OFF_GUH;
#pragma unroll
      for (int kk = 0; kk < 128; kk += 32) {
        int kb = (kk + lk8 * 8) * 2;
        int k8 = ((p * 128 + kk) >> 3) + lk8;
        int o0 = (k8 * 256 + n0w + lrow) << 4;
        int o1 = (k8 * 256 + n0w + 16 + lrow) << 4;
        short8v bh0 = *(const short8v*)(wh + o0);
        short8v bh1 = *(const short8v*)(wh + o1);
        short8v bl0 = *(const short8v*)(wl + o0);
        short8v bl1 = *(const short8v*)(wl + o1);
        short8v g0 = *(const short8v*)(gu + o0);
        short8v g1 = *(const short8v*)(gu + o1);
#pragma unroll
        for (int rg = 0; rg < 2; ++rg) {
          int ar = rg * 16 + lrow;
          short8v ah = *(const short8v*)(sm + XUH + SWZ(ar * 256 + kb, ar));
          short8v al = *(const short8v*)(sm + XUL + SWZ(ar * 256 + kb, ar));
          acc2[rg][0] = __builtin_amdgcn_mfma_f32_16x16x32_bf16(ah, bh0, acc2[rg][0], 0, 0, 0);
          acc2[rg][0] = __builtin_amdgcn_mfma_f32_16x16x32_bf16(ah, bl0, acc2[rg][0], 0, 0, 0);
          acc2[rg][0] = __builtin_amdgcn_mfma_f32_16x16x32_bf16(al, bh0, acc2[rg][0], 0, 0, 0);
          acc2[rg][1] = __builtin_amdgcn_mfma_f32_16x16x32_bf16(ah, bh1, acc2[rg][1], 0, 0, 0);
          acc2[rg][1] = __builtin_amdgcn_mfma_f32_16x16x32_bf16(ah, bl1, acc2[rg][1], 0, 0, 0);
          acc2[rg][1] = __builtin_amdgcn_mfma_f32_16x16x32_bf16(al, bh1, acc2[rg][1], 0, 0, 0);
          accG2[rg][0] = __builtin_amdgcn_mfma_f32_16x16x32_bf16(ah, g0, accG2[rg][0], 0, 0, 0);
          accG2[rg][1] = __builtin_amdgcn_mfma_f32_16x16x32_bf16(ah, g1, accG2[rg][1], 0, 0, 0);
        }
      }
    }
  }

  // ---- epilogue: sigmoid + mix -> F global (R20-validated) ----
#pragma unroll
  for (int rg = 0; rg < 2; ++rg)
#pragma unroll
    for (int nt = 0; nt < 2; ++nt) {
      int n = n0w + nt * 16 + lrow;
      float bvT = bT[n], bvU = bU[n], gbn = gb2[n];
#pragma unroll
      for (int reg = 0; reg < 4; ++reg) {
        long row = row0 + rg * 16 + lk8 * 4 + reg;
        float a1 = acc1[rg][nt][reg] + bvT;
        float a2 = acc2[rg][nt][reg] + bvU;
        float logit = accG1[rg][nt][reg] + accG2[rg][nt][reg] + gbn;
        float g = 1.f / (1.f + __expf(-logit));
        float f = (n < 128) ? fmaf(g, a2 - a1, a1)
                            : fmaf(g, a1 - a2, a2);
        Fg[row * 256 + n] = f;
      }
    }
}

// ---------------- kB1: ff MFMA (F staged hi/lo -> 3-term MFMA -> H over F) ----------------
// 512 threads = 8 waves, 32 rows/block (2048 blocks), 32 KB LDS.
// FHg serves as F (input) and H (output): block reads its 32 rows into LDS
// first, then overwrites the same rows -> no cross-block hazard.

__launch_bounds__(512)
__global__ void k_ff32(float* FHg, const char* __restrict__ wsb,
                       const float* __restrict__ ff_b) {
  __shared__ __align__(16) char sm[32768];
  constexpr int FLO = 16384;  // F lo (F hi at 0; [32][256] bf16 = 16384 B each)

  const int t = threadIdx.x;
  const int wave = t >> 6, lane = t & 63;
  const int lrow = lane & 15;
  const int lk8 = lane >> 4;
  const int n0w = wave * 32;
  const long row0 = (long)blockIdx.x * 32;

  // ---- stage F -> LDS hi/lo (scalar data; quarantine-compliant) ----
  // 32 rows x 64 float4/row = 2048 float4 / 512t = 4 iters; ushort4 out -> rem*8
#pragma unroll
  for (int it = 0; it < 4; ++it) {
    int idx = it * 512 + t;
    int row = idx >> 6, rem = idx & 63;
    float4 v = *(const float4*)(FHg + (row0 + row) * 256 + rem * 4);
    int b0 = row * 512 + rem * 8;
    ushort4 hh, ll;
    split2(v.x, hh.x, ll.x); split2(v.y, hh.y, ll.y);
    split2(v.z, hh.z, ll.z); split2(v.w, hh.w, ll.w);
    *(ushort4*)(sm + SWZ(b0, row)) = hh;
    *(ushort4*)(sm + FLO + SWZ(b0, row)) = ll;
  }
  __syncthreads();

  floatx4 zero = {0.f, 0.f, 0.f, 0.f};
  floatx4 acc[2][2] = {{zero, zero}, {zero, zero}};  // [rowgrp][nt]

  {
    const char* wh = wsb + OFF_FFH;
    const char* wl = wsb + OFF_FFL;
#pragma unroll
    for (int kk = 0; kk < 256; kk += 32) {
      int kb = (kk + lk8 * 8) * 2;
      int k8 = (kk >> 3) + lk8;
      int o0 = (k8 * 256 + n0w + lrow) << 4;
      int o1 = (k8 * 256 + n0w + 16 + lrow) << 4;
      short8v bh0 = *(const short8v*)(wh + o0);
      short8v bh1 = *(const short8v*)(wh + o1);
      short8v bl0 = *(const short8v*)(wl + o0);
      short8v bl1 = *(const short8v*)(wl + o1);
#pragma unroll
      for (int rg = 0; rg < 2; ++rg) {
        int ar = rg * 16 + lrow;
        short8v ah = *(const short8v*)(sm + SWZ(ar * 512 + kb, ar));
        short8v al = *(const short8v*)(sm + FLO + SWZ(ar * 512 + kb, ar));
        acc[rg][0] = __builtin_amdgcn_mfma_f32_16x16x32_bf16(ah, bh0, acc[rg][0], 0, 0, 0);
        acc[rg][0] = __builtin_amdgcn_mfma_f32_16x16x32_bf16(ah, bl0, acc[rg][0], 0, 0, 0);
        acc[rg][0] = __builtin_amdgcn_mfma_f32_16x16x32_bf16(al, bh0, acc[rg][0], 0, 0, 0);
        acc[rg][1] = __builtin_amdgcn_mfma_f32_16x16x32_bf16(ah, bh1, acc[rg][1], 0, 0, 0);
        acc[rg][1] = __builtin_amdgcn_mfma_f32_16x16x32_bf16(ah, bl1, acc[rg][1], 0, 0, 0);
        acc[rg][1] = __builtin_amdgcn_mfma_f32_16x16x32_bf16(al, bh1, acc[rg][1], 0, 0, 0);
      }
    }
  }

  // ---- epilogue: acc + ff_b -> H over the SAME rows (quarantine-compliant) ----
#pragma unroll
  for (int rg = 0; rg < 2; ++rg)
#pragma unroll
    for (int nt = 0; nt < 2; ++nt) {
      int n = n0w + nt * 16 + lrow;
      float fb = ff_b[n];
#pragma unroll
      for (int reg = 0; reg < 4; ++reg) {
        long row = row0 + rg * 16 + lk8 * 4 + reg;
        FHg[row * 256 + n] = acc[rg][nt][reg] + fb;
      }
    }
}

// ---------------- kB2: LayerNorm + ReLU from global H (R14-validated pattern) ----------------
// 256 threads, 16 rows/block (4096 blocks). No LDS.

__launch_bounds__(256)
__global__ void k_ln(const float* __restrict__ Hg, const float* __restrict__ ln_g,
                     const float* __restrict__ ln_b, float* __restrict__ out) {
  const int t = threadIdx.x;
  const long row0 = (long)blockIdx.x * 16;
  int r = t >> 4, q = t & 15;
  const float* Hr = Hg + (row0 + r) * 256 + q * 16;
  float4 hv[4];
  float s1 = 0.f, s2 = 0.f;
#pragma unroll
  for (int j = 0; j < 4; ++j) {
    hv[j] = *(const float4*)(Hr + j * 4);
    s1 += hv[j].x + hv[j].y + hv[j].z + hv[j].w;
    s2 += hv[j].x * hv[j].x + hv[j].y * hv[j].y + hv[j].z * hv[j].z + hv[j].w * hv[j].w;
  }
#pragma unroll
  for (int off = 1; off < 16; off <<= 1) {
    s1 += __shfl_xor(s1, off);
    s2 += __shfl_xor(s2, off);
  }
  float mu = s1 * (1.f / 256.f);
  float var = s2 * (1.f / 256.f) - mu * mu;
  float rstd = rsqrtf(var + 1e-5f);
  float* op = out + (row0 + r) * 256 + q * 16;
#pragma unroll
  for (int j = 0; j < 4; ++j) {
    const float* gp = ln_g + q * 16 + j * 4;
    const float* bp = ln_b + q * 16 + j * 4;
    float4 o;
    o.x = fmaf((hv[j].x - mu) * rstd, gp[0], bp[0]);
    o.y = fmaf((hv[j].y - mu) * rstd, gp[1], bp[1]);
    o.z = fmaf((hv[j].z - mu) * rstd, gp[2], bp[2]);
    o.w = fmaf((hv[j].w - mu) * rstd, gp[3], bp[3]);
    o.x = o.x > 0.f ? o.x : 0.f;
    o.y = o.y > 0.f ? o.y : 0.f;
    o.z = o.z > 0.f ? o.z : 0.f;
    o.w = o.w > 0.f ? o.w : 0.f;
    *(float4*)(op + j * 4) = o;
  }
}

// ---------------- fallback: R5 fused scalar kernel (known-pass) ----------------

__launch_bounds__(256)
__global__ void k_main5(const float* __restrict__ xt_g, const float* __restrict__ xu_g,
                        const char* __restrict__ wsb,
                        const float* __restrict__ tg_b, const float* __restrict__ ug_b,
                        const float* __restrict__ ff_b, const float* __restrict__ ln_g,
                        const float* __restrict__ ln_b, float* __restrict__ out) {
  __shared__ float lds[8 * 768 + 8 * 512 + 8 * 256];  // 48 KB
  float* xt = lds;
  float* S = lds + 8 * 768;
  float* xu = lds + 8 * 768 + 8 * 512;

  const int t = threadIdx.x;
  const long row0 = (long)blockIdx.x * 8;

  {
    const float4* g = (const float4*)(xt_g + row0 * 768);
    float4* l = (float4*)xt;
#pragma unroll
    for (int it = 0; it < 6; ++it) l[it * 256 + t] = g[it * 256 + t];
    const float4* gu = (const float4*)(xu_g + row0 * 256);
    float4* lu = (float4*)xu;
#pragma unroll
    for (int it = 0; it < 2; ++it) lu[it * 256 + t] = gu[it * 256 + t];
  }
  __syncthreads();

  {
    const float4* W4 = (const float4*)(wsb + OFF_MT4);
    float acc[8];
#pragma unroll
    for (int r = 0; r < 8; ++r) acc[r] = 0.f;
    for (int k = 0; k < 768; k += 4) {
      float4 w = W4[(k >> 2) * 256 + t];
#pragma unroll
      for (int r = 0; r < 8; ++r) {
        float4 xv = *(const float4*)&xt[r * 768 + k];
        acc[r] = fmaf(w.x, xv.x, acc[r]);
        acc[r] = fmaf(w.y, xv.y, acc[r]);
        acc[r] = fmaf(w.z, xv.z, acc[r]);
        acc[r] = fmaf(w.w, xv.w, acc[r]);
      }
    }
    float bias = ((const float*)(wsb + OFF_BT))[t];
    int d = (t < 128) ? t : (256 + t);
#pragma unroll
    for (int r = 0; r < 8; ++r) S[r * 512 + d] = acc[r] + bias;
  }

  {
    const float4* W4 = (const float4*)(wsb + OFF_MU4);
    float acc[8];
#pragma unroll
    for (int r = 0; r < 8; ++r) acc[r] = 0.f;
    for (int k = 0; k < 256; k += 4) {
      float4 w = W4[(k >> 2) * 256 + t];
#pragma unroll
      for (int r = 0; r < 8; ++r) {
        float4 xv = *(const float4*)&xu[r * 256 + k];
        acc[r] = fmaf(w.x, xv.x, acc[r]);
        acc[r] = fmaf(w.y, xv.y, acc[r]);
        acc[r] = fmaf(w.z, xv.z, acc[r]);
        acc[r] = fmaf(w.w, xv.w, acc[r]);
      }
    }
    float bias = ((const float*)(wsb + OFF_BU))[t];
#pragma unroll
    for (int r = 0; r < 8; ++r) S[r * 512 + 128 + t] = acc[r] + bias;
  }
  __syncthreads();

  {
    int c = t & 127, half = t >> 7;
    const float4* W4 = (const float4*)(wsb + OFF_GW4);
    const int wcol = half * 128 + c;
    const int so = half * 256;
    float acc[8];
#pragma unroll
    for (int r = 0; r < 8; ++r) acc[r] = 0.f;
    for (int j = 0; j < 256; j += 4) {
      float4 w = W4[(j >> 2) * 256 + wcol];
#pragma unroll
      for (int r = 0; r < 8; ++r) {
        float4 sv = *(const float4*)&S[r * 512 + so + j];
        acc[r] = fmaf(w.x, sv.x, acc[r]);
        acc[r] = fmaf(w.y, sv.y, acc[r]);
        acc[r] = fmaf(w.z, sv.z, acc[r]);
        acc[r] = fmaf(w.w, sv.w, acc[r]);
      }
    }
    float gb = half ? ug_b[c] : tg_b[c];
    float* F = xu;
#pragma unroll
    for (int r = 0; r < 8; ++r) {
      float g = 1.f / (1.f + __expf(-(acc[r] + gb)));
      float a = S[r * 512 + so + c];
      float b = S[r * 512 + so + 128 + c];
      F[r * 256 + half * 128 + c] = fmaf(g, b - a, a);
    }
  }
  __syncthreads();

  {
    const float4* W4 = (const float4*)(wsb + OFF_FW4);
    const float* F = xu;
    float acc[8];
#pragma unroll
    for (int r = 0; r < 8; ++r) acc[r] = 0.f;
    for (int j = 0; j < 256; j += 4) {
      float4 w = W4[(j >> 2) * 256 + t];
#pragma unroll
      for (int r = 0; r < 8; ++r) {
        float4 fv = *(const float4*)&F[r * 256 + j];
        acc[r] = fmaf(w.x, fv.x, acc[r]);
        acc[r] = fmaf(w.y, fv.y, acc[r]);
        acc[r] = fmaf(w.z, fv.z, acc[r]);
        acc[r] = fmaf(w.w, fv.w, acc[r]);
      }
    }
    float* H = xt;
    float bias = ff_b[t];
#pragma unroll
    for (int r = 0; r < 8; ++r) H[r * 256 + t] = acc[r] + bias;
  }
  __syncthreads();

  {
    const float* H = xt;
    int r = t >> 5, q = t & 31;
    const float* Hr = H + r * 256 + q * 8;
    float s1 = 0.f, s2 = 0.f;
#pragma unroll
    for (int i = 0; i < 8; ++i) {
      float v = Hr[i];
      s1 += v;
      s2 += v * v;
    }
#pragma unroll
    for (int off = 1; off < 32; off <<= 1) {
      s1 += __shfl_xor(s1, off);
      s2 += __shfl_xor(s2, off);
    }
    float mu = s1 * (1.f / 256.f);
    float var = s2 * (1.f / 256.f) - mu * mu;
    float rstd = rsqrtf(var + 1e-5f);
    float* op = out + (row0 + r) * 256 + q * 8;
#pragma unroll
    for (int i = 0; i < 8; ++i) {
      float v = (Hr[i] - mu) * rstd * ln_g[q * 8 + i] + ln_b[q * 8 + i];
      op[i] = v > 0.f ? v : 0.f;
    }
  }
}

}  // namespace

extern "C" void kernel_launch(void* const* d_in, const int* in_sizes, int n_in,
                              void* d_out, int out_size, void* d_ws, size_t ws_size,
                              hipStream_t stream) {
  const float* text = (const float*)d_in[0];
  const float* user = (const float*)d_in[1];
  const float* tm_w = (const float*)d_in[2];
  const float* tm_b = (const float*)d_in[3];
  const float* um_w = (const float*)d_in[4];
  const float* um_b = (const float*)d_in[5];
  const float* ipw = (const float*)d_in[6];
  const float* ipb = (const float*)d_in[7];
  const float* opw = (const float*)d_in[8];
  const float* opb = (const float*)d_in[9];
  const float* tg_w = (const float*)d_in[10];
  const float* tg_b = (const float*)d_in[11];
  const float* ug_w = (const float*)d_in[12];
  const float* ug_b = (const float*)d_in[13];
  const float* ff_w = (const float*)d_in[14];
  const float* ff_b = (const float*)d_in[15];
  const float* ln_g = (const float*)d_in[16];
  const float* ln_b = (const float*)d_in[17];
  char* wsb = (char*)d_ws;
  float* out = (float*)d_out;

  // common precompute
  k_combine<<<256, 256, 0, stream>>>(ipw, opw, wsb);
  k_combine_bias<<<2, 256, 0, stream>>>(ipb, opb, opw, wsb);
  k_bias_tu<<<2, 256, 0, stream>>>(tm_b, um_b, wsb);
  k_mt4<<<768, 256, 0, stream>>>(tm_w, wsb);
  k_mu4<<<256, 256, 0, stream>>>(um_w, wsb);

  if ((long)ws_size >= WS_NEED) {
    // fast path: gate-folded MFMA front -> F -> ff MFMA (H over F) -> LN
    float* Fg = (float*)(wsb + OFF_F);
    k_mt_hl<<<768, 256, 0, stream>>>(tm_w, wsb);
    k_mu_hl<<<256, 256, 0, stream>>>(um_w, wsb);
    k_gt<<<768, 256, 0, stream>>>(tg_w, ug_w, wsb);
    k_gu<<<256, 256, 0, stream>>>(tg_w, ug_w, wsb);
    k_gbias<<<1, 256, 0, stream>>>(tg_w, tg_b, ug_w, ug_b, wsb);
    k_ff_hl<<<256, 256, 0, stream>>>(ff_w, wsb);
    k_s12g<<<2048, 512, 0, stream>>>(text, user, wsb, Fg);
    k_ff32<<<2048, 512, 0, stream>>>(Fg, wsb, ff_b);
    k_ln<<<4096, 256, 0, stream>>>(Fg, ln_g, ln_b, out);
  } else {
    // fallback: R5 fused scalar (known-pass)
    k_pack_gw4<<<256, 256, 0, stream>>>(tg_w, ug_w, wsb);
    k_transpose4<<<256, 256, 0, stream>>>(ff_w, (float*)(wsb + OFF_FW4), 256, 256);
    k_main5<<<8192, 256, 0, stream>>>(text, user, wsb, tg_b, ug_b, ff_b, ln_g, ln_b, out);
  }
}